// Round 13
// baseline (366.745 us; speedup 1.0000x reference)
//
#include <hip/hip_runtime.h>
#include <hip/hip_bf16.h>
#include <math.h>

// ---------------- problem constants ----------------
constexpr int BB   = 512;
constexpr int TSEQ = 24;
constexpr int NF   = 81;
constexpr int DD   = 64;
constexpr int MTOT = BB * TSEQ;      // 12288
constexpr int FDIM = NF * DD;        // 5184
constexpr int KS   = 6;              // split-K groups (5184/6 = 864)
constexpr int KSL  = 864;
constexpr int NW   = 160;
constexpr int NT   = 6;
constexpr float LN_EPS = 1e-5f;

typedef __attribute__((ext_vector_type(8))) short short8v;
typedef __attribute__((ext_vector_type(4))) float f32x4;

static __device__ __forceinline__ float sigmoidf_(float x) {
    return __builtin_amdgcn_rcpf(1.f + __expf(-x));
}
static __device__ __forceinline__ float eluf_(float x) {
    return x > 0.f ? x : (__expf(x) - 1.f);
}
static __device__ __forceinline__ float ftanh_(float x) {
    float e = __expf(2.f * x);
    return 1.f - 2.f * __builtin_amdgcn_rcpf(e + 1.f);
}
static __device__ __forceinline__ unsigned short f2bf(float x) {
    __hip_bfloat16 h = __float2bfloat16(x);
    return *reinterpret_cast<unsigned short*>(&h);
}
static __device__ __forceinline__ float b2f(unsigned short u) {
    __hip_bfloat16 h = *reinterpret_cast<__hip_bfloat16*>(&u);
    return __bfloat162float(h);
}

// =====================================================================
// x transpose: LDS-tiled. grid MTOT/128.
// =====================================================================
__global__ __launch_bounds__(256) void xt_kernel(
    const float* __restrict__ x, float* __restrict__ xT)
{
    __shared__ float tile[128 * 81];
    const int m0 = blockIdx.x * 128;
    const int t  = threadIdx.x;
    for (int e = t; e < 128 * 81; e += 256)
        tile[e] = x[(size_t)m0 * NF + e];
    __syncthreads();
    for (int e = t; e < 128 * 81; e += 256) {
        int f = e >> 7, r = e & 127;
        xT[(size_t)f * MTOT + m0 + r] = tile[r * 81 + f];
    }
}

// =====================================================================
// Kernel 1: VSN v6 (verified round 11/12)
// =====================================================================
__global__ __launch_bounds__(256) void vsn_kernel(
    const float* __restrict__ xT,
    const float* __restrict__ f_w1,  const float* __restrict__ f_b1,
    const float* __restrict__ f_w2,  const float* __restrict__ f_b2,
    const float* __restrict__ f_g1w, const float* __restrict__ f_g1b,
    const float* __restrict__ f_g2w, const float* __restrict__ f_g2b,
    const float* __restrict__ f_skw, const float* __restrict__ f_skb,
    const float* __restrict__ f_lng, const float* __restrict__ f_lnb,
    __hip_bfloat16* __restrict__ stacked)
{
    const int f  = blockIdx.y;
    const int t  = threadIdx.x;
    const int w  = t >> 6;
    const int l  = t & 63;
    const int lr = l & 15;
    const int lg = l >> 4;

    __shared__ __align__(16) unsigned short W2t[64 * 72];
    __shared__ __align__(16) unsigned short G1t[64 * 72];
    __shared__ __align__(16) unsigned short G2t[64 * 72];
    __shared__ __align__(16) unsigned short hS[4][16 * 72];
    __shared__ float vw1[64], vb1[64], vb2[64], vg1b[64], vg2b[64];
    __shared__ float vskw[64], vskb[64], vlng[64], vlnb[64];

    if (t < 64) {
        vw1[t]  = f_w1 [f*64 + t];  vb1[t]  = f_b1 [f*64 + t];
        vb2[t]  = f_b2 [f*64 + t];
        vg1b[t] = f_g1b[f*64 + t];  vg2b[t] = f_g2b[f*64 + t];
        vskw[t] = f_skw[f*64 + t];  vskb[t] = f_skb[f*64 + t];
        vlng[t] = f_lng[f*64 + t];  vlnb[t] = f_lnb[f*64 + t];
    }
    {
        const float* w2p = f_w2  + (size_t)f * 4096;
        const float* g1p = f_g1w + (size_t)f * 4096;
        const float* g2p = f_g2w + (size_t)f * 4096;
        #pragma unroll
        for (int p = 0; p < 16; ++p) {
            int e = t + 256 * p; int k = e >> 6, c = e & 63;
            W2t[c*72 + k] = f2bf(w2p[k*64 + c]);
            G1t[c*72 + k] = f2bf(g1p[k*64 + c]);
            G2t[c*72 + k] = f2bf(g2p[k*64 + c]);
        }
    }
    __syncthreads();

    unsigned short* slab = hS[w];

    for (int it = 0; it < NT; ++it) {
        const int m0 = (blockIdx.x * NT + it) * 64;
        const float xval = xT[(size_t)f * MTOT + m0 + w*16 + lr];

        short8v a0f, a1f;
        #pragma unroll
        for (int j = 0; j < 8; ++j) {
            const int d0 = lg*8 + j, d1 = 32 + lg*8 + j;
            a0f[j] = (short)f2bf(eluf_(xval * vw1[d0] + vb1[d0]));
            a1f[j] = (short)f2bf(eluf_(xval * vw1[d1] + vb1[d1]));
        }

        f32x4 acc1[4];
        #pragma unroll
        for (int cf = 0; cf < 4; ++cf) acc1[cf] = (f32x4){0.f,0.f,0.f,0.f};
        #pragma unroll
        for (int cf = 0; cf < 4; ++cf) {
            short8v b0 = *(const short8v*)&W2t[(cf*16 + lr)*72 + lg*8];
            short8v b1 = *(const short8v*)&W2t[(cf*16 + lr)*72 + 32 + lg*8];
            acc1[cf] = __builtin_amdgcn_mfma_f32_16x16x32_bf16(a0f, b0, acc1[cf], 0, 0, 0);
            acc1[cf] = __builtin_amdgcn_mfma_f32_16x16x32_bf16(a1f, b1, acc1[cf], 0, 0, 0);
        }

        #pragma unroll
        for (int cf = 0; cf < 4; ++cf)
            #pragma unroll
            for (int j = 0; j < 4; ++j) {
                const int c = cf*16 + lr;
                slab[(4*lg + j)*72 + c] = f2bf(acc1[cf][j] + vb2[c]);
            }
        __builtin_amdgcn_sched_barrier(0);

        short8v h0f = *(const short8v*)&slab[lr*72 + lg*8];
        short8v h1f = *(const short8v*)&slab[lr*72 + 32 + lg*8];

        f32x4 aA[4], aB[4];
        #pragma unroll
        for (int cf = 0; cf < 4; ++cf) { aA[cf] = (f32x4){0.f,0.f,0.f,0.f}; aB[cf] = (f32x4){0.f,0.f,0.f,0.f}; }
        #pragma unroll
        for (int cf = 0; cf < 4; ++cf) {
            short8v b10 = *(const short8v*)&G1t[(cf*16 + lr)*72 + lg*8];
            short8v b11 = *(const short8v*)&G1t[(cf*16 + lr)*72 + 32 + lg*8];
            short8v b20 = *(const short8v*)&G2t[(cf*16 + lr)*72 + lg*8];
            short8v b21 = *(const short8v*)&G2t[(cf*16 + lr)*72 + 32 + lg*8];
            aA[cf] = __builtin_amdgcn_mfma_f32_16x16x32_bf16(h0f, b10, aA[cf], 0, 0, 0);
            aA[cf] = __builtin_amdgcn_mfma_f32_16x16x32_bf16(h1f, b11, aA[cf], 0, 0, 0);
            aB[cf] = __builtin_amdgcn_mfma_f32_16x16x32_bf16(h0f, b20, aB[cf], 0, 0, 0);
            aB[cf] = __builtin_amdgcn_mfma_f32_16x16x32_bf16(h1f, b21, aB[cf], 0, 0, 0);
        }

        float xs[4];
        #pragma unroll
        for (int j = 0; j < 4; ++j) xs[j] = __shfl(xval, 4*lg + j, 64);
        float yv[4][4];
        #pragma unroll
        for (int cf = 0; cf < 4; ++cf)
            #pragma unroll
            for (int j = 0; j < 4; ++j) {
                const int c = cf*16 + lr;
                float sg = sigmoidf_(aA[cf][j] + vg1b[c]);
                yv[cf][j] = sg * (aB[cf][j] + vg2b[c]) + xs[j] * vskw[c] + vskb[c];
            }

        #pragma unroll
        for (int j = 0; j < 4; ++j) {
            float part = yv[0][j] + yv[1][j] + yv[2][j] + yv[3][j];
            #pragma unroll
            for (int off = 1; off < 16; off <<= 1) part += __shfl_xor(part, off);
            const float mean = part * (1.f / 64.f);
            float vp = 0.f;
            #pragma unroll
            for (int cf = 0; cf < 4; ++cf) { float d = yv[cf][j] - mean; vp += d * d; }
            #pragma unroll
            for (int off = 1; off < 16; off <<= 1) vp += __shfl_xor(vp, off);
            const float inv = rsqrtf(vp * (1.f / 64.f) + LN_EPS);
            #pragma unroll
            for (int cf = 0; cf < 4; ++cf) {
                const int c = cf*16 + lr;
                slab[(4*lg + j)*72 + c] = f2bf((yv[cf][j] - mean) * inv * vlng[c] + vlnb[c]);
            }
        }
        __builtin_amdgcn_sched_barrier(0);

        {
            const size_t base = (size_t)(m0 + w*16 + lr) * FDIM + (size_t)f * 64 + lg*16;
            short8v s0 = *(const short8v*)&slab[lr*72 + lg*16];
            short8v s1 = *(const short8v*)&slab[lr*72 + lg*16 + 8];
            *(short8v*)&stacked[base]     = s0;
            *(short8v*)&stacked[base + 8] = s1;
        }
    }
}

// =====================================================================
// Pack w_w1 / w_skw into bf16 WcatT[160][FDIM]
// =====================================================================
__global__ void wprep_kernel(
    const float* __restrict__ w_w1, const float* __restrict__ w_skw,
    unsigned short* __restrict__ WcatT)
{
    const int c = blockIdx.y;
    const int k = blockIdx.x * 256 + threadIdx.x;
    if (k >= FDIM) return;
    float v = 0.f;
    if (c < 64)       v = w_w1[(size_t)k * 64 + c];
    else if (c < 145) v = w_skw[(size_t)k * 81 + (c - 64)];
    WcatT[(size_t)c * FDIM + k] = f2bf(v);
}

// =====================================================================
// Split-K fused weight-head GEMM (MFMA, LDS-free), MR=2, KS=6
// =====================================================================
__global__ __launch_bounds__(64) void wgemm_kernel(
    const __hip_bfloat16* __restrict__ stacked,
    const unsigned short* __restrict__ WcatT,
    float* __restrict__ partial, int mc)
{
    const int m0 = blockIdx.x * 32;
    const int ks = blockIdx.y;
    const int l  = threadIdx.x;
    const int lr = l & 15, lg = l >> 4;

    f32x4 acc[2][10];
    #pragma unroll
    for (int h = 0; h < 2; ++h)
        #pragma unroll
        for (int n = 0; n < 10; ++n) acc[h][n] = (f32x4){0.f, 0.f, 0.f, 0.f};

    const size_t a0r = (size_t)(m0 + lr) * FDIM;
    const size_t a1r = (size_t)(m0 + 16 + lr) * FDIM;
    const int k0base = ks * KSL;
    for (int kk = 0; kk < KSL; kk += 32) {
        const int k = k0base + kk + lg * 8;
        short8v a0 = *(const short8v*)(stacked + a0r + k);
        short8v a1 = *(const short8v*)(stacked + a1r + k);
        #pragma unroll
        for (int n = 0; n < 10; ++n) {
            short8v bf = *(const short8v*)(WcatT + (size_t)(n*16 + lr) * FDIM + k);
            acc[0][n] = __builtin_amdgcn_mfma_f32_16x16x32_bf16(a0, bf, acc[0][n], 0, 0, 0);
            acc[1][n] = __builtin_amdgcn_mfma_f32_16x16x32_bf16(a1, bf, acc[1][n], 0, 0, 0);
        }
    }
    #pragma unroll
    for (int h = 0; h < 2; ++h)
        #pragma unroll
        for (int n = 0; n < 10; ++n)
            #pragma unroll
            for (int j = 0; j < 4; ++j) {
                const int m = m0 + h*16 + lg*4 + j;
                partial[((size_t)ks * mc + m) * NW + n*16 + lr] = acc[h][n][j];
            }
}

// =====================================================================
// Weight-GRN tail v3 (verified round 12): reduce -> GRN -> softmax ->
// merged weighted feature-sum.  16 rows/block.
// =====================================================================
__global__ __launch_bounds__(256) void wtail_kernel(
    const float* __restrict__ partial,
    const __hip_bfloat16* __restrict__ stacked,
    const float* __restrict__ w_b1,  const float* __restrict__ w_skb,
    const float* __restrict__ w_w2,  const float* __restrict__ w_b2,
    const float* __restrict__ w_g1w, const float* __restrict__ w_g1b,
    const float* __restrict__ w_g2w, const float* __restrict__ w_g2b,
    const float* __restrict__ w_lng, const float* __restrict__ w_lnb,
    float* __restrict__ sel, __hip_bfloat16* __restrict__ selb, int mc)
{
    __shared__ float w2s[5184];
    __shared__ float g1s[6561];
    __shared__ float g2s[6561];
    __shared__ float sWh[16][64];
    __shared__ float sW2[16][96];
    __shared__ float wsh[16][81];

    const int t  = threadIdx.x;
    const int wv = t >> 6, l = t & 63;
    const int m0 = blockIdx.x * 16;
    const bool v1 = (l < 17);

    for (int e = t; e < 5184; e += 256) w2s[e] = w_w2[e];
    for (int e = t; e < 6561; e += 256) { g1s[e] = w_g1w[e]; g2s[e] = w_g2w[e]; }

    float s0[4], sk0[4], sk1[4];
    {
        const float b1v = w_b1[l], skb0 = w_skb[l], skb1 = v1 ? w_skb[64 + l] : 0.f;
        #pragma unroll
        for (int rr = 0; rr < 4; ++rr) { s0[rr] = b1v; sk0[rr] = skb0; sk1[rr] = skb1; }
    }
    #pragma unroll
    for (int ks = 0; ks < KS; ++ks) {
        #pragma unroll
        for (int rr = 0; rr < 4; ++rr) {
            const float* pr = partial + ((size_t)ks * mc + (m0 + wv*4 + rr)) * NW;
            s0[rr]  += pr[l];
            sk0[rr] += pr[64 + l];
            if (v1) sk1[rr] += pr[128 + l];
        }
    }
    #pragma unroll
    for (int rr = 0; rr < 4; ++rr) sWh[wv*4 + rr][l] = eluf_(s0[rr]);
    __syncthreads();

    float a0[4], a1[4];
    {
        const float b0 = w_b2[l], b1v = v1 ? w_b2[64 + l] : 0.f;
        #pragma unroll
        for (int rr = 0; rr < 4; ++rr) { a0[rr] = b0; a1[rr] = b1v; }
    }
    #pragma unroll 4
    for (int i = 0; i < 64; ++i) {
        const float wl = w2s[i*81 + l];
        const float wh = v1 ? w2s[i*81 + 64 + l] : 0.f;
        #pragma unroll
        for (int rr = 0; rr < 4; ++rr) {
            const float h = sWh[wv*4 + rr][i];
            a0[rr] += h * wl;
            a1[rr] += h * wh;
        }
    }
    #pragma unroll
    for (int rr = 0; rr < 4; ++rr) {
        sW2[wv*4 + rr][l] = a0[rr];
        if (v1) sW2[wv*4 + rr][64 + l] = a1[rr];
    }
    __syncthreads();

    float g10[4], g20[4], g11[4], g21[4];
    {
        const float c10 = w_g1b[l], c20 = w_g2b[l];
        const float c11 = v1 ? w_g1b[64 + l] : 0.f, c21 = v1 ? w_g2b[64 + l] : 0.f;
        #pragma unroll
        for (int rr = 0; rr < 4; ++rr) { g10[rr] = c10; g20[rr] = c20; g11[rr] = c11; g21[rr] = c21; }
    }
    #pragma unroll 3
    for (int i = 0; i < 81; ++i) {
        const float w1l = g1s[i*81 + l],            w2l = g2s[i*81 + l];
        const float w1h = v1 ? g1s[i*81 + 64 + l] : 0.f;
        const float w2h = v1 ? g2s[i*81 + 64 + l] : 0.f;
        #pragma unroll
        for (int rr = 0; rr < 4; ++rr) {
            const float h = sW2[wv*4 + rr][i];
            g10[rr] += h * w1l; g20[rr] += h * w2l;
            g11[rr] += h * w1h; g21[rr] += h * w2h;
        }
    }

    #pragma unroll
    for (int rr = 0; rr < 4; ++rr) {
        float y0 = sigmoidf_(g10[rr]) * g20[rr] + sk0[rr];
        float y1 = v1 ? (sigmoidf_(g11[rr]) * g21[rr] + sk1[rr]) : 0.f;

        float s = y0 + (v1 ? y1 : 0.f);
        #pragma unroll
        for (int off = 32; off; off >>= 1) s += __shfl_xor(s, off);
        const float mean = s / 81.f;
        float d0 = y0 - mean, d1 = v1 ? (y1 - mean) : 0.f;
        float vs = d0*d0 + (v1 ? d1*d1 : 0.f);
        #pragma unroll
        for (int off = 32; off; off >>= 1) vs += __shfl_xor(vs, off);
        const float inv = rsqrtf(vs / 81.f + LN_EPS);
        float wn0 = d0 * inv * w_lng[l] + w_lnb[l];
        float wn1 = v1 ? (d1 * inv * w_lng[64 + l] + w_lnb[64 + l]) : -1e30f;

        float mx = fmaxf(wn0, wn1);
        #pragma unroll
        for (int off = 32; off; off >>= 1) mx = fmaxf(mx, __shfl_xor(mx, off));
        float e0 = __expf(wn0 - mx), e1 = v1 ? __expf(wn1 - mx) : 0.f;
        float es = e0 + e1;
        #pragma unroll
        for (int off = 32; off; off >>= 1) es += __shfl_xor(es, off);
        const float r = __builtin_amdgcn_rcpf(es);
        wsh[wv*4 + rr][l] = e0 * r;
        if (v1) wsh[wv*4 + rr][64 + l] = e1 * r;
    }
    __syncthreads();

    {
        const int rr2 = t >> 4;
        const int d0 = (t & 15) * 4;
        const size_t mrow = (size_t)(m0 + rr2);
        float acc0 = 0.f, acc1f = 0.f, acc2 = 0.f, acc3 = 0.f;
        for (int f = 0; f < 81; ++f) {
            const float wv81 = wsh[rr2][f];
            ushort4 u = *(const ushort4*)&stacked[mrow * FDIM + f*64 + d0];
            acc0 += b2f(u.x) * wv81;
            acc1f += b2f(u.y) * wv81;
            acc2 += b2f(u.z) * wv81;
            acc3 += b2f(u.w) * wv81;
        }
        float4 ov = {acc0, acc1f, acc2, acc3};
        *(float4*)&sel[mrow * 64 + d0] = ov;
        ushort4 ub;
        ub.x = f2bf(acc0); ub.y = f2bf(acc1f); ub.z = f2bf(acc2); ub.w = f2bf(acc3);
        *(ushort4*)&((unsigned short*)selb)[mrow * 64 + d0] = ub;
    }
}

// =====================================================================
// xW = selb @ wih^T + (bih+bhh)
// =====================================================================
__global__ __launch_bounds__(256) void xw_kernel(
    const __hip_bfloat16* __restrict__ selb,
    const float* __restrict__ wih,
    const float* __restrict__ bih, const float* __restrict__ bhh,
    float* __restrict__ xW)
{
    const int m0 = blockIdx.x * 64;
    const int t = threadIdx.x;
    const int w = t >> 6, l = t & 63, lr = l & 15, lg = l >> 4;
    __shared__ __align__(16) unsigned short hA[64 * 72];
    __shared__ __align__(16) unsigned short Wt[256 * 72];
    __shared__ float vbs[256];

    vbs[t] = bih[t] + bhh[t];
    #pragma unroll
    for (int p = 0; p < 16; ++p) {
        int e = t + 256 * p; int r = e >> 6, d = e & 63;
        hA[r*72 + d] = *(const unsigned short*)&selb[(size_t)(m0 + r) * 64 + d];
    }
    #pragma unroll
    for (int p = 0; p < 64; ++p) {
        int e = t + 256 * p; int c = e >> 6, k = e & 63;
        Wt[c*72 + k] = f2bf(wih[c*64 + k]);
    }
    __syncthreads();

    f32x4 acc[4][4];
    #pragma unroll
    for (int rg = 0; rg < 4; ++rg)
        #pragma unroll
        for (int cf = 0; cf < 4; ++cf) acc[rg][cf] = (f32x4){0.f,0.f,0.f,0.f};
    #pragma unroll
    for (int ks = 0; ks < 2; ++ks) {
        short8v af[4];
        #pragma unroll
        for (int rg = 0; rg < 4; ++rg)
            af[rg] = *(const short8v*)&hA[(rg*16 + lr)*72 + ks*32 + lg*8];
        #pragma unroll
        for (int cf = 0; cf < 4; ++cf) {
            short8v bf = *(const short8v*)&Wt[(w*64 + cf*16 + lr)*72 + ks*32 + lg*8];
            #pragma unroll
            for (int rg = 0; rg < 4; ++rg)
                acc[rg][cf] = __builtin_amdgcn_mfma_f32_16x16x32_bf16(af[rg], bf, acc[rg][cf], 0, 0, 0);
        }
    }
    #pragma unroll
    for (int rg = 0; rg < 4; ++rg)
        #pragma unroll
        for (int cf = 0; cf < 4; ++cf)
            #pragma unroll
            for (int j = 0; j < 4; ++j) {
                int r = rg*16 + lg*4 + j, c = w*64 + cf*16 + lr;
                xW[(size_t)(m0 + r) * 256 + c] = acc[rg][cf][j] + vbs[c];
            }
}

// =====================================================================
// batch_kernel: per-batch mega fusion.  grid BB=512, 256 threads.
// LSTM -> pl GLU+LN -> QKV -> attention -> pa GLU+LN -> FF GRN -> head.
// All intermediates in LDS; output written directly to out[b][6].
// =====================================================================
__global__ __launch_bounds__(256) void batch_kernel(
    const float* __restrict__ xW, const float* __restrict__ whh,
    const float* __restrict__ sel,
    const float* __restrict__ pg1w, const float* __restrict__ pg1b,
    const float* __restrict__ pg2w, const float* __restrict__ pg2b,
    const float* __restrict__ plng, const float* __restrict__ plnb,
    const float* __restrict__ wqkv, const float* __restrict__ bqkv,
    const float* __restrict__ wout, const float* __restrict__ bout,
    const float* __restrict__ ag1w, const float* __restrict__ ag1b,
    const float* __restrict__ ag2w, const float* __restrict__ ag2b,
    const float* __restrict__ alng, const float* __restrict__ alnb,
    const float* __restrict__ fw1, const float* __restrict__ fb1,
    const float* __restrict__ fw2, const float* __restrict__ fb2,
    const float* __restrict__ fg1w, const float* __restrict__ fg1b,
    const float* __restrict__ fg2w, const float* __restrict__ fg2b,
    const float* __restrict__ flng, const float* __restrict__ flnb,
    const float* __restrict__ fc1_w, const float* __restrict__ fc1_b,
    const float* __restrict__ fc2_w, const float* __restrict__ fc2_b,
    float* __restrict__ out)
{
    const int b  = blockIdx.x;
    const int m0 = b * TSEQ;            // 24 rows
    const int t  = threadIdx.x;
    const int w  = t >> 6, l = t & 63, lr = l & 15, lg = l >> 4;
    const int tr = t >> 4, tc = t & 15;

    __shared__ float tmp[32 * 68];                 // temporal f32 (reused as outln)
    __shared__ float enr[32 * 68];                 // enriched f32
    __shared__ __align__(16) unsigned short hA[32 * 72];
    __shared__ __align__(16) unsigned short hB[32 * 136];
    __shared__ __align__(16) unsigned char U[35840];
    __shared__ float sh[64], sg[256];
    __shared__ float vpg1b[64], vpg2b[64], vplg[64], vplb[64], vbq[192];
    __shared__ float vob[64], vag1b[64], vag2b[64], valg[64], valb[64];
    __shared__ float vf1b[128], vf2b[64], vfg1b[64], vfg2b[64], vflg[64], vflb[64];

    unsigned short* Wt0 = (unsigned short*)U;
    unsigned short* Wt1 = (unsigned short*)(U + 9216);
    float*          yA  = (float*)(U + 18432);     // [32][68] (8704 B)
    unsigned short* Wq  = (unsigned short*)U;      // [192][72] (27648 B)
    float* sq = (float*)U;                         // [4][24][16] 6144
    float* sk = (float*)(U + 6144);
    float* sv = (float*)(U + 12288);
    float* sp = (float*)(U + 18432);               // [4][24][24] 9216
    unsigned short* W1t = (unsigned short*)U;      // [128][72] 18432
    unsigned short* W2t = (unsigned short*)(U + 18432);   // [64][136] 17408

    // ---- stage biases ----
    if (t < 64) {
        vpg1b[t] = pg1b[t]; vpg2b[t] = pg2b[t]; vplg[t] = plng[t]; vplb[t] = plnb[t];
        vob[t] = bout[t]; vag1b[t] = ag1b[t]; vag2b[t] = ag2b[t];
        valg[t] = alng[t]; valb[t] = alnb[t];
        vf2b[t] = fb2[t]; vfg1b[t] = fg1b[t]; vfg2b[t] = fg2b[t];
        vflg[t] = flng[t]; vflb[t] = flnb[t];
    }
    if (t < 192) vbq[t] = bqkv[t];
    if (t < 128) vf1b[t] = fb1[t];
    // zero hA rows 24..31 (padding rows stay finite through all phases)
    for (int e = t; e < 8 * 72; e += 256) hA[24*72 + e] = 0;

    // ---- LSTM recurrence (thread t owns gate column t) ----
    float wreg[64];
    #pragma unroll
    for (int i = 0; i < 64; ++i) wreg[i] = whh[t*64 + i];
    if (t < 64) sh[t] = 0.f;
    float c_reg = 0.f;
    float xnext = xW[(size_t)m0 * 256 + t];
    __syncthreads();

    for (int tt = 0; tt < TSEQ; ++tt) {
        float acc = xnext;
        if (tt + 1 < TSEQ)
            xnext = xW[(size_t)(m0 + tt + 1) * 256 + t];
        #pragma unroll
        for (int i = 0; i < 64; ++i) acc += sh[i] * wreg[i];
        sg[t] = acc;
        __syncthreads();
        if (t < 64) {
            float gi = sg[t], gf = sg[64 + t], gg = sg[128 + t], go = sg[192 + t];
            c_reg = sigmoidf_(gf) * c_reg + sigmoidf_(gi) * ftanh_(gg);
            float hn = sigmoidf_(go) * ftanh_(c_reg);
            sh[t] = hn;
            hA[tt*72 + t] = f2bf(hn);
        }
        __syncthreads();
    }

    // ---- pl GLU: stage g1/g2 ----
    #pragma unroll
    for (int p = 0; p < 16; ++p) {
        int e = t + 256 * p; int k = e >> 6, c = e & 63;
        Wt0[c*72 + k] = f2bf(pg1w[k*64 + c]);
        Wt1[c*72 + k] = f2bf(pg2w[k*64 + c]);
    }
    __syncthreads();

    f32x4 aA[2], aB[2];
    #pragma unroll
    for (int rg = 0; rg < 2; ++rg) { aA[rg] = (f32x4){0.f,0.f,0.f,0.f}; aB[rg] = (f32x4){0.f,0.f,0.f,0.f}; }
    #pragma unroll
    for (int ks = 0; ks < 2; ++ks) {
        short8v b0f = *(const short8v*)&Wt0[(w*16 + lr)*72 + ks*32 + lg*8];
        short8v b1f = *(const short8v*)&Wt1[(w*16 + lr)*72 + ks*32 + lg*8];
        #pragma unroll
        for (int rg = 0; rg < 2; ++rg) {
            short8v af = *(const short8v*)&hA[(rg*16 + lr)*72 + ks*32 + lg*8];
            aA[rg] = __builtin_amdgcn_mfma_f32_16x16x32_bf16(af, b0f, aA[rg], 0, 0, 0);
            aB[rg] = __builtin_amdgcn_mfma_f32_16x16x32_bf16(af, b1f, aB[rg], 0, 0, 0);
        }
    }
    float yv[2][4];
    #pragma unroll
    for (int rg = 0; rg < 2; ++rg)
        #pragma unroll
        for (int j = 0; j < 4; ++j) {
            int r = rg*16 + lg*4 + j, c = w*16 + lr;
            size_t rrow = (size_t)(m0 + r); if (rrow >= MTOT) rrow = MTOT - 1;
            float sgv = sigmoidf_(aA[rg][j] + vpg1b[c]);
            yv[rg][j] = sgv * (aB[rg][j] + vpg2b[c]) + sel[rrow * 64 + c];
        }
    __syncthreads();   // Wt reads done -> yA may overlay

    #pragma unroll
    for (int rg = 0; rg < 2; ++rg)
        #pragma unroll
        for (int j = 0; j < 4; ++j) {
            int r = rg*16 + lg*4 + j, c = w*16 + lr;
            yA[r*68 + c] = yv[rg][j];
        }
    __syncthreads();

    // pl-LN -> temporal: tmp (f32) + hA (bf16)
    #pragma unroll
    for (int a = 0; a < 2; ++a) {
        const int r = tr + 16*a;
        float4 v4 = *(const float4*)&yA[r*68 + tc*4];
        float part = v4.x + v4.y + v4.z + v4.w;
        #pragma unroll
        for (int off = 1; off < 16; off <<= 1) part += __shfl_xor(part, off);
        const float mean = part * (1.f / 64.f);
        float d0 = v4.x - mean, d1 = v4.y - mean, d2 = v4.z - mean, d3 = v4.w - mean;
        float vp = d0*d0 + d1*d1 + d2*d2 + d3*d3;
        #pragma unroll
        for (int off = 1; off < 16; off <<= 1) vp += __shfl_xor(vp, off);
        const float inv = rsqrtf(vp * (1.f / 64.f) + LN_EPS);
        const int c0 = tc * 4;
        float4 ov;
        ov.x = d0 * inv * vplg[c0+0] + vplb[c0+0];
        ov.y = d1 * inv * vplg[c0+1] + vplb[c0+1];
        ov.z = d2 * inv * vplg[c0+2] + vplb[c0+2];
        ov.w = d3 * inv * vplg[c0+3] + vplb[c0+3];
        *(float4*)&tmp[r*68 + c0] = ov;
        ushort4 ob;
        ob.x = f2bf(ov.x); ob.y = f2bf(ov.y); ob.z = f2bf(ov.z); ob.w = f2bf(ov.w);
        *(ushort4*)&hA[r*72 + c0] = ob;
    }
    __syncthreads();   // yA dead; hA(temporal) ready

    // ---- QKV projection ----
    #pragma unroll
    for (int p = 0; p < 48; ++p) {
        int e = t + 256 * p; int c = e >> 6, k = e & 63;
        Wq[c*72 + k] = f2bf(wqkv[(size_t)k * 192 + c]);
    }
    __syncthreads();

    f32x4 accq[2][3];
    #pragma unroll
    for (int rg = 0; rg < 2; ++rg)
        #pragma unroll
        for (int cf = 0; cf < 3; ++cf) accq[rg][cf] = (f32x4){0.f,0.f,0.f,0.f};
    #pragma unroll
    for (int ks = 0; ks < 2; ++ks) {
        short8v af[2];
        #pragma unroll
        for (int rg = 0; rg < 2; ++rg)
            af[rg] = *(const short8v*)&hA[(rg*16 + lr)*72 + ks*32 + lg*8];
        #pragma unroll
        for (int cf = 0; cf < 3; ++cf) {
            short8v bf = *(const short8v*)&Wq[(w*48 + cf*16 + lr)*72 + ks*32 + lg*8];
            #pragma unroll
            for (int rg = 0; rg < 2; ++rg)
                accq[rg][cf] = __builtin_amdgcn_mfma_f32_16x16x32_bf16(af[rg], bf, accq[rg][cf], 0, 0, 0);
        }
    }
    __syncthreads();   // Wq reads done -> overlay with sq/sk/sv/sp

    #pragma unroll
    for (int rg = 0; rg < 2; ++rg)
        #pragma unroll
        for (int cf = 0; cf < 3; ++cf)
            #pragma unroll
            for (int j = 0; j < 4; ++j) {
                int r = rg*16 + lg*4 + j, c = w*48 + cf*16 + lr;
                if (r < TSEQ) {
                    float val = accq[rg][cf][j] + vbq[c];
                    int seg = c >> 6, hh = (c & 63) >> 4, dd = c & 15;
                    float* dst = (seg == 0) ? sq : (seg == 1 ? sk : sv);
                    dst[(hh*24 + r)*16 + dd] = val;
                }
            }
    __syncthreads();

    // ---- attention (wave w = head) ----
    #pragma unroll
    for (int p = 0; p < 9; ++p) {
        int e = l + 64 * p; int i = e / 24, j2 = e - i * 24;
        float s = 0.f;
        #pragma unroll
        for (int d = 0; d < 16; ++d) s += sq[(w*24 + i)*16 + d] * sk[(w*24 + j2)*16 + d];
        sp[(w*24 + i)*24 + j2] = s * 0.25f;
    }
    __syncthreads();
    if (l < 24) {
        float mx = -1e30f;
        for (int j = 0; j < 24; ++j) mx = fmaxf(mx, sp[(w*24 + l)*24 + j]);
        float s = 0.f;
        for (int j = 0; j < 24; ++j) { float e = __expf(sp[(w*24 + l)*24 + j] - mx); sp[(w*24 + l)*24 + j] = e; s += e; }
        float inv = __builtin_amdgcn_rcpf(s);
        for (int j = 0; j < 24; ++j) sp[(w*24 + l)*24 + j] *= inv;
    }
    __syncthreads();
    #pragma unroll
    for (int p = 0; p < 6; ++p) {
        int e = l + 64 * p; int ti = e >> 4, d = e & 15;
        float s = 0.f;
        #pragma unroll
        for (int j = 0; j < 24; ++j) s += sp[(w*24 + ti)*24 + j] * sv[(w*24 + j)*16 + d];
        hA[ti*72 + w*16 + d] = f2bf(s);   // ao bf16 rows 0..23
    }
    __syncthreads();

    // ---- pa mm1 ----
    #pragma unroll
    for (int p = 0; p < 16; ++p) {
        int e = t + 256 * p; int k = e >> 6, c = e & 63;
        Wt0[c*72 + k] = f2bf(wout[k*64 + c]);
    }
    __syncthreads();

    f32x4 acc1[2];
    #pragma unroll
    for (int rg = 0; rg < 2; ++rg) acc1[rg] = (f32x4){0.f,0.f,0.f,0.f};
    #pragma unroll
    for (int ks = 0; ks < 2; ++ks) {
        short8v bf = *(const short8v*)&Wt0[(w*16 + lr)*72 + ks*32 + lg*8];
        #pragma unroll
        for (int rg = 0; rg < 2; ++rg) {
            short8v af = *(const short8v*)&hA[(rg*16 + lr)*72 + ks*32 + lg*8];
            acc1[rg] = __builtin_amdgcn_mfma_f32_16x16x32_bf16(af, bf, acc1[rg], 0, 0, 0);
        }
    }
    #pragma unroll
    for (int p = 0; p < 16; ++p) {
        int e = t + 256 * p; int k = e >> 6, c = e & 63;
        Wt1[c*72 + k] = f2bf(ag1w[k*64 + c]);
    }
    __syncthreads();

    #pragma unroll
    for (int rg = 0; rg < 2; ++rg)
        #pragma unroll
        for (int j = 0; j < 4; ++j) {
            int r = rg*16 + lg*4 + j, c = w*16 + lr;
            hA[r*72 + c] = f2bf(acc1[rg][j] + vob[c]);
        }
    #pragma unroll
    for (int p = 0; p < 16; ++p) {
        int e = t + 256 * p; int k = e >> 6, c = e & 63;
        Wt0[c*72 + k] = f2bf(ag2w[k*64 + c]);
    }
    __syncthreads();

    // ---- pa GLU + residual(temporal LDS) ----
    #pragma unroll
    for (int rg = 0; rg < 2; ++rg) { aA[rg] = (f32x4){0.f,0.f,0.f,0.f}; aB[rg] = (f32x4){0.f,0.f,0.f,0.f}; }
    #pragma unroll
    for (int ks = 0; ks < 2; ++ks) {
        short8v b1f = *(const short8v*)&Wt1[(w*16 + lr)*72 + ks*32 + lg*8];
        short8v b2f = *(const short8v*)&Wt0[(w*16 + lr)*72 + ks*32 + lg*8];
        #pragma unroll
        for (int rg = 0; rg < 2; ++rg) {
            short8v af = *(const short8v*)&hA[(rg*16 + lr)*72 + ks*32 + lg*8];
            aA[rg] = __builtin_amdgcn_mfma_f32_16x16x32_bf16(af, b1f, aA[rg], 0, 0, 0);
            aB[rg] = __builtin_amdgcn_mfma_f32_16x16x32_bf16(af, b2f, aB[rg], 0, 0, 0);
        }
    }
    #pragma unroll
    for (int rg = 0; rg < 2; ++rg)
        #pragma unroll
        for (int j = 0; j < 4; ++j) {
            int r = rg*16 + lg*4 + j, c = w*16 + lr;
            float sgv = sigmoidf_(aA[rg][j] + vag1b[c]);
            yv[rg][j] = sgv * (aB[rg][j] + vag2b[c]) + tmp[r*68 + c];
        }
    __syncthreads();

    #pragma unroll
    for (int rg = 0; rg < 2; ++rg)
        #pragma unroll
        for (int j = 0; j < 4; ++j) {
            int r = rg*16 + lg*4 + j, c = w*16 + lr;
            yA[r*68 + c] = yv[rg][j];
        }
    __syncthreads();

    // pa-LN -> enriched (enr f32 + hA bf16)
    #pragma unroll
    for (int a = 0; a < 2; ++a) {
        const int r = tr + 16*a;
        float4 v4 = *(const float4*)&yA[r*68 + tc*4];
        float part = v4.x + v4.y + v4.z + v4.w;
        #pragma unroll
        for (int off = 1; off < 16; off <<= 1) part += __shfl_xor(part, off);
        const float mean = part * (1.f / 64.f);
        float d0 = v4.x - mean, d1 = v4.y - mean, d2 = v4.z - mean, d3 = v4.w - mean;
        float vp = d0*d0 + d1*d1 + d2*d2 + d3*d3;
        #pragma unroll
        for (int off = 1; off < 16; off <<= 1) vp += __shfl_xor(vp, off);
        const float inv = rsqrtf(vp * (1.f / 64.f) + LN_EPS);
        const int c0 = tc * 4;
        float4 ov;
        ov.x = d0 * inv * valg[c0+0] + valb[c0+0];
        ov.y = d1 * inv * valg[c0+1] + valb[c0+1];
        ov.z = d2 * inv * valg[c0+2] + valb[c0+2];
        ov.w = d3 * inv * valg[c0+3] + valb[c0+3];
        *(float4*)&enr[r*68 + c0] = ov;
        ushort4 ob;
        ob.x = f2bf(ov.x); ob.y = f2bf(ov.y); ob.z = f2bf(ov.z); ob.w = f2bf(ov.w);
        *(ushort4*)&hA[r*72 + c0] = ob;
    }
    __syncthreads();

    // ---- ff mm1 ----
    #pragma unroll
    for (int p = 0; p < 32; ++p) {
        int e = t + 256 * p; int k = e >> 7, c = e & 127;
        W1t[c*72 + k] = f2bf(fw1[(size_t)k * 128 + c]);
    }
    __syncthreads();

    f32x4 accf[2][2];
    #pragma unroll
    for (int rg = 0; rg < 2; ++rg)
        #pragma unroll
        for (int cf = 0; cf < 2; ++cf) accf[rg][cf] = (f32x4){0.f,0.f,0.f,0.f};
    #pragma unroll
    for (int ks = 0; ks < 2; ++ks) {
        short8v af[2];
        #pragma unroll
        for (int rg = 0; rg < 2; ++rg)
            af[rg] = *(const short8v*)&hA[(rg*16 + lr)*72 + ks*32 + lg*8];
        #pragma unroll
        for (int cf = 0; cf < 2; ++cf) {
            short8v bf = *(const short8v*)&W1t[(w*32 + cf*16 + lr)*72 + ks*32 + lg*8];
            #pragma unroll
            for (int rg = 0; rg < 2; ++rg)
                accf[rg][cf] = __builtin_amdgcn_mfma_f32_16x16x32_bf16(af[rg], bf, accf[rg][cf], 0, 0, 0);
        }
    }
    #pragma unroll
    for (int rg = 0; rg < 2; ++rg)
        #pragma unroll
        for (int cf = 0; cf < 2; ++cf)
            #pragma unroll
            for (int j = 0; j < 4; ++j) {
                int r = rg*16 + lg*4 + j, c = w*32 + cf*16 + lr;
                hB[r*136 + c] = f2bf(eluf_(accf[rg][cf][j] + vf1b[c]));
            }
    __syncthreads();

    // ---- ff mm2 + GLU weights ----
    #pragma unroll
    for (int p = 0; p < 32; ++p) {
        int e = t + 256 * p; int k = e >> 6, c = e & 63;
        W2t[c*136 + k] = f2bf(fw2[(size_t)k * 64 + c]);
    }
    #pragma unroll
    for (int p = 0; p < 16; ++p) {
        int e = t + 256 * p; int k = e >> 6, c = e & 63;
        Wt0[c*72 + k] = f2bf(fg1w[k*64 + c]);
        Wt1[c*72 + k] = f2bf(fg2w[k*64 + c]);
    }
    __syncthreads();

    f32x4 acc2[2];
    #pragma unroll
    for (int rg = 0; rg < 2; ++rg) acc2[rg] = (f32x4){0.f,0.f,0.f,0.f};
    #pragma unroll
    for (int ks = 0; ks < 4; ++ks) {
        short8v bf = *(const short8v*)&W2t[(w*16 + lr)*136 + ks*32 + lg*8];
        #pragma unroll
        for (int rg = 0; rg < 2; ++rg) {
            short8v af = *(const short8v*)&hB[(rg*16 + lr)*136 + ks*32 + lg*8];
            acc2[rg] = __builtin_amdgcn_mfma_f32_16x16x32_bf16(af, bf, acc2[rg], 0, 0, 0);
        }
    }
    #pragma unroll
    for (int rg = 0; rg < 2; ++rg)
        #pragma unroll
        for (int j = 0; j < 4; ++j) {
            int r = rg*16 + lg*4 + j, c = w*16 + lr;
            hA[r*72 + c] = f2bf(acc2[rg][j] + vf2b[c]);
        }
    __syncthreads();

    // ---- ff GLU + residual(enriched) ----
    #pragma unroll
    for (int rg = 0; rg < 2; ++rg) { aA[rg] = (f32x4){0.f,0.f,0.f,0.f}; aB[rg] = (f32x4){0.f,0.f,0.f,0.f}; }
    #pragma unroll
    for (int ks = 0; ks < 2; ++ks) {
        short8v b1f = *(const short8v*)&Wt0[(w*16 + lr)*72 + ks*32 + lg*8];
        short8v b2f = *(const short8v*)&Wt1[(w*16 + lr)*72 + ks*32 + lg*8];
        #pragma unroll
        for (int rg = 0; rg < 2; ++rg) {
            short8v af = *(const short8v*)&hA[(rg*16 + lr)*72 + ks*32 + lg*8];
            aA[rg] = __builtin_amdgcn_mfma_f32_16x16x32_bf16(af, b1f, aA[rg], 0, 0, 0);
            aB[rg] = __builtin_amdgcn_mfma_f32_16x16x32_bf16(af, b2f, aB[rg], 0, 0, 0);
        }
    }
    #pragma unroll
    for (int rg = 0; rg < 2; ++rg)
        #pragma unroll
        for (int j = 0; j < 4; ++j) {
            int r = rg*16 + lg*4 + j, c = w*16 + lr;
            float sgv = sigmoidf_(aA[rg][j] + vfg1b[c]);
            yv[rg][j] = sgv * (aB[rg][j] + vfg2b[c]) + enr[r*68 + c];
        }
    __syncthreads();   // W2t reads done -> yA may overlay

    #pragma unroll
    for (int rg = 0; rg < 2; ++rg)
        #pragma unroll
        for (int j = 0; j < 4; ++j) {
            int r = rg*16 + lg*4 + j, c = w*16 + lr;
            yA[r*68 + c] = yv[rg][j];
        }
    __syncthreads();

    // ff-LN -> outln (tmp reused)
    #pragma unroll
    for (int a = 0; a < 2; ++a) {
        const int r = tr + 16*a;
        float4 v4 = *(const float4*)&yA[r*68 + tc*4];
        float part = v4.x + v4.y + v4.z + v4.w;
        #pragma unroll
        for (int off = 1; off < 16; off <<= 1) part += __shfl_xor(part, off);
        const float mean = part * (1.f / 64.f);
        float d0 = v4.x - mean, d1 = v4.y - mean, d2 = v4.z - mean, d3 = v4.w - mean;
        float vp = d0*d0 + d1*d1 + d2*d2 + d3*d3;
        #pragma unroll
        for (int off = 1; off < 16; off <<= 1) vp += __shfl_xor(vp, off);
        const float inv = rsqrtf(vp * (1.f / 64.f) + LN_EPS);
        const int c0 = tc * 4;
        float4 ov;
        ov.x = d0 * inv * vflg[c0+0] + vflb[c0+0];
        ov.y = d1 * inv * vflg[c0+1] + vflb[c0+1];
        ov.z = d2 * inv * vflg[c0+2] + vflb[c0+2];
        ov.w = d3 * inv * vflg[c0+3] + vflb[c0+3];
        *(float4*)&tmp[r*68 + c0] = ov;
    }
    __syncthreads();

    // ---- head: pool -> fc1+relu -> fc2 ----
    if (t < 64) {
        float s = 0.f;
        #pragma unroll
        for (int tt = 0; tt < TSEQ; ++tt) s += tmp[tt*68 + t];
        sh[t] = s * (1.f / 24.f);
    }
    __syncthreads();
    if (t < 64) {
        float a = fc1_b[t];
        for (int k = 0; k < 64; ++k) a += sh[k] * fc1_w[k*64 + t];
        float f1 = fmaxf(a, 0.f);
        #pragma unroll
        for (int j = 0; j < 6; ++j) {
            float p = f1 * fc2_w[t*6 + j];
            #pragma unroll
            for (int off = 32; off; off >>= 1) p += __shfl_xor(p, off);
            if (t == 0) out[b*6 + j] = p + fc2_b[j];
        }
    }
}

// =====================================================================
extern "C" void kernel_launch(void* const* d_in, const int* in_sizes, int n_in,
                              void* d_out, int out_size, void* d_ws, size_t ws_size,
                              hipStream_t stream)
{
    const float* x        = (const float*)d_in[0];
    const float* f_w1     = (const float*)d_in[1];
    const float* f_b1     = (const float*)d_in[2];
    const float* f_w2     = (const float*)d_in[3];
    const float* f_b2     = (const float*)d_in[4];
    const float* f_g1w    = (const float*)d_in[5];
    const float* f_g1b    = (const float*)d_in[6];
    const float* f_g2w    = (const float*)d_in[7];
    const float* f_g2b    = (const float*)d_in[8];
    const float* f_skw    = (const float*)d_in[9];
    const float* f_skb    = (const float*)d_in[10];
    const float* f_lng    = (const float*)d_in[11];
    const float* f_lnb    = (const float*)d_in[12];
    const float* w_w1     = (const float*)d_in[13];
    const float* w_b1     = (const float*)d_in[14];
    const float* w_w2     = (const float*)d_in[15];
    const float* w_b2     = (const float*)d_in[16];
    const float* w_g1w    = (const float*)d_in[17];
    const float* w_g1b    = (const float*)d_in[18];
    const float* w_g2w    = (const float*)d_in[19];
    const float* w_g2b    = (const float*)d_in[20];
    const float* w_skw    = (const float*)d_in[21];
    const float* w_skb    = (const float*)d_in[22];
    const float* w_lng    = (const float*)d_in[23];
    const float* w_lnb    = (const float*)d_in[24];
    const float* lstm_wih = (const float*)d_in[25];
    const float* lstm_whh = (const float*)d_in[26];
    const float* lstm_bih = (const float*)d_in[27];
    const float* lstm_bhh = (const float*)d_in[28];
    const float* pl_g1w   = (const float*)d_in[29];
    const float* pl_g1b   = (const float*)d_in[30];
    const float* pl_g2w   = (const float*)d_in[31];
    const float* pl_g2b   = (const float*)d_in[32];
    const float* pl_lng   = (const float*)d_in[33];
    const float* pl_lnb   = (const float*)d_in[34];
    const float* attn_in_w  = (const float*)d_in[35];
    const float* attn_in_b  = (const float*)d_in[36];
    const float* attn_out_w = (const float*)d_in[37];
    const float* attn_out_b = (const float*)d_in[38];
    const float* pa_g1w   = (const float*)d_in[39];
    const float* pa_g1b   = (const float*)d_in[40];
    const float* pa_g2w   = (const float*)d_in[41];
    const float* pa_g2b   = (const float*)d_in[42];
    const float* pa_lng   = (const float*)d_in[43];
    const float* pa_lnb   = (const float*)d_in[44];
    const float* ff_w1    = (const float*)d_in[45];
    const float* ff_b1    = (const float*)d_in[46];
    const float* ff_w2    = (const float*)d_in[47];
    const float* ff_b2    = (const float*)d_in[48];
    const float* ff_g1w   = (const float*)d_in[49];
    const float* ff_g1b   = (const float*)d_in[50];
    const float* ff_g2w   = (const float*)d_in[51];
    const float* ff_g2b   = (const float*)d_in[52];
    const float* ff_lng   = (const float*)d_in[53];
    const float* ff_lnb   = (const float*)d_in[54];
    const float* fc1_w    = (const float*)d_in[55];
    const float* fc1_b    = (const float*)d_in[56];
    const float* fc2_w    = (const float*)d_in[57];
    const float* fc2_b    = (const float*)d_in[58];

    float* ws = (float*)d_ws;

    // ---------------- layout (unchanged shell; fewer live buffers) -------
    size_t o = 0;
    const size_t o_S0   = o; o += (size_t)MTOT * 256;   // xW
    o += (size_t)MTOT * 64;                              // (unused)
    o += (size_t)MTOT * 64;
    o += (size_t)MTOT * 64;
    o += (size_t)MTOT * 64;
    o += (size_t)MTOT * 128;
    o += 16384;
    const size_t unionP2 = o;                            // 7,880,704 floats

    const size_t persist = (size_t)MTOT * 177;           // sel + selb + xT
    int mc = 0;
    {
        const int cands[4] = {12288, 6144, 3072, 1536};
        for (int ci = 0; ci < 4; ++ci) {
            const size_t c = (size_t)cands[ci];
            size_t overlay = c * FDIM / 2 + (size_t)KS * c * NW + c * 81
                           + (size_t)NW * FDIM / 2;
            size_t A = overlay > unionP2 ? overlay : unionP2;
            if ((A + persist) * sizeof(float) <= ws_size) { mc = cands[ci]; break; }
        }
        if (mc == 0) return;
    }
    const size_t ovl_partial = (size_t)mc * FDIM / 2;
    const size_t ovl_w81     = ovl_partial + (size_t)KS * mc * NW;
    const size_t ovl_wcat    = ovl_w81 + (size_t)mc * 81;
    const size_t ovl_end     = ovl_wcat + (size_t)NW * FDIM / 2;
    const size_t regA        = ovl_end > unionP2 ? ovl_end : unionP2;
    const size_t o_sel  = regA;
    const size_t o_selb = o_sel + (size_t)MTOT * 64;
    const size_t o_xt   = o_selb + (size_t)MTOT * 32;

    const dim3 blk(256);

    // 0) transpose x ; pack weight-head matrices
    xt_kernel<<<dim3(MTOT / 128), blk, 0, stream>>>(x, ws + o_xt);
    wprep_kernel<<<dim3((FDIM + 255) / 256, NW), blk, 0, stream>>>(
        w_w1, w_skw, (unsigned short*)(ws + ovl_wcat));

    // ---------------- phase 1: VSN + weight-GRN ----------
    for (int mb = 0; mb < MTOT; mb += mc) {
        __hip_bfloat16* chunk = (__hip_bfloat16*)ws;
        vsn_kernel<<<dim3((mc / 64) / NT, NF), blk, 0, stream>>>(
            ws + o_xt + mb, f_w1, f_b1, f_w2, f_b2, f_g1w, f_g1b,
            f_g2w, f_g2b, f_skw, f_skb, f_lng, f_lnb, chunk);
        wgemm_kernel<<<dim3(mc / 32, KS), dim3(64), 0, stream>>>(
            chunk, (const unsigned short*)(ws + ovl_wcat), ws + ovl_partial, mc);
        wtail_kernel<<<dim3(mc / 16), blk, 0, stream>>>(
            ws + ovl_partial, chunk, w_b1, w_skb, w_w2, w_b2, w_g1w, w_g1b,
            w_g2w, w_g2b, w_lng, w_lnb,
            ws + o_sel + (size_t)mb * 64,
            (__hip_bfloat16*)(ws + o_selb) + (size_t)mb * 64, mc);
    }

    // ---------------- phase 2: xW then per-batch mega kernel -------------
    xw_kernel<<<dim3(MTOT / 64), blk, 0, stream>>>(
        (const __hip_bfloat16*)(ws + o_selb), lstm_wih, lstm_bih, lstm_bhh, ws + o_S0);
    batch_kernel<<<dim3(BB), blk, 0, stream>>>(
        ws + o_S0, lstm_whh, ws + o_sel,
        pl_g1w, pl_g1b, pl_g2w, pl_g2b, pl_lng, pl_lnb,
        attn_in_w, attn_in_b, attn_out_w, attn_out_b,
        pa_g1w, pa_g1b, pa_g2w, pa_g2b, pa_lng, pa_lnb,
        ff_w1, ff_b1, ff_w2, ff_b2, ff_g1w, ff_g1b, ff_g2w, ff_g2b,
        ff_lng, ff_lnb, fc1_w, fc1_b, fc2_w, fc2_b, (float*)d_out);
}

// Round 14
// 350.199 us; speedup vs baseline: 1.0472x; 1.0472x over previous
//
#include <hip/hip_runtime.h>
#include <hip/hip_bf16.h>
#include <math.h>

// ---------------- problem constants ----------------
constexpr int BB   = 512;
constexpr int TSEQ = 24;
constexpr int NF   = 81;
constexpr int DD   = 64;
constexpr int MTOT = BB * TSEQ;      // 12288
constexpr int FDIM = NF * DD;        // 5184
constexpr int KS   = 6;              // split-K groups (5184/6 = 864)
constexpr int KSL  = 864;
constexpr int NW   = 160;
constexpr int NT   = 6;
constexpr float LN_EPS = 1e-5f;

typedef __attribute__((ext_vector_type(8))) short short8v;
typedef __attribute__((ext_vector_type(4))) float f32x4;

static __device__ __forceinline__ float sigmoidf_(float x) {
    return __builtin_amdgcn_rcpf(1.f + __expf(-x));
}
static __device__ __forceinline__ float eluf_(float x) {
    return x > 0.f ? x : (__expf(x) - 1.f);
}
static __device__ __forceinline__ float ftanh_(float x) {
    float e = __expf(2.f * x);
    return 1.f - 2.f * __builtin_amdgcn_rcpf(e + 1.f);
}
static __device__ __forceinline__ unsigned short f2bf(float x) {
    __hip_bfloat16 h = __float2bfloat16(x);
    return *reinterpret_cast<unsigned short*>(&h);
}
static __device__ __forceinline__ float b2f(unsigned short u) {
    __hip_bfloat16 h = *reinterpret_cast<__hip_bfloat16*>(&u);
    return __bfloat162float(h);
}

// =====================================================================
// x transpose: LDS-tiled. grid MTOT/128.
// =====================================================================
__global__ __launch_bounds__(256) void xt_kernel(
    const float* __restrict__ x, float* __restrict__ xT)
{
    __shared__ float tile[128 * 81];
    const int m0 = blockIdx.x * 128;
    const int t  = threadIdx.x;
    for (int e = t; e < 128 * 81; e += 256)
        tile[e] = x[(size_t)m0 * NF + e];
    __syncthreads();
    for (int e = t; e < 128 * 81; e += 256) {
        int f = e >> 7, r = e & 127;
        xT[(size_t)f * MTOT + m0 + r] = tile[r * 81 + f];
    }
}

// =====================================================================
// Kernel 1: VSN v6 (verified round 11/12)
// =====================================================================
__global__ __launch_bounds__(256) void vsn_kernel(
    const float* __restrict__ xT,
    const float* __restrict__ f_w1,  const float* __restrict__ f_b1,
    const float* __restrict__ f_w2,  const float* __restrict__ f_b2,
    const float* __restrict__ f_g1w, const float* __restrict__ f_g1b,
    const float* __restrict__ f_g2w, const float* __restrict__ f_g2b,
    const float* __restrict__ f_skw, const float* __restrict__ f_skb,
    const float* __restrict__ f_lng, const float* __restrict__ f_lnb,
    __hip_bfloat16* __restrict__ stacked)
{
    const int f  = blockIdx.y;
    const int t  = threadIdx.x;
    const int w  = t >> 6;
    const int l  = t & 63;
    const int lr = l & 15;
    const int lg = l >> 4;

    __shared__ __align__(16) unsigned short W2t[64 * 72];
    __shared__ __align__(16) unsigned short G1t[64 * 72];
    __shared__ __align__(16) unsigned short G2t[64 * 72];
    __shared__ __align__(16) unsigned short hS[4][16 * 72];
    __shared__ float vw1[64], vb1[64], vb2[64], vg1b[64], vg2b[64];
    __shared__ float vskw[64], vskb[64], vlng[64], vlnb[64];

    if (t < 64) {
        vw1[t]  = f_w1 [f*64 + t];  vb1[t]  = f_b1 [f*64 + t];
        vb2[t]  = f_b2 [f*64 + t];
        vg1b[t] = f_g1b[f*64 + t];  vg2b[t] = f_g2b[f*64 + t];
        vskw[t] = f_skw[f*64 + t];  vskb[t] = f_skb[f*64 + t];
        vlng[t] = f_lng[f*64 + t];  vlnb[t] = f_lnb[f*64 + t];
    }
    {
        const float* w2p = f_w2  + (size_t)f * 4096;
        const float* g1p = f_g1w + (size_t)f * 4096;
        const float* g2p = f_g2w + (size_t)f * 4096;
        #pragma unroll
        for (int p = 0; p < 16; ++p) {
            int e = t + 256 * p; int k = e >> 6, c = e & 63;
            W2t[c*72 + k] = f2bf(w2p[k*64 + c]);
            G1t[c*72 + k] = f2bf(g1p[k*64 + c]);
            G2t[c*72 + k] = f2bf(g2p[k*64 + c]);
        }
    }
    __syncthreads();

    unsigned short* slab = hS[w];

    for (int it = 0; it < NT; ++it) {
        const int m0 = (blockIdx.x * NT + it) * 64;
        const float xval = xT[(size_t)f * MTOT + m0 + w*16 + lr];

        short8v a0f, a1f;
        #pragma unroll
        for (int j = 0; j < 8; ++j) {
            const int d0 = lg*8 + j, d1 = 32 + lg*8 + j;
            a0f[j] = (short)f2bf(eluf_(xval * vw1[d0] + vb1[d0]));
            a1f[j] = (short)f2bf(eluf_(xval * vw1[d1] + vb1[d1]));
        }

        f32x4 acc1[4];
        #pragma unroll
        for (int cf = 0; cf < 4; ++cf) acc1[cf] = (f32x4){0.f,0.f,0.f,0.f};
        #pragma unroll
        for (int cf = 0; cf < 4; ++cf) {
            short8v b0 = *(const short8v*)&W2t[(cf*16 + lr)*72 + lg*8];
            short8v b1 = *(const short8v*)&W2t[(cf*16 + lr)*72 + 32 + lg*8];
            acc1[cf] = __builtin_amdgcn_mfma_f32_16x16x32_bf16(a0f, b0, acc1[cf], 0, 0, 0);
            acc1[cf] = __builtin_amdgcn_mfma_f32_16x16x32_bf16(a1f, b1, acc1[cf], 0, 0, 0);
        }

        #pragma unroll
        for (int cf = 0; cf < 4; ++cf)
            #pragma unroll
            for (int j = 0; j < 4; ++j) {
                const int c = cf*16 + lr;
                slab[(4*lg + j)*72 + c] = f2bf(acc1[cf][j] + vb2[c]);
            }
        __builtin_amdgcn_sched_barrier(0);

        short8v h0f = *(const short8v*)&slab[lr*72 + lg*8];
        short8v h1f = *(const short8v*)&slab[lr*72 + 32 + lg*8];

        f32x4 aA[4], aB[4];
        #pragma unroll
        for (int cf = 0; cf < 4; ++cf) { aA[cf] = (f32x4){0.f,0.f,0.f,0.f}; aB[cf] = (f32x4){0.f,0.f,0.f,0.f}; }
        #pragma unroll
        for (int cf = 0; cf < 4; ++cf) {
            short8v b10 = *(const short8v*)&G1t[(cf*16 + lr)*72 + lg*8];
            short8v b11 = *(const short8v*)&G1t[(cf*16 + lr)*72 + 32 + lg*8];
            short8v b20 = *(const short8v*)&G2t[(cf*16 + lr)*72 + lg*8];
            short8v b21 = *(const short8v*)&G2t[(cf*16 + lr)*72 + 32 + lg*8];
            aA[cf] = __builtin_amdgcn_mfma_f32_16x16x32_bf16(h0f, b10, aA[cf], 0, 0, 0);
            aA[cf] = __builtin_amdgcn_mfma_f32_16x16x32_bf16(h1f, b11, aA[cf], 0, 0, 0);
            aB[cf] = __builtin_amdgcn_mfma_f32_16x16x32_bf16(h0f, b20, aB[cf], 0, 0, 0);
            aB[cf] = __builtin_amdgcn_mfma_f32_16x16x32_bf16(h1f, b21, aB[cf], 0, 0, 0);
        }

        float xs[4];
        #pragma unroll
        for (int j = 0; j < 4; ++j) xs[j] = __shfl(xval, 4*lg + j, 64);
        float yv[4][4];
        #pragma unroll
        for (int cf = 0; cf < 4; ++cf)
            #pragma unroll
            for (int j = 0; j < 4; ++j) {
                const int c = cf*16 + lr;
                float sg = sigmoidf_(aA[cf][j] + vg1b[c]);
                yv[cf][j] = sg * (aB[cf][j] + vg2b[c]) + xs[j] * vskw[c] + vskb[c];
            }

        #pragma unroll
        for (int j = 0; j < 4; ++j) {
            float part = yv[0][j] + yv[1][j] + yv[2][j] + yv[3][j];
            #pragma unroll
            for (int off = 1; off < 16; off <<= 1) part += __shfl_xor(part, off);
            const float mean = part * (1.f / 64.f);
            float vp = 0.f;
            #pragma unroll
            for (int cf = 0; cf < 4; ++cf) { float d = yv[cf][j] - mean; vp += d * d; }
            #pragma unroll
            for (int off = 1; off < 16; off <<= 1) vp += __shfl_xor(vp, off);
            const float inv = rsqrtf(vp * (1.f / 64.f) + LN_EPS);
            #pragma unroll
            for (int cf = 0; cf < 4; ++cf) {
                const int c = cf*16 + lr;
                slab[(4*lg + j)*72 + c] = f2bf((yv[cf][j] - mean) * inv * vlng[c] + vlnb[c]);
            }
        }
        __builtin_amdgcn_sched_barrier(0);

        {
            const size_t base = (size_t)(m0 + w*16 + lr) * FDIM + (size_t)f * 64 + lg*16;
            short8v s0 = *(const short8v*)&slab[lr*72 + lg*16];
            short8v s1 = *(const short8v*)&slab[lr*72 + lg*16 + 8];
            *(short8v*)&stacked[base]     = s0;
            *(short8v*)&stacked[base + 8] = s1;
        }
    }
}

// =====================================================================
// Pack w_w1 / w_skw into bf16 WcatT[160][FDIM]
// =====================================================================
__global__ void wprep_kernel(
    const float* __restrict__ w_w1, const float* __restrict__ w_skw,
    unsigned short* __restrict__ WcatT)
{
    const int c = blockIdx.y;
    const int k = blockIdx.x * 256 + threadIdx.x;
    if (k >= FDIM) return;
    float v = 0.f;
    if (c < 64)       v = w_w1[(size_t)k * 64 + c];
    else if (c < 145) v = w_skw[(size_t)k * 81 + (c - 64)];
    WcatT[(size_t)c * FDIM + k] = f2bf(v);
}

// =====================================================================
// Split-K fused weight-head GEMM (MFMA, LDS-free), MR=2, KS=6
// =====================================================================
__global__ __launch_bounds__(64) void wgemm_kernel(
    const __hip_bfloat16* __restrict__ stacked,
    const unsigned short* __restrict__ WcatT,
    float* __restrict__ partial, int mc)
{
    const int m0 = blockIdx.x * 32;
    const int ks = blockIdx.y;
    const int l  = threadIdx.x;
    const int lr = l & 15, lg = l >> 4;

    f32x4 acc[2][10];
    #pragma unroll
    for (int h = 0; h < 2; ++h)
        #pragma unroll
        for (int n = 0; n < 10; ++n) acc[h][n] = (f32x4){0.f, 0.f, 0.f, 0.f};

    const size_t a0r = (size_t)(m0 + lr) * FDIM;
    const size_t a1r = (size_t)(m0 + 16 + lr) * FDIM;
    const int k0base = ks * KSL;
    for (int kk = 0; kk < KSL; kk += 32) {
        const int k = k0base + kk + lg * 8;
        short8v a0 = *(const short8v*)(stacked + a0r + k);
        short8v a1 = *(const short8v*)(stacked + a1r + k);
        #pragma unroll
        for (int n = 0; n < 10; ++n) {
            short8v bf = *(const short8v*)(WcatT + (size_t)(n*16 + lr) * FDIM + k);
            acc[0][n] = __builtin_amdgcn_mfma_f32_16x16x32_bf16(a0, bf, acc[0][n], 0, 0, 0);
            acc[1][n] = __builtin_amdgcn_mfma_f32_16x16x32_bf16(a1, bf, acc[1][n], 0, 0, 0);
        }
    }
    #pragma unroll
    for (int h = 0; h < 2; ++h)
        #pragma unroll
        for (int n = 0; n < 10; ++n)
            #pragma unroll
            for (int j = 0; j < 4; ++j) {
                const int m = m0 + h*16 + lg*4 + j;
                partial[((size_t)ks * mc + m) * NW + n*16 + lr] = acc[h][n][j];
            }
}

// =====================================================================
// Weight-GRN tail v3 (verified round 12)
// =====================================================================
__global__ __launch_bounds__(256) void wtail_kernel(
    const float* __restrict__ partial,
    const __hip_bfloat16* __restrict__ stacked,
    const float* __restrict__ w_b1,  const float* __restrict__ w_skb,
    const float* __restrict__ w_w2,  const float* __restrict__ w_b2,
    const float* __restrict__ w_g1w, const float* __restrict__ w_g1b,
    const float* __restrict__ w_g2w, const float* __restrict__ w_g2b,
    const float* __restrict__ w_lng, const float* __restrict__ w_lnb,
    float* __restrict__ sel, __hip_bfloat16* __restrict__ selb, int mc)
{
    __shared__ float w2s[5184];
    __shared__ float g1s[6561];
    __shared__ float g2s[6561];
    __shared__ float sWh[16][64];
    __shared__ float sW2[16][96];
    __shared__ float wsh[16][81];

    const int t  = threadIdx.x;
    const int wv = t >> 6, l = t & 63;
    const int m0 = blockIdx.x * 16;
    const bool v1 = (l < 17);

    for (int e = t; e < 5184; e += 256) w2s[e] = w_w2[e];
    for (int e = t; e < 6561; e += 256) { g1s[e] = w_g1w[e]; g2s[e] = w_g2w[e]; }

    float s0[4], sk0[4], sk1[4];
    {
        const float b1v = w_b1[l], skb0 = w_skb[l], skb1 = v1 ? w_skb[64 + l] : 0.f;
        #pragma unroll
        for (int rr = 0; rr < 4; ++rr) { s0[rr] = b1v; sk0[rr] = skb0; sk1[rr] = skb1; }
    }
    #pragma unroll
    for (int ks = 0; ks < KS; ++ks) {
        #pragma unroll
        for (int rr = 0; rr < 4; ++rr) {
            const float* pr = partial + ((size_t)ks * mc + (m0 + wv*4 + rr)) * NW;
            s0[rr]  += pr[l];
            sk0[rr] += pr[64 + l];
            if (v1) sk1[rr] += pr[128 + l];
        }
    }
    #pragma unroll
    for (int rr = 0; rr < 4; ++rr) sWh[wv*4 + rr][l] = eluf_(s0[rr]);
    __syncthreads();

    float a0[4], a1[4];
    {
        const float b0 = w_b2[l], b1v = v1 ? w_b2[64 + l] : 0.f;
        #pragma unroll
        for (int rr = 0; rr < 4; ++rr) { a0[rr] = b0; a1[rr] = b1v; }
    }
    #pragma unroll 4
    for (int i = 0; i < 64; ++i) {
        const float wl = w2s[i*81 + l];
        const float wh = v1 ? w2s[i*81 + 64 + l] : 0.f;
        #pragma unroll
        for (int rr = 0; rr < 4; ++rr) {
            const float h = sWh[wv*4 + rr][i];
            a0[rr] += h * wl;
            a1[rr] += h * wh;
        }
    }
    #pragma unroll
    for (int rr = 0; rr < 4; ++rr) {
        sW2[wv*4 + rr][l] = a0[rr];
        if (v1) sW2[wv*4 + rr][64 + l] = a1[rr];
    }
    __syncthreads();

    float g10[4], g20[4], g11[4], g21[4];
    {
        const float c10 = w_g1b[l], c20 = w_g2b[l];
        const float c11 = v1 ? w_g1b[64 + l] : 0.f, c21 = v1 ? w_g2b[64 + l] : 0.f;
        #pragma unroll
        for (int rr = 0; rr < 4; ++rr) { g10[rr] = c10; g20[rr] = c20; g11[rr] = c11; g21[rr] = c21; }
    }
    #pragma unroll 3
    for (int i = 0; i < 81; ++i) {
        const float w1l = g1s[i*81 + l],            w2l = g2s[i*81 + l];
        const float w1h = v1 ? g1s[i*81 + 64 + l] : 0.f;
        const float w2h = v1 ? g2s[i*81 + 64 + l] : 0.f;
        #pragma unroll
        for (int rr = 0; rr < 4; ++rr) {
            const float h = sW2[wv*4 + rr][i];
            g10[rr] += h * w1l; g20[rr] += h * w2l;
            g11[rr] += h * w1h; g21[rr] += h * w2h;
        }
    }

    #pragma unroll
    for (int rr = 0; rr < 4; ++rr) {
        float y0 = sigmoidf_(g10[rr]) * g20[rr] + sk0[rr];
        float y1 = v1 ? (sigmoidf_(g11[rr]) * g21[rr] + sk1[rr]) : 0.f;

        float s = y0 + (v1 ? y1 : 0.f);
        #pragma unroll
        for (int off = 32; off; off >>= 1) s += __shfl_xor(s, off);
        const float mean = s / 81.f;
        float d0 = y0 - mean, d1 = v1 ? (y1 - mean) : 0.f;
        float vs = d0*d0 + (v1 ? d1*d1 : 0.f);
        #pragma unroll
        for (int off = 32; off; off >>= 1) vs += __shfl_xor(vs, off);
        const float inv = rsqrtf(vs / 81.f + LN_EPS);
        float wn0 = d0 * inv * w_lng[l] + w_lnb[l];
        float wn1 = v1 ? (d1 * inv * w_lng[64 + l] + w_lnb[64 + l]) : -1e30f;

        float mx = fmaxf(wn0, wn1);
        #pragma unroll
        for (int off = 32; off; off >>= 1) mx = fmaxf(mx, __shfl_xor(mx, off));
        float e0 = __expf(wn0 - mx), e1 = v1 ? __expf(wn1 - mx) : 0.f;
        float es = e0 + e1;
        #pragma unroll
        for (int off = 32; off; off >>= 1) es += __shfl_xor(es, off);
        const float r = __builtin_amdgcn_rcpf(es);
        wsh[wv*4 + rr][l] = e0 * r;
        if (v1) wsh[wv*4 + rr][64 + l] = e1 * r;
    }
    __syncthreads();

    {
        const int rr2 = t >> 4;
        const int d0 = (t & 15) * 4;
        const size_t mrow = (size_t)(m0 + rr2);
        float acc0 = 0.f, acc1f = 0.f, acc2 = 0.f, acc3 = 0.f;
        for (int f = 0; f < 81; ++f) {
            const float wv81 = wsh[rr2][f];
            ushort4 u = *(const ushort4*)&stacked[mrow * FDIM + f*64 + d0];
            acc0 += b2f(u.x) * wv81;
            acc1f += b2f(u.y) * wv81;
            acc2 += b2f(u.z) * wv81;
            acc3 += b2f(u.w) * wv81;
        }
        float4 ov = {acc0, acc1f, acc2, acc3};
        *(float4*)&sel[mrow * 64 + d0] = ov;
        ushort4 ub;
        ub.x = f2bf(acc0); ub.y = f2bf(acc1f); ub.z = f2bf(acc2); ub.w = f2bf(acc3);
        *(ushort4*)&((unsigned short*)selb)[mrow * 64 + d0] = ub;
    }
}

// =====================================================================
// xW = selb @ wih^T + (bih+bhh)
// =====================================================================
__global__ __launch_bounds__(256) void xw_kernel(
    const __hip_bfloat16* __restrict__ selb,
    const float* __restrict__ wih,
    const float* __restrict__ bih, const float* __restrict__ bhh,
    float* __restrict__ xW)
{
    const int m0 = blockIdx.x * 64;
    const int t = threadIdx.x;
    const int w = t >> 6, l = t & 63, lr = l & 15, lg = l >> 4;
    __shared__ __align__(16) unsigned short hA[64 * 72];
    __shared__ __align__(16) unsigned short Wt[256 * 72];
    __shared__ float vbs[256];

    vbs[t] = bih[t] + bhh[t];
    #pragma unroll
    for (int p = 0; p < 16; ++p) {
        int e = t + 256 * p; int r = e >> 6, d = e & 63;
        hA[r*72 + d] = *(const unsigned short*)&selb[(size_t)(m0 + r) * 64 + d];
    }
    #pragma unroll
    for (int p = 0; p < 64; ++p) {
        int e = t + 256 * p; int c = e >> 6, k = e & 63;
        Wt[c*72 + k] = f2bf(wih[c*64 + k]);
    }
    __syncthreads();

    f32x4 acc[4][4];
    #pragma unroll
    for (int rg = 0; rg < 4; ++rg)
        #pragma unroll
        for (int cf = 0; cf < 4; ++cf) acc[rg][cf] = (f32x4){0.f,0.f,0.f,0.f};
    #pragma unroll
    for (int ks = 0; ks < 2; ++ks) {
        short8v af[4];
        #pragma unroll
        for (int rg = 0; rg < 4; ++rg)
            af[rg] = *(const short8v*)&hA[(rg*16 + lr)*72 + ks*32 + lg*8];
        #pragma unroll
        for (int cf = 0; cf < 4; ++cf) {
            short8v bf = *(const short8v*)&Wt[(w*64 + cf*16 + lr)*72 + ks*32 + lg*8];
            #pragma unroll
            for (int rg = 0; rg < 4; ++rg)
                acc[rg][cf] = __builtin_amdgcn_mfma_f32_16x16x32_bf16(af[rg], bf, acc[rg][cf], 0, 0, 0);
        }
    }
    #pragma unroll
    for (int rg = 0; rg < 4; ++rg)
        #pragma unroll
        for (int cf = 0; cf < 4; ++cf)
            #pragma unroll
            for (int j = 0; j < 4; ++j) {
                int r = rg*16 + lg*4 + j, c = w*64 + cf*16 + lr;
                xW[(size_t)(m0 + r) * 256 + c] = acc[rg][cf][j] + vbs[c];
            }
}

// =====================================================================
// batch_kernel v2: per-batch mega fusion, LDS-trimmed to ~50.7 KB
// (3 blocks/CU).  grid BB=512, 256 threads.
// =====================================================================
__global__ __launch_bounds__(256) void batch_kernel(
    const float* __restrict__ xW, const float* __restrict__ whh,
    const float* __restrict__ sel,
    const float* __restrict__ pg1w, const float* __restrict__ pg1b,
    const float* __restrict__ pg2w, const float* __restrict__ pg2b,
    const float* __restrict__ plng, const float* __restrict__ plnb,
    const float* __restrict__ wqkv, const float* __restrict__ bqkv,
    const float* __restrict__ wout, const float* __restrict__ bout,
    const float* __restrict__ ag1w, const float* __restrict__ ag1b,
    const float* __restrict__ ag2w, const float* __restrict__ ag2b,
    const float* __restrict__ alng, const float* __restrict__ alnb,
    const float* __restrict__ fw1, const float* __restrict__ fb1,
    const float* __restrict__ fw2, const float* __restrict__ fb2,
    const float* __restrict__ fg1w, const float* __restrict__ fg1b,
    const float* __restrict__ fg2w, const float* __restrict__ fg2b,
    const float* __restrict__ flng, const float* __restrict__ flnb,
    const float* __restrict__ fc1_w, const float* __restrict__ fc1_b,
    const float* __restrict__ fc2_w, const float* __restrict__ fc2_b,
    float* __restrict__ out)
{
    const int b  = blockIdx.x;
    const int m0 = b * TSEQ;            // 24 rows
    const int t  = threadIdx.x;
    const int w  = t >> 6, l = t & 63, lr = l & 15, lg = l >> 4;
    const int tr = t >> 4, tc = t & 15;

    __shared__ float tmpS[24 * 68];                // temporal f32 (reused as outln)
    __shared__ float enrS[24 * 68];                // enriched f32
    __shared__ __align__(16) unsigned short hA[32 * 72];
    __shared__ __align__(16) unsigned char U[27648];
    __shared__ float sh[64], sg[256];
    __shared__ float vpg1b[64], vpg2b[64], vplg[64], vplb[64];
    __shared__ float vob[64], vag1b[64], vag2b[64], valg[64], valb[64];
    __shared__ float vf1b[128], vf2b[64], vfg1b[64], vfg2b[64], vflg[64], vflb[64];

    unsigned short* Wt0 = (unsigned short*)U;
    unsigned short* Wt1 = (unsigned short*)(U + 9216);
    float*          yA  = (float*)(U + 18432);     // [32][68] (8704 B)
    unsigned short* Wq  = (unsigned short*)U;      // [192][72] (27648 B)
    float* sq = (float*)U;                         // [4][24][16] 6144
    float* sk = (float*)(U + 6144);
    float* sv = (float*)(U + 12288);
    float* sp = (float*)(U + 18432);               // [4][24][24] 9216
    unsigned short* W1t = (unsigned short*)U;      // [128][72] 18432
    unsigned short* W2t = (unsigned short*)U;      // [64][136] 17408 (ff2)
    unsigned short* hBs = (unsigned short*)(U + 18432);  // [32][136] 8704

    // ---- stage biases ----
    if (t < 64) {
        vpg1b[t] = pg1b[t]; vpg2b[t] = pg2b[t]; vplg[t] = plng[t]; vplb[t] = plnb[t];
        vob[t] = bout[t]; vag1b[t] = ag1b[t]; vag2b[t] = ag2b[t];
        valg[t] = alng[t]; valb[t] = alnb[t];
        vf2b[t] = fb2[t]; vfg1b[t] = fg1b[t]; vfg2b[t] = fg2b[t];
        vflg[t] = flng[t]; vflb[t] = flnb[t];
    }
    if (t < 128) vf1b[t] = fb1[t];
    // zero hA rows 24..31 (padding rows stay finite through all phases)
    for (int e = t; e < 8 * 72; e += 256) hA[24*72 + e] = 0;

    // ---- LSTM recurrence (thread t owns gate column t) ----
    float wreg[64];
    #pragma unroll
    for (int i = 0; i < 64; ++i) wreg[i] = whh[t*64 + i];
    if (t < 64) sh[t] = 0.f;
    float c_reg = 0.f;
    float xnext = xW[(size_t)m0 * 256 + t];
    __syncthreads();

    for (int tt = 0; tt < TSEQ; ++tt) {
        float acc = xnext;
        if (tt + 1 < TSEQ)
            xnext = xW[(size_t)(m0 + tt + 1) * 256 + t];
        #pragma unroll
        for (int i = 0; i < 64; ++i) acc += sh[i] * wreg[i];
        sg[t] = acc;
        __syncthreads();
        if (t < 64) {
            float gi = sg[t], gf = sg[64 + t], gg = sg[128 + t], go = sg[192 + t];
            c_reg = sigmoidf_(gf) * c_reg + sigmoidf_(gi) * ftanh_(gg);
            float hn = sigmoidf_(go) * ftanh_(c_reg);
            sh[t] = hn;
            hA[tt*72 + t] = f2bf(hn);
        }
        __syncthreads();
    }

    // ---- pl GLU: stage g1/g2 ----
    #pragma unroll
    for (int p = 0; p < 16; ++p) {
        int e = t + 256 * p; int k = e >> 6, c = e & 63;
        Wt0[c*72 + k] = f2bf(pg1w[k*64 + c]);
        Wt1[c*72 + k] = f2bf(pg2w[k*64 + c]);
    }
    __syncthreads();

    f32x4 aA[2], aB[2];
    #pragma unroll
    for (int rg = 0; rg < 2; ++rg) { aA[rg] = (f32x4){0.f,0.f,0.f,0.f}; aB[rg] = (f32x4){0.f,0.f,0.f,0.f}; }
    #pragma unroll
    for (int ks = 0; ks < 2; ++ks) {
        short8v b0f = *(const short8v*)&Wt0[(w*16 + lr)*72 + ks*32 + lg*8];
        short8v b1f = *(const short8v*)&Wt1[(w*16 + lr)*72 + ks*32 + lg*8];
        #pragma unroll
        for (int rg = 0; rg < 2; ++rg) {
            short8v af = *(const short8v*)&hA[(rg*16 + lr)*72 + ks*32 + lg*8];
            aA[rg] = __builtin_amdgcn_mfma_f32_16x16x32_bf16(af, b0f, aA[rg], 0, 0, 0);
            aB[rg] = __builtin_amdgcn_mfma_f32_16x16x32_bf16(af, b1f, aB[rg], 0, 0, 0);
        }
    }
    float yv[2][4];
    #pragma unroll
    for (int rg = 0; rg < 2; ++rg)
        #pragma unroll
        for (int j = 0; j < 4; ++j) {
            int r = rg*16 + lg*4 + j, c = w*16 + lr;
            size_t rrow = (size_t)(m0 + (r < TSEQ ? r : TSEQ - 1));
            float sgv = sigmoidf_(aA[rg][j] + vpg1b[c]);
            yv[rg][j] = sgv * (aB[rg][j] + vpg2b[c]) + sel[rrow * 64 + c];
        }
    __syncthreads();   // Wt reads done -> yA may overlay (yA disjoint anyway)

    #pragma unroll
    for (int rg = 0; rg < 2; ++rg)
        #pragma unroll
        for (int j = 0; j < 4; ++j) {
            int r = rg*16 + lg*4 + j, c = w*16 + lr;
            yA[r*68 + c] = yv[rg][j];
        }
    __syncthreads();

    // pl-LN -> temporal: tmpS (f32, rows<24) + hA (bf16, all rows)
    #pragma unroll
    for (int a = 0; a < 2; ++a) {
        const int r = tr + 16*a;
        float4 v4 = *(const float4*)&yA[r*68 + tc*4];
        float part = v4.x + v4.y + v4.z + v4.w;
        #pragma unroll
        for (int off = 1; off < 16; off <<= 1) part += __shfl_xor(part, off);
        const float mean = part * (1.f / 64.f);
        float d0 = v4.x - mean, d1 = v4.y - mean, d2 = v4.z - mean, d3 = v4.w - mean;
        float vp = d0*d0 + d1*d1 + d2*d2 + d3*d3;
        #pragma unroll
        for (int off = 1; off < 16; off <<= 1) vp += __shfl_xor(vp, off);
        const float inv = rsqrtf(vp * (1.f / 64.f) + LN_EPS);
        const int c0 = tc * 4;
        float4 ov;
        ov.x = d0 * inv * vplg[c0+0] + vplb[c0+0];
        ov.y = d1 * inv * vplg[c0+1] + vplb[c0+1];
        ov.z = d2 * inv * vplg[c0+2] + vplb[c0+2];
        ov.w = d3 * inv * vplg[c0+3] + vplb[c0+3];
        if (r < TSEQ) *(float4*)&tmpS[r*68 + c0] = ov;
        ushort4 ob;
        ob.x = f2bf(ov.x); ob.y = f2bf(ov.y); ob.z = f2bf(ov.z); ob.w = f2bf(ov.w);
        *(ushort4*)&hA[r*72 + c0] = ob;
    }
    __syncthreads();   // yA dead; hA(temporal) ready

    // ---- QKV projection ----
    #pragma unroll
    for (int p = 0; p < 48; ++p) {
        int e = t + 256 * p; int c = e >> 6, k = e & 63;
        Wq[c*72 + k] = f2bf(wqkv[(size_t)k * 192 + c]);
    }
    __syncthreads();

    f32x4 accq[2][3];
    #pragma unroll
    for (int rg = 0; rg < 2; ++rg)
        #pragma unroll
        for (int cf = 0; cf < 3; ++cf) accq[rg][cf] = (f32x4){0.f,0.f,0.f,0.f};
    #pragma unroll
    for (int ks = 0; ks < 2; ++ks) {
        short8v af[2];
        #pragma unroll
        for (int rg = 0; rg < 2; ++rg)
            af[rg] = *(const short8v*)&hA[(rg*16 + lr)*72 + ks*32 + lg*8];
        #pragma unroll
        for (int cf = 0; cf < 3; ++cf) {
            short8v bf = *(const short8v*)&Wq[(w*48 + cf*16 + lr)*72 + ks*32 + lg*8];
            #pragma unroll
            for (int rg = 0; rg < 2; ++rg)
                accq[rg][cf] = __builtin_amdgcn_mfma_f32_16x16x32_bf16(af[rg], bf, accq[rg][cf], 0, 0, 0);
        }
    }
    __syncthreads();   // Wq reads done -> overlay with sq/sk/sv/sp

    #pragma unroll
    for (int rg = 0; rg < 2; ++rg)
        #pragma unroll
        for (int cf = 0; cf < 3; ++cf)
            #pragma unroll
            for (int j = 0; j < 4; ++j) {
                int r = rg*16 + lg*4 + j, c = w*48 + cf*16 + lr;
                if (r < TSEQ) {
                    float val = accq[rg][cf][j] + bqkv[c];
                    int seg = c >> 6, hh = (c & 63) >> 4, dd = c & 15;
                    float* dst = (seg == 0) ? sq : (seg == 1 ? sk : sv);
                    dst[(hh*24 + r)*16 + dd] = val;
                }
            }
    __syncthreads();

    // ---- attention (wave w = head) ----
    #pragma unroll
    for (int p = 0; p < 9; ++p) {
        int e = l + 64 * p; int i = e / 24, j2 = e - i * 24;
        float s = 0.f;
        #pragma unroll
        for (int d = 0; d < 16; ++d) s += sq[(w*24 + i)*16 + d] * sk[(w*24 + j2)*16 + d];
        sp[(w*24 + i)*24 + j2] = s * 0.25f;
    }
    __syncthreads();
    if (l < 24) {
        float mx = -1e30f;
        for (int j = 0; j < 24; ++j) mx = fmaxf(mx, sp[(w*24 + l)*24 + j]);
        float s = 0.f;
        for (int j = 0; j < 24; ++j) { float e = __expf(sp[(w*24 + l)*24 + j] - mx); sp[(w*24 + l)*24 + j] = e; s += e; }
        float inv = __builtin_amdgcn_rcpf(s);
        for (int j = 0; j < 24; ++j) sp[(w*24 + l)*24 + j] *= inv;
    }
    __syncthreads();
    #pragma unroll
    for (int p = 0; p < 6; ++p) {
        int e = l + 64 * p; int ti = e >> 4, d = e & 15;
        float s = 0.f;
        #pragma unroll
        for (int j = 0; j < 24; ++j) s += sp[(w*24 + ti)*24 + j] * sv[(w*24 + j)*16 + d];
        hA[ti*72 + w*16 + d] = f2bf(s);   // ao bf16 rows 0..23
    }
    __syncthreads();

    // ---- pa mm1 ----
    #pragma unroll
    for (int p = 0; p < 16; ++p) {
        int e = t + 256 * p; int k = e >> 6, c = e & 63;
        Wt0[c*72 + k] = f2bf(wout[k*64 + c]);
    }
    __syncthreads();

    f32x4 acc1[2];
    #pragma unroll
    for (int rg = 0; rg < 2; ++rg) acc1[rg] = (f32x4){0.f,0.f,0.f,0.f};
    #pragma unroll
    for (int ks = 0; ks < 2; ++ks) {
        short8v bf = *(const short8v*)&Wt0[(w*16 + lr)*72 + ks*32 + lg*8];
        #pragma unroll
        for (int rg = 0; rg < 2; ++rg) {
            short8v af = *(const short8v*)&hA[(rg*16 + lr)*72 + ks*32 + lg*8];
            acc1[rg] = __builtin_amdgcn_mfma_f32_16x16x32_bf16(af, bf, acc1[rg], 0, 0, 0);
        }
    }
    #pragma unroll
    for (int p = 0; p < 16; ++p) {
        int e = t + 256 * p; int k = e >> 6, c = e & 63;
        Wt1[c*72 + k] = f2bf(ag1w[k*64 + c]);
    }
    __syncthreads();

    #pragma unroll
    for (int rg = 0; rg < 2; ++rg)
        #pragma unroll
        for (int j = 0; j < 4; ++j) {
            int r = rg*16 + lg*4 + j, c = w*16 + lr;
            hA[r*72 + c] = f2bf(acc1[rg][j] + vob[c]);
        }
    #pragma unroll
    for (int p = 0; p < 16; ++p) {
        int e = t + 256 * p; int k = e >> 6, c = e & 63;
        Wt0[c*72 + k] = f2bf(ag2w[k*64 + c]);
    }
    __syncthreads();

    // ---- pa GLU + residual(temporal tmpS) ----
    #pragma unroll
    for (int rg = 0; rg < 2; ++rg) { aA[rg] = (f32x4){0.f,0.f,0.f,0.f}; aB[rg] = (f32x4){0.f,0.f,0.f,0.f}; }
    #pragma unroll
    for (int ks = 0; ks < 2; ++ks) {
        short8v b1f = *(const short8v*)&Wt1[(w*16 + lr)*72 + ks*32 + lg*8];
        short8v b2f = *(const short8v*)&Wt0[(w*16 + lr)*72 + ks*32 + lg*8];
        #pragma unroll
        for (int rg = 0; rg < 2; ++rg) {
            short8v af = *(const short8v*)&hA[(rg*16 + lr)*72 + ks*32 + lg*8];
            aA[rg] = __builtin_amdgcn_mfma_f32_16x16x32_bf16(af, b1f, aA[rg], 0, 0, 0);
            aB[rg] = __builtin_amdgcn_mfma_f32_16x16x32_bf16(af, b2f, aB[rg], 0, 0, 0);
        }
    }
    #pragma unroll
    for (int rg = 0; rg < 2; ++rg)
        #pragma unroll
        for (int j = 0; j < 4; ++j) {
            int r = rg*16 + lg*4 + j, c = w*16 + lr;
            int rc = r < TSEQ ? r : TSEQ - 1;
            float sgv = sigmoidf_(aA[rg][j] + vag1b[c]);
            yv[rg][j] = sgv * (aB[rg][j] + vag2b[c]) + tmpS[rc*68 + c];
        }
    __syncthreads();

    #pragma unroll
    for (int rg = 0; rg < 2; ++rg)
        #pragma unroll
        for (int j = 0; j < 4; ++j) {
            int r = rg*16 + lg*4 + j, c = w*16 + lr;
            yA[r*68 + c] = yv[rg][j];
        }
    __syncthreads();

    // pa-LN -> enriched (enrS f32 rows<24 + hA bf16 all rows)
    #pragma unroll
    for (int a = 0; a < 2; ++a) {
        const int r = tr + 16*a;
        float4 v4 = *(const float4*)&yA[r*68 + tc*4];
        float part = v4.x + v4.y + v4.z + v4.w;
        #pragma unroll
        for (int off = 1; off < 16; off <<= 1) part += __shfl_xor(part, off);
        const float mean = part * (1.f / 64.f);
        float d0 = v4.x - mean, d1 = v4.y - mean, d2 = v4.z - mean, d3 = v4.w - mean;
        float vp = d0*d0 + d1*d1 + d2*d2 + d3*d3;
        #pragma unroll
        for (int off = 1; off < 16; off <<= 1) vp += __shfl_xor(vp, off);
        const float inv = rsqrtf(vp * (1.f / 64.f) + LN_EPS);
        const int c0 = tc * 4;
        float4 ov;
        ov.x = d0 * inv * valg[c0+0] + valb[c0+0];
        ov.y = d1 * inv * valg[c0+1] + valb[c0+1];
        ov.z = d2 * inv * valg[c0+2] + valb[c0+2];
        ov.w = d3 * inv * valg[c0+3] + valb[c0+3];
        if (r < TSEQ) *(float4*)&enrS[r*68 + c0] = ov;
        ushort4 ob;
        ob.x = f2bf(ov.x); ob.y = f2bf(ov.y); ob.z = f2bf(ov.z); ob.w = f2bf(ov.w);
        *(ushort4*)&hA[r*72 + c0] = ob;
    }
    __syncthreads();

    // ---- ff mm1 (W1t over full U front; hB at U+18432) ----
    #pragma unroll
    for (int p = 0; p < 32; ++p) {
        int e = t + 256 * p; int k = e >> 7, c = e & 127;
        W1t[c*72 + k] = f2bf(fw1[(size_t)k * 128 + c]);
    }
    __syncthreads();

    f32x4 accf[2][2];
    #pragma unroll
    for (int rg = 0; rg < 2; ++rg)
        #pragma unroll
        for (int cf = 0; cf < 2; ++cf) accf[rg][cf] = (f32x4){0.f,0.f,0.f,0.f};
    #pragma unroll
    for (int ks = 0; ks < 2; ++ks) {
        short8v af[2];
        #pragma unroll
        for (int rg = 0; rg < 2; ++rg)
            af[rg] = *(const short8v*)&hA[(rg*16 + lr)*72 + ks*32 + lg*8];
        #pragma unroll
        for (int cf = 0; cf < 2; ++cf) {
            short8v bf = *(const short8v*)&W1t[(w*32 + cf*16 + lr)*72 + ks*32 + lg*8];
            #pragma unroll
            for (int rg = 0; rg < 2; ++rg)
                accf[rg][cf] = __builtin_amdgcn_mfma_f32_16x16x32_bf16(af[rg], bf, accf[rg][cf], 0, 0, 0);
        }
    }
    __syncthreads();   // W1t reads done -> hBs region (disjoint) + W1t front dead

    #pragma unroll
    for (int rg = 0; rg < 2; ++rg)
        #pragma unroll
        for (int cf = 0; cf < 2; ++cf)
            #pragma unroll
            for (int j = 0; j < 4; ++j) {
                int r = rg*16 + lg*4 + j, c = w*32 + cf*16 + lr;
                hBs[r*136 + c] = f2bf(eluf_(accf[rg][cf][j] + vf1b[c]));
            }
    // stage W2t over dead W1t front (0..17408)
    #pragma unroll
    for (int p = 0; p < 32; ++p) {
        int e = t + 256 * p; int k = e >> 6, c = e & 63;
        W2t[c*136 + k] = f2bf(fw2[(size_t)k * 64 + c]);
    }
    __syncthreads();

    // ff mm2: h2 = h@W2+b2 (K=128) -> hA
    f32x4 acc2[2];
    #pragma unroll
    for (int rg = 0; rg < 2; ++rg) acc2[rg] = (f32x4){0.f,0.f,0.f,0.f};
    #pragma unroll
    for (int ks = 0; ks < 4; ++ks) {
        short8v bf = *(const short8v*)&W2t[(w*16 + lr)*136 + ks*32 + lg*8];
        #pragma unroll
        for (int rg = 0; rg < 2; ++rg) {
            short8v af = *(const short8v*)&hBs[(rg*16 + lr)*136 + ks*32 + lg*8];
            acc2[rg] = __builtin_amdgcn_mfma_f32_16x16x32_bf16(af, bf, acc2[rg], 0, 0, 0);
        }
    }
    #pragma unroll
    for (int rg = 0; rg < 2; ++rg)
        #pragma unroll
        for (int j = 0; j < 4; ++j) {
            int r = rg*16 + lg*4 + j, c = w*16 + lr;
            hA[r*72 + c] = f2bf(acc2[rg][j] + vf2b[c]);
        }
    __syncthreads();   // mm2 reads done; W2t + hBs dead

    // stage ff GLU weights over dead front
    #pragma unroll
    for (int p = 0; p < 16; ++p) {
        int e = t + 256 * p; int k = e >> 6, c = e & 63;
        Wt0[c*72 + k] = f2bf(fg1w[k*64 + c]);
        Wt1[c*72 + k] = f2bf(fg2w[k*64 + c]);
    }
    __syncthreads();

    // ---- ff GLU + residual(enriched enrS) ----
    #pragma unroll
    for (int rg = 0; rg < 2; ++rg) { aA[rg] = (f32x4){0.f,0.f,0.f,0.f}; aB[rg] = (f32x4){0.f,0.f,0.f,0.f}; }
    #pragma unroll
    for (int ks = 0; ks < 2; ++ks) {
        short8v b1f = *(const short8v*)&Wt0[(w*16 + lr)*72 + ks*32 + lg*8];
        short8v b2f = *(const short8v*)&Wt1[(w*16 + lr)*72 + ks*32 + lg*8];
        #pragma unroll
        for (int rg = 0; rg < 2; ++rg) {
            short8v af = *(const short8v*)&hA[(rg*16 + lr)*72 + ks*32 + lg*8];
            aA[rg] = __builtin_amdgcn_mfma_f32_16x16x32_bf16(af, b1f, aA[rg], 0, 0, 0);
            aB[rg] = __builtin_amdgcn_mfma_f32_16x16x32_bf16(af, b2f, aB[rg], 0, 0, 0);
        }
    }
    #pragma unroll
    for (int rg = 0; rg < 2; ++rg)
        #pragma unroll
        for (int j = 0; j < 4; ++j) {
            int r = rg*16 + lg*4 + j, c = w*16 + lr;
            int rc = r < TSEQ ? r : TSEQ - 1;
            float sgv = sigmoidf_(aA[rg][j] + vfg1b[c]);
            yv[rg][j] = sgv * (aB[rg][j] + vfg2b[c]) + enrS[rc*68 + c];
        }
    __syncthreads();

    #pragma unroll
    for (int rg = 0; rg < 2; ++rg)
        #pragma unroll
        for (int j = 0; j < 4; ++j) {
            int r = rg*16 + lg*4 + j, c = w*16 + lr;
            yA[r*68 + c] = yv[rg][j];
        }
    __syncthreads();

    // ff-LN -> outln (tmpS reused, rows<24)
    #pragma unroll
    for (int a = 0; a < 2; ++a) {
        const int r = tr + 16*a;
        float4 v4 = *(const float4*)&yA[r*68 + tc*4];
        float part = v4.x + v4.y + v4.z + v4.w;
        #pragma unroll
        for (int off = 1; off < 16; off <<= 1) part += __shfl_xor(part, off);
        const float mean = part * (1.f / 64.f);
        float d0 = v4.x - mean, d1 = v4.y - mean, d2 = v4.z - mean, d3 = v4.w - mean;
        float vp = d0*d0 + d1*d1 + d2*d2 + d3*d3;
        #pragma unroll
        for (int off = 1; off < 16; off <<= 1) vp += __shfl_xor(vp, off);
        const float inv = rsqrtf(vp * (1.f / 64.f) + LN_EPS);
        const int c0 = tc * 4;
        if (r < TSEQ) {
            float4 ov;
            ov.x = d0 * inv * vflg[c0+0] + vflb[c0+0];
            ov.y = d1 * inv * vflg[c0+1] + vflb[c0+1];
            ov.z = d2 * inv * vflg[c0+2] + vflb[c0+2];
            ov.w = d3 * inv * vflg[c0+3] + vflb[c0+3];
            *(float4*)&tmpS[r*68 + c0] = ov;
        }
    }
    __syncthreads();

    // ---- head: pool -> fc1+relu -> fc2 ----
    if (t < 64) {
        float s = 0.f;
        #pragma unroll
        for (int tt = 0; tt < TSEQ; ++tt) s += tmpS[tt*68 + t];
        sh[t] = s * (1.f / 24.f);
    }
    __syncthreads();
    if (t < 64) {
        float a = fc1_b[t];
        for (int k = 0; k < 64; ++k) a += sh[k] * fc1_w[k*64 + t];
        float f1 = fmaxf(a, 0.f);
        #pragma unroll
        for (int j = 0; j < 6; ++j) {
            float p = f1 * fc2_w[t*6 + j];
            #pragma unroll
            for (int off = 32; off; off >>= 1) p += __shfl_xor(p, off);
            if (t == 0) out[b*6 + j] = p + fc2_b[j];
        }
    }
}

// =====================================================================
extern "C" void kernel_launch(void* const* d_in, const int* in_sizes, int n_in,
                              void* d_out, int out_size, void* d_ws, size_t ws_size,
                              hipStream_t stream)
{
    const float* x        = (const float*)d_in[0];
    const float* f_w1     = (const float*)d_in[1];
    const float* f_b1     = (const float*)d_in[2];
    const float* f_w2     = (const float*)d_in[3];
    const float* f_b2     = (const float*)d_in[4];
    const float* f_g1w    = (const float*)d_in[5];
    const float* f_g1b    = (const float*)d_in[6];
    const float* f_g2w    = (const float*)d_in[7];
    const float* f_g2b    = (const float*)d_in[8];
    const float* f_skw    = (const float*)d_in[9];
    const float* f_skb    = (const float*)d_in[10];
    const float* f_lng    = (const float*)d_in[11];
    const float* f_lnb    = (const float*)d_in[12];
    const float* w_w1     = (const float*)d_in[13];
    const float* w_b1     = (const float*)d_in[14];
    const float* w_w2     = (const float*)d_in[15];
    const float* w_b2     = (const float*)d_in[16];
    const float* w_g1w    = (const float*)d_in[17];
    const float* w_g1b    = (const float*)d_in[18];
    const float* w_g2w    = (const float*)d_in[19];
    const float* w_g2b    = (const float*)d_in[20];
    const float* w_skw    = (const float*)d_in[21];
    const float* w_skb    = (const float*)d_in[22];
    const float* w_lng    = (const float*)d_in[23];
    const float* w_lnb    = (const float*)d_in[24];
    const float* lstm_wih = (const float*)d_in[25];
    const float* lstm_whh = (const float*)d_in[26];
    const float* lstm_bih = (const float*)d_in[27];
    const float* lstm_bhh = (const float*)d_in[28];
    const float* pl_g1w   = (const float*)d_in[29];
    const float* pl_g1b   = (const float*)d_in[30];
    const float* pl_g2w   = (const float*)d_in[31];
    const float* pl_g2b   = (const float*)d_in[32];
    const float* pl_lng   = (const float*)d_in[33];
    const float* pl_lnb   = (const float*)d_in[34];
    const float* attn_in_w  = (const float*)d_in[35];
    const float* attn_in_b  = (const float*)d_in[36];
    const float* attn_out_w = (const float*)d_in[37];
    const float* attn_out_b = (const float*)d_in[38];
    const float* pa_g1w   = (const float*)d_in[39];
    const float* pa_g1b   = (const float*)d_in[40];
    const float* pa_g2w   = (const float*)d_in[41];
    const float* pa_g2b   = (const float*)d_in[42];
    const float* pa_lng   = (const float*)d_in[43];
    const float* pa_lnb   = (const float*)d_in[44];
    const float* ff_w1    = (const float*)d_in[45];
    const float* ff_b1    = (const float*)d_in[46];
    const float* ff_w2    = (const float*)d_in[47];
    const float* ff_b2    = (const float*)d_in[48];
    const float* ff_g1w   = (const float*)d_in[49];
    const float* ff_g1b   = (const float*)d_in[50];
    const float* ff_g2w   = (const float*)d_in[51];
    const float* ff_g2b   = (const float*)d_in[52];
    const float* ff_lng   = (const float*)d_in[53];
    const float* ff_lnb   = (const float*)d_in[54];
    const float* fc1_w    = (const float*)d_in[55];
    const float* fc1_b    = (const float*)d_in[56];
    const float* fc2_w    = (const float*)d_in[57];
    const float* fc2_b    = (const float*)d_in[58];

    float* ws = (float*)d_ws;

    // ---------------- layout (unchanged shell) ----------------------------
    size_t o = 0;
    const size_t o_S0   = o; o += (size_t)MTOT * 256;   // xW
    o += (size_t)MTOT * 64;
    o += (size_t)MTOT * 64;
    o += (size_t)MTOT * 64;
    o += (size_t)MTOT * 64;
    o += (size_t)MTOT * 128;
    o += 16384;
    const size_t unionP2 = o;                            // 7,880,704 floats

    const size_t persist = (size_t)MTOT * 177;           // sel + selb + xT
    int mc = 0;
    {
        const int cands[4] = {12288, 6144, 3072, 1536};
        for (int ci = 0; ci < 4; ++ci) {
            const size_t c = (size_t)cands[ci];
            size_t overlay = c * FDIM / 2 + (size_t)KS * c * NW + c * 81
                           + (size_t)NW * FDIM / 2;
            size_t A = overlay > unionP2 ? overlay : unionP2;
            if ((A + persist) * sizeof(float) <= ws_size) { mc = cands[ci]; break; }
        }
        if (mc == 0) return;
    }
    const size_t ovl_partial = (size_t)mc * FDIM / 2;
    const size_t ovl_w81     = ovl_partial + (size_t)KS * mc * NW;
    const size_t ovl_wcat    = ovl_w81 + (size_t)mc * 81;
    const size_t ovl_end     = ovl_wcat + (size_t)NW * FDIM / 2;
    const size_t regA        = ovl_end > unionP2 ? ovl_end : unionP2;
    const size_t o_sel  = regA;
    const size_t o_selb = o_sel + (size_t)MTOT * 64;
    const size_t o_xt   = o_selb + (size_t)MTOT * 32;

    const dim3 blk(256);

    // 0) transpose x ; pack weight-head matrices
    xt_kernel<<<dim3(MTOT / 128), blk, 0, stream>>>(x, ws + o_xt);
    wprep_kernel<<<dim3((FDIM + 255) / 256, NW), blk, 0, stream>>>(
        w_w1, w_skw, (unsigned short*)(ws + ovl_wcat));

    // ---------------- phase 1: VSN + weight-GRN ----------
    for (int mb = 0; mb < MTOT; mb += mc) {
        __hip_bfloat16* chunk = (__hip_bfloat16*)ws;
        vsn_kernel<<<dim3((mc / 64) / NT, NF), blk, 0, stream>>>(
            ws + o_xt + mb, f_w1, f_b1, f_w2, f_b2, f_g1w, f_g1b,
            f_g2w, f_g2b, f_skw, f_skb, f_lng, f_lnb, chunk);
        wgemm_kernel<<<dim3(mc / 32, KS), dim3(64), 0, stream>>>(
            chunk, (const unsigned short*)(ws + ovl_wcat), ws + ovl_partial, mc);
        wtail_kernel<<<dim3(mc / 16), blk, 0, stream>>>(
            ws + ovl_partial, chunk, w_b1, w_skb, w_w2, w_b2, w_g1w, w_g1b,
            w_g2w, w_g2b, w_lng, w_lnb,
            ws + o_sel + (size_t)mb * 64,
            (__hip_bfloat16*)(ws + o_selb) + (size_t)mb * 64, mc);
    }

    // ---------------- phase 2: xW then per-batch mega kernel -------------
    xw_kernel<<<dim3(MTOT / 64), blk, 0, stream>>>(
        (const __hip_bfloat16*)(ws + o_selb), lstm_wih, lstm_bih, lstm_bhh, ws + o_S0);
    batch_kernel<<<dim3(BB), blk, 0, stream>>>(
        ws + o_S0, lstm_whh, ws + o_sel,
        pl_g1w, pl_g1b, pl_g2w, pl_g2b, pl_lng, pl_lnb,
        attn_in_w, attn_in_b, attn_out_w, attn_out_b,
        pa_g1w, pa_g1b, pa_g2w, pa_g2b, pa_lng, pa_lnb,
        ff_w1, ff_b1, ff_w2, ff_b2, ff_g1w, ff_g1b, ff_g2w, ff_g2b,
        ff_lng, ff_lnb, fc1_w, fc1_b, fc2_w, fc2_b, (float*)d_out);
}

// Round 15
// 293.945 us; speedup vs baseline: 1.2477x; 1.1914x over previous
//
#include <hip/hip_runtime.h>
#include <hip/hip_bf16.h>
#include <math.h>

// ---------------- problem constants ----------------
constexpr int BB   = 512;
constexpr int TSEQ = 24;
constexpr int NF   = 81;
constexpr int DD   = 64;
constexpr int MTOT = BB * TSEQ;      // 12288
constexpr int FDIM = NF * DD;        // 5184
constexpr int KS   = 6;              // split-K groups (5184/6 = 864)
constexpr int KSL  = 864;
constexpr int NW   = 160;
constexpr int NT   = 6;
constexpr float LN_EPS = 1e-5f;

// ---- bf16 weight arena offsets (ushort units) ----
constexpr size_t AV    = 0;          // vsn: [81][3][64][64] (c-major)
constexpr size_t AWIH  = 995328;     // lstm wih [256][64] (already [c][k])
constexpr size_t APL1  = 1011712;    // pl_g1w  [64][64] (c-major)
constexpr size_t APL2  = 1015808;    // pl_g2w
constexpr size_t AWQ   = 1019904;    // attn_in_w [192][64] (c-major)
constexpr size_t AWOUT = 1032192;    // attn_out_w [64][64]
constexpr size_t AAG1  = 1036288;    // pa_g1w
constexpr size_t AAG2  = 1040384;    // pa_g2w
constexpr size_t AFW1  = 1044480;    // ff_w1 [128][64] (c-major)
constexpr size_t AFW2  = 1052672;    // ff_w2 [64][128] (c-major)
constexpr size_t AFG1  = 1060864;    // ff_g1w
constexpr size_t AFG2  = 1064960;    // ff_g2w
constexpr size_t AW2S  = 1069056;    // w_w2 [64][81] natural
constexpr size_t AG1S  = 1074240;    // w_g1w [81][81] natural
constexpr size_t AG2S  = 1080801;    // w_g2w [81][81] natural
constexpr size_t ATOT  = 1087362;

typedef __attribute__((ext_vector_type(8))) short short8v;
typedef __attribute__((ext_vector_type(4))) float f32x4;

static __device__ __forceinline__ float sigmoidf_(float x) {
    return __builtin_amdgcn_rcpf(1.f + __expf(-x));
}
static __device__ __forceinline__ float eluf_(float x) {
    return x > 0.f ? x : (__expf(x) - 1.f);
}
static __device__ __forceinline__ float ftanh_(float x) {
    float e = __expf(2.f * x);
    return 1.f - 2.f * __builtin_amdgcn_rcpf(e + 1.f);
}
static __device__ __forceinline__ unsigned short f2bf(float x) {
    __hip_bfloat16 h = __float2bfloat16(x);
    return *reinterpret_cast<unsigned short*>(&h);
}
static __device__ __forceinline__ float b2f(unsigned short u) {
    __hip_bfloat16 h = *reinterpret_cast<__hip_bfloat16*>(&u);
    return __bfloat162float(h);
}

// =====================================================================
// x transpose: LDS-tiled. grid MTOT/128.
// =====================================================================
__global__ __launch_bounds__(256) void xt_kernel(
    const float* __restrict__ x, float* __restrict__ xT)
{
    __shared__ float tile[128 * 81];
    const int m0 = blockIdx.x * 128;
    const int t  = threadIdx.x;
    for (int e = t; e < 128 * 81; e += 256)
        tile[e] = x[(size_t)m0 * NF + e];
    __syncthreads();
    for (int e = t; e < 128 * 81; e += 256) {
        int f = e >> 7, r = e & 127;
        xT[(size_t)f * MTOT + m0 + r] = tile[r * 81 + f];
    }
}

// =====================================================================
// wprep2: pack ALL reused weights into the bf16 arena (pre-transposed).
// =====================================================================
__global__ void wprep2_kernel(
    const float* __restrict__ f_w2, const float* __restrict__ f_g1w,
    const float* __restrict__ f_g2w, const float* __restrict__ wih,
    const float* __restrict__ pg1w, const float* __restrict__ pg2w,
    const float* __restrict__ wqkv, const float* __restrict__ wout,
    const float* __restrict__ ag1w, const float* __restrict__ ag2w,
    const float* __restrict__ fw1, const float* __restrict__ fw2,
    const float* __restrict__ fg1w, const float* __restrict__ fg2w,
    const float* __restrict__ w_w2, const float* __restrict__ w_g1w,
    const float* __restrict__ w_g2w,
    unsigned short* __restrict__ A)
{
    size_t i = (size_t)blockIdx.x * 256 + threadIdx.x;
    if (i >= ATOT) return;
    float v;
    if (i < AWIH) {
        size_t f = i / 12288; int r = (int)(i % 12288); int mat = r >> 12; int e = r & 4095;
        int c = e >> 6, k = e & 63;
        const float* src = mat == 0 ? f_w2 : (mat == 1 ? f_g1w : f_g2w);
        v = src[f * 4096 + k * 64 + c];
    }
    else if (i < APL1) { v = wih[i - AWIH]; }
    else if (i < APL2) { int e = (int)(i - APL1); int c = e >> 6, k = e & 63; v = pg1w[k*64 + c]; }
    else if (i < AWQ)  { int e = (int)(i - APL2); int c = e >> 6, k = e & 63; v = pg2w[k*64 + c]; }
    else if (i < AWOUT){ int e = (int)(i - AWQ);  int c = e >> 6, k = e & 63; v = wqkv[k*192 + c]; }
    else if (i < AAG1) { int e = (int)(i - AWOUT);int c = e >> 6, k = e & 63; v = wout[k*64 + c]; }
    else if (i < AAG2) { int e = (int)(i - AAG1); int c = e >> 6, k = e & 63; v = ag1w[k*64 + c]; }
    else if (i < AFW1) { int e = (int)(i - AAG2); int c = e >> 6, k = e & 63; v = ag2w[k*64 + c]; }
    else if (i < AFW2) { int e = (int)(i - AFW1); int c = e >> 6, k = e & 63; v = fw1[k*128 + c]; }
    else if (i < AFG1) { int e = (int)(i - AFW2); int c = e >> 7, k = e & 127; v = fw2[k*64 + c]; }
    else if (i < AFG2) { int e = (int)(i - AFG1); int c = e >> 6, k = e & 63; v = fg1w[k*64 + c]; }
    else if (i < AW2S) { int e = (int)(i - AFG2); int c = e >> 6, k = e & 63; v = fg2w[k*64 + c]; }
    else if (i < AG1S) { v = w_w2[i - AW2S]; }
    else if (i < AG2S) { v = w_g1w[i - AG1S]; }
    else               { v = w_g2w[i - AG2S]; }
    A[i] = f2bf(v);
}

// =====================================================================
// Kernel 1: VSN v6 (verified) — arena-fed weight staging (no cvt)
// =====================================================================
__global__ __launch_bounds__(256) void vsn_kernel(
    const float* __restrict__ xT,
    const unsigned short* __restrict__ A,
    const float* __restrict__ f_w1,  const float* __restrict__ f_b1,
    const float* __restrict__ f_b2,
    const float* __restrict__ f_g1b, const float* __restrict__ f_g2b,
    const float* __restrict__ f_skw, const float* __restrict__ f_skb,
    const float* __restrict__ f_lng, const float* __restrict__ f_lnb,
    __hip_bfloat16* __restrict__ stacked)
{
    const int f  = blockIdx.y;
    const int t  = threadIdx.x;
    const int w  = t >> 6;
    const int l  = t & 63;
    const int lr = l & 15;
    const int lg = l >> 4;

    __shared__ __align__(16) unsigned short W2t[64 * 72];
    __shared__ __align__(16) unsigned short G1t[64 * 72];
    __shared__ __align__(16) unsigned short G2t[64 * 72];
    __shared__ __align__(16) unsigned short hS[4][16 * 72];
    __shared__ float vw1[64], vb1[64], vb2[64], vg1b[64], vg2b[64];
    __shared__ float vskw[64], vskb[64], vlng[64], vlnb[64];

    if (t < 64) {
        vw1[t]  = f_w1 [f*64 + t];  vb1[t]  = f_b1 [f*64 + t];
        vb2[t]  = f_b2 [f*64 + t];
        vg1b[t] = f_g1b[f*64 + t];  vg2b[t] = f_g2b[f*64 + t];
        vskw[t] = f_skw[f*64 + t];  vskb[t] = f_skb[f*64 + t];
        vlng[t] = f_lng[f*64 + t];  vlnb[t] = f_lnb[f*64 + t];
    }
    {
        const unsigned short* av = A + (size_t)f * 12288;
        const int c = t >> 2, k0 = (t & 3) * 16;
        *(short8v*)&W2t[c*72 + k0]     = *(const short8v*)&av[c*64 + k0];
        *(short8v*)&W2t[c*72 + k0 + 8] = *(const short8v*)&av[c*64 + k0 + 8];
        *(short8v*)&G1t[c*72 + k0]     = *(const short8v*)&av[4096 + c*64 + k0];
        *(short8v*)&G1t[c*72 + k0 + 8] = *(const short8v*)&av[4096 + c*64 + k0 + 8];
        *(short8v*)&G2t[c*72 + k0]     = *(const short8v*)&av[8192 + c*64 + k0];
        *(short8v*)&G2t[c*72 + k0 + 8] = *(const short8v*)&av[8192 + c*64 + k0 + 8];
    }
    __syncthreads();

    unsigned short* slab = hS[w];

    for (int it = 0; it < NT; ++it) {
        const int m0 = (blockIdx.x * NT + it) * 64;
        const float xval = xT[(size_t)f * MTOT + m0 + w*16 + lr];

        short8v a0f, a1f;
        #pragma unroll
        for (int j = 0; j < 8; ++j) {
            const int d0 = lg*8 + j, d1 = 32 + lg*8 + j;
            a0f[j] = (short)f2bf(eluf_(xval * vw1[d0] + vb1[d0]));
            a1f[j] = (short)f2bf(eluf_(xval * vw1[d1] + vb1[d1]));
        }

        f32x4 acc1[4];
        #pragma unroll
        for (int cf = 0; cf < 4; ++cf) acc1[cf] = (f32x4){0.f,0.f,0.f,0.f};
        #pragma unroll
        for (int cf = 0; cf < 4; ++cf) {
            short8v b0 = *(const short8v*)&W2t[(cf*16 + lr)*72 + lg*8];
            short8v b1 = *(const short8v*)&W2t[(cf*16 + lr)*72 + 32 + lg*8];
            acc1[cf] = __builtin_amdgcn_mfma_f32_16x16x32_bf16(a0f, b0, acc1[cf], 0, 0, 0);
            acc1[cf] = __builtin_amdgcn_mfma_f32_16x16x32_bf16(a1f, b1, acc1[cf], 0, 0, 0);
        }

        #pragma unroll
        for (int cf = 0; cf < 4; ++cf)
            #pragma unroll
            for (int j = 0; j < 4; ++j) {
                const int c = cf*16 + lr;
                slab[(4*lg + j)*72 + c] = f2bf(acc1[cf][j] + vb2[c]);
            }
        __builtin_amdgcn_sched_barrier(0);

        short8v h0f = *(const short8v*)&slab[lr*72 + lg*8];
        short8v h1f = *(const short8v*)&slab[lr*72 + 32 + lg*8];

        f32x4 aA[4], aB[4];
        #pragma unroll
        for (int cf = 0; cf < 4; ++cf) { aA[cf] = (f32x4){0.f,0.f,0.f,0.f}; aB[cf] = (f32x4){0.f,0.f,0.f,0.f}; }
        #pragma unroll
        for (int cf = 0; cf < 4; ++cf) {
            short8v b10 = *(const short8v*)&G1t[(cf*16 + lr)*72 + lg*8];
            short8v b11 = *(const short8v*)&G1t[(cf*16 + lr)*72 + 32 + lg*8];
            short8v b20 = *(const short8v*)&G2t[(cf*16 + lr)*72 + lg*8];
            short8v b21 = *(const short8v*)&G2t[(cf*16 + lr)*72 + 32 + lg*8];
            aA[cf] = __builtin_amdgcn_mfma_f32_16x16x32_bf16(h0f, b10, aA[cf], 0, 0, 0);
            aA[cf] = __builtin_amdgcn_mfma_f32_16x16x32_bf16(h1f, b11, aA[cf], 0, 0, 0);
            aB[cf] = __builtin_amdgcn_mfma_f32_16x16x32_bf16(h0f, b20, aB[cf], 0, 0, 0);
            aB[cf] = __builtin_amdgcn_mfma_f32_16x16x32_bf16(h1f, b21, aB[cf], 0, 0, 0);
        }

        float xs[4];
        #pragma unroll
        for (int j = 0; j < 4; ++j) xs[j] = __shfl(xval, 4*lg + j, 64);
        float yv[4][4];
        #pragma unroll
        for (int cf = 0; cf < 4; ++cf)
            #pragma unroll
            for (int j = 0; j < 4; ++j) {
                const int c = cf*16 + lr;
                float sg = sigmoidf_(aA[cf][j] + vg1b[c]);
                yv[cf][j] = sg * (aB[cf][j] + vg2b[c]) + xs[j] * vskw[c] + vskb[c];
            }

        #pragma unroll
        for (int j = 0; j < 4; ++j) {
            float part = yv[0][j] + yv[1][j] + yv[2][j] + yv[3][j];
            #pragma unroll
            for (int off = 1; off < 16; off <<= 1) part += __shfl_xor(part, off);
            const float mean = part * (1.f / 64.f);
            float vp = 0.f;
            #pragma unroll
            for (int cf = 0; cf < 4; ++cf) { float d = yv[cf][j] - mean; vp += d * d; }
            #pragma unroll
            for (int off = 1; off < 16; off <<= 1) vp += __shfl_xor(vp, off);
            const float inv = rsqrtf(vp * (1.f / 64.f) + LN_EPS);
            #pragma unroll
            for (int cf = 0; cf < 4; ++cf) {
                const int c = cf*16 + lr;
                slab[(4*lg + j)*72 + c] = f2bf((yv[cf][j] - mean) * inv * vlng[c] + vlnb[c]);
            }
        }
        __builtin_amdgcn_sched_barrier(0);

        {
            const size_t base = (size_t)(m0 + w*16 + lr) * FDIM + (size_t)f * 64 + lg*16;
            short8v s0 = *(const short8v*)&slab[lr*72 + lg*16];
            short8v s1 = *(const short8v*)&slab[lr*72 + lg*16 + 8];
            *(short8v*)&stacked[base]     = s0;
            *(short8v*)&stacked[base + 8] = s1;
        }
    }
}

// =====================================================================
// Pack w_w1 / w_skw into bf16 WcatT[160][FDIM]
// =====================================================================
__global__ void wprep_kernel(
    const float* __restrict__ w_w1, const float* __restrict__ w_skw,
    unsigned short* __restrict__ WcatT)
{
    const int c = blockIdx.y;
    const int k = blockIdx.x * 256 + threadIdx.x;
    if (k >= FDIM) return;
    float v = 0.f;
    if (c < 64)       v = w_w1[(size_t)k * 64 + c];
    else if (c < 145) v = w_skw[(size_t)k * 81 + (c - 64)];
    WcatT[(size_t)c * FDIM + k] = f2bf(v);
}

// =====================================================================
// Split-K fused weight-head GEMM (MFMA, LDS-free), MR=2, KS=6
// =====================================================================
__global__ __launch_bounds__(64) void wgemm_kernel(
    const __hip_bfloat16* __restrict__ stacked,
    const unsigned short* __restrict__ WcatT,
    float* __restrict__ partial, int mc)
{
    const int m0 = blockIdx.x * 32;
    const int ks = blockIdx.y;
    const int l  = threadIdx.x;
    const int lr = l & 15, lg = l >> 4;

    f32x4 acc[2][10];
    #pragma unroll
    for (int h = 0; h < 2; ++h)
        #pragma unroll
        for (int n = 0; n < 10; ++n) acc[h][n] = (f32x4){0.f, 0.f, 0.f, 0.f};

    const size_t a0r = (size_t)(m0 + lr) * FDIM;
    const size_t a1r = (size_t)(m0 + 16 + lr) * FDIM;
    const int k0base = ks * KSL;
    for (int kk = 0; kk < KSL; kk += 32) {
        const int k = k0base + kk + lg * 8;
        short8v a0 = *(const short8v*)(stacked + a0r + k);
        short8v a1 = *(const short8v*)(stacked + a1r + k);
        #pragma unroll
        for (int n = 0; n < 10; ++n) {
            short8v bf = *(const short8v*)(WcatT + (size_t)(n*16 + lr) * FDIM + k);
            acc[0][n] = __builtin_amdgcn_mfma_f32_16x16x32_bf16(a0, bf, acc[0][n], 0, 0, 0);
            acc[1][n] = __builtin_amdgcn_mfma_f32_16x16x32_bf16(a1, bf, acc[1][n], 0, 0, 0);
        }
    }
    #pragma unroll
    for (int h = 0; h < 2; ++h)
        #pragma unroll
        for (int n = 0; n < 10; ++n)
            #pragma unroll
            for (int j = 0; j < 4; ++j) {
                const int m = m0 + h*16 + lg*4 + j;
                partial[((size_t)ks * mc + m) * NW + n*16 + lr] = acc[h][n][j];
            }
}

// =====================================================================
// Weight-GRN tail v4: bf16 weight LDS (52 KB -> 3 blocks/CU)
// =====================================================================
__global__ __launch_bounds__(256) void wtail_kernel(
    const float* __restrict__ partial,
    const __hip_bfloat16* __restrict__ stacked,
    const unsigned short* __restrict__ A,
    const float* __restrict__ w_b1,  const float* __restrict__ w_skb,
    const float* __restrict__ w_b2,
    const float* __restrict__ w_g1b, const float* __restrict__ w_g2b,
    const float* __restrict__ w_lng, const float* __restrict__ w_lnb,
    float* __restrict__ sel, __hip_bfloat16* __restrict__ selb, int mc)
{
    __shared__ unsigned short w2h[5184];
    __shared__ unsigned short g1h[6561];
    __shared__ unsigned short g2h[6561];
    __shared__ float sWh[16][64];
    __shared__ float sW2[16][96];
    __shared__ float wsh[16][81];

    const int t  = threadIdx.x;
    const int wv = t >> 6, l = t & 63;
    const int m0 = blockIdx.x * 16;
    const bool v1 = (l < 17);

    for (int e = t; e < 5184; e += 256) w2h[e] = A[AW2S + e];
    for (int e = t; e < 6561; e += 256) { g1h[e] = A[AG1S + e]; g2h[e] = A[AG2S + e]; }

    float s0[4], sk0[4], sk1[4];
    {
        const float b1v = w_b1[l], skb0 = w_skb[l], skb1 = v1 ? w_skb[64 + l] : 0.f;
        #pragma unroll
        for (int rr = 0; rr < 4; ++rr) { s0[rr] = b1v; sk0[rr] = skb0; sk1[rr] = skb1; }
    }
    #pragma unroll
    for (int ks = 0; ks < KS; ++ks) {
        #pragma unroll
        for (int rr = 0; rr < 4; ++rr) {
            const float* pr = partial + ((size_t)ks * mc + (m0 + wv*4 + rr)) * NW;
            s0[rr]  += pr[l];
            sk0[rr] += pr[64 + l];
            if (v1) sk1[rr] += pr[128 + l];
        }
    }
    #pragma unroll
    for (int rr = 0; rr < 4; ++rr) sWh[wv*4 + rr][l] = eluf_(s0[rr]);
    __syncthreads();

    float a0[4], a1[4];
    {
        const float b0 = w_b2[l], b1v = v1 ? w_b2[64 + l] : 0.f;
        #pragma unroll
        for (int rr = 0; rr < 4; ++rr) { a0[rr] = b0; a1[rr] = b1v; }
    }
    #pragma unroll 4
    for (int i = 0; i < 64; ++i) {
        const float wl = b2f(w2h[i*81 + l]);
        const float wh = v1 ? b2f(w2h[i*81 + 64 + l]) : 0.f;
        #pragma unroll
        for (int rr = 0; rr < 4; ++rr) {
            const float h = sWh[wv*4 + rr][i];
            a0[rr] += h * wl;
            a1[rr] += h * wh;
        }
    }
    #pragma unroll
    for (int rr = 0; rr < 4; ++rr) {
        sW2[wv*4 + rr][l] = a0[rr];
        if (v1) sW2[wv*4 + rr][64 + l] = a1[rr];
    }
    __syncthreads();

    float g10[4], g20[4], g11[4], g21[4];
    {
        const float c10 = w_g1b[l], c20 = w_g2b[l];
        const float c11 = v1 ? w_g1b[64 + l] : 0.f, c21 = v1 ? w_g2b[64 + l] : 0.f;
        #pragma unroll
        for (int rr = 0; rr < 4; ++rr) { g10[rr] = c10; g20[rr] = c20; g11[rr] = c11; g21[rr] = c21; }
    }
    #pragma unroll 3
    for (int i = 0; i < 81; ++i) {
        const float w1l = b2f(g1h[i*81 + l]),        w2l = b2f(g2h[i*81 + l]);
        const float w1h = v1 ? b2f(g1h[i*81 + 64 + l]) : 0.f;
        const float w2h2 = v1 ? b2f(g2h[i*81 + 64 + l]) : 0.f;
        #pragma unroll
        for (int rr = 0; rr < 4; ++rr) {
            const float h = sW2[wv*4 + rr][i];
            g10[rr] += h * w1l; g20[rr] += h * w2l;
            g11[rr] += h * w1h; g21[rr] += h * w2h2;
        }
    }

    #pragma unroll
    for (int rr = 0; rr < 4; ++rr) {
        float y0 = sigmoidf_(g10[rr]) * g20[rr] + sk0[rr];
        float y1 = v1 ? (sigmoidf_(g11[rr]) * g21[rr] + sk1[rr]) : 0.f;

        float s = y0 + (v1 ? y1 : 0.f);
        #pragma unroll
        for (int off = 32; off; off >>= 1) s += __shfl_xor(s, off);
        const float mean = s / 81.f;
        float d0 = y0 - mean, d1 = v1 ? (y1 - mean) : 0.f;
        float vs = d0*d0 + (v1 ? d1*d1 : 0.f);
        #pragma unroll
        for (int off = 32; off; off >>= 1) vs += __shfl_xor(vs, off);
        const float inv = rsqrtf(vs / 81.f + LN_EPS);
        float wn0 = d0 * inv * w_lng[l] + w_lnb[l];
        float wn1 = v1 ? (d1 * inv * w_lng[64 + l] + w_lnb[64 + l]) : -1e30f;

        float mx = fmaxf(wn0, wn1);
        #pragma unroll
        for (int off = 32; off; off >>= 1) mx = fmaxf(mx, __shfl_xor(mx, off));
        float e0 = __expf(wn0 - mx), e1 = v1 ? __expf(wn1 - mx) : 0.f;
        float es = e0 + e1;
        #pragma unroll
        for (int off = 32; off; off >>= 1) es += __shfl_xor(es, off);
        const float r = __builtin_amdgcn_rcpf(es);
        wsh[wv*4 + rr][l] = e0 * r;
        if (v1) wsh[wv*4 + rr][64 + l] = e1 * r;
    }
    __syncthreads();

    {
        const int rr2 = t >> 4;
        const int d0 = (t & 15) * 4;
        const size_t mrow = (size_t)(m0 + rr2);
        float acc0 = 0.f, acc1f = 0.f, acc2 = 0.f, acc3 = 0.f;
        for (int f = 0; f < 81; ++f) {
            const float wv81 = wsh[rr2][f];
            ushort4 u = *(const ushort4*)&stacked[mrow * FDIM + f*64 + d0];
            acc0 += b2f(u.x) * wv81;
            acc1f += b2f(u.y) * wv81;
            acc2 += b2f(u.z) * wv81;
            acc3 += b2f(u.w) * wv81;
        }
        float4 ov = {acc0, acc1f, acc2, acc3};
        *(float4*)&sel[mrow * 64 + d0] = ov;
        ushort4 ub;
        ub.x = f2bf(acc0); ub.y = f2bf(acc1f); ub.z = f2bf(acc2); ub.w = f2bf(acc3);
        *(ushort4*)&((unsigned short*)selb)[mrow * 64 + d0] = ub;
    }
}

// =====================================================================
// xW = selb @ wih^T + (bih+bhh)   — arena-fed staging
// =====================================================================
__global__ __launch_bounds__(256) void xw_kernel(
    const __hip_bfloat16* __restrict__ selb,
    const unsigned short* __restrict__ A,
    const float* __restrict__ bih, const float* __restrict__ bhh,
    float* __restrict__ xW)
{
    const int m0 = blockIdx.x * 64;
    const int t = threadIdx.x;
    const int w = t >> 6, l = t & 63, lr = l & 15, lg = l >> 4;
    __shared__ __align__(16) unsigned short hA[64 * 72];
    __shared__ __align__(16) unsigned short Wt[256 * 72];
    __shared__ float vbs[256];

    vbs[t] = bih[t] + bhh[t];
    #pragma unroll
    for (int p = 0; p < 16; ++p) {
        int e = t + 256 * p; int r = e >> 6, d = e & 63;
        hA[r*72 + d] = *(const unsigned short*)&selb[(size_t)(m0 + r) * 64 + d];
    }
    {
        const int c = t;
        #pragma unroll
        for (int j = 0; j < 8; ++j)
            *(short8v*)&Wt[c*72 + j*8] = *(const short8v*)&A[AWIH + (size_t)c*64 + j*8];
    }
    __syncthreads();

    f32x4 acc[4][4];
    #pragma unroll
    for (int rg = 0; rg < 4; ++rg)
        #pragma unroll
        for (int cf = 0; cf < 4; ++cf) acc[rg][cf] = (f32x4){0.f,0.f,0.f,0.f};
    #pragma unroll
    for (int ks = 0; ks < 2; ++ks) {
        short8v af[4];
        #pragma unroll
        for (int rg = 0; rg < 4; ++rg)
            af[rg] = *(const short8v*)&hA[(rg*16 + lr)*72 + ks*32 + lg*8];
        #pragma unroll
        for (int cf = 0; cf < 4; ++cf) {
            short8v bf = *(const short8v*)&Wt[(w*64 + cf*16 + lr)*72 + ks*32 + lg*8];
            #pragma unroll
            for (int rg = 0; rg < 4; ++rg)
                acc[rg][cf] = __builtin_amdgcn_mfma_f32_16x16x32_bf16(af[rg], bf, acc[rg][cf], 0, 0, 0);
        }
    }
    #pragma unroll
    for (int rg = 0; rg < 4; ++rg)
        #pragma unroll
        for (int cf = 0; cf < 4; ++cf)
            #pragma unroll
            for (int j = 0; j < 4; ++j) {
                int r = rg*16 + lg*4 + j, c = w*64 + cf*16 + lr;
                xW[(size_t)(m0 + r) * 256 + c] = acc[rg][cf][j] + vbs[c];
            }
}

// =====================================================================
// batch_kernel v3: per-batch mega fusion, arena-fed (no cvt staging)
// =====================================================================
__global__ __launch_bounds__(256) void batch_kernel(
    const float* __restrict__ xW, const float* __restrict__ whh,
    const float* __restrict__ sel,
    const unsigned short* __restrict__ A,
    const float* __restrict__ pg1b, const float* __restrict__ pg2b,
    const float* __restrict__ plng, const float* __restrict__ plnb,
    const float* __restrict__ bqkv, const float* __restrict__ bout,
    const float* __restrict__ ag1b, const float* __restrict__ ag2b,
    const float* __restrict__ alng, const float* __restrict__ alnb,
    const float* __restrict__ fb1, const float* __restrict__ fb2,
    const float* __restrict__ fg1b, const float* __restrict__ fg2b,
    const float* __restrict__ flng, const float* __restrict__ flnb,
    const float* __restrict__ fc1_w, const float* __restrict__ fc1_b,
    const float* __restrict__ fc2_w, const float* __restrict__ fc2_b,
    float* __restrict__ out)
{
    const int b  = blockIdx.x;
    const int m0 = b * TSEQ;            // 24 rows
    const int t  = threadIdx.x;
    const int w  = t >> 6, l = t & 63, lr = l & 15, lg = l >> 4;
    const int tr = t >> 4, tc = t & 15;

    __shared__ float tmpS[24 * 68];
    __shared__ float enrS[24 * 68];
    __shared__ __align__(16) unsigned short hA[32 * 72];
    __shared__ __align__(16) unsigned char U[27648];
    __shared__ float sh[64], sg[256];
    __shared__ float vpg1b[64], vpg2b[64], vplg[64], vplb[64];
    __shared__ float vob[64], vag1b[64], vag2b[64], valg[64], valb[64];
    __shared__ float vf1b[128], vf2b[64], vfg1b[64], vfg2b[64], vflg[64], vflb[64];

    unsigned short* Wt0 = (unsigned short*)U;
    unsigned short* Wt1 = (unsigned short*)(U + 9216);
    float*          yA  = (float*)(U + 18432);
    unsigned short* Wq  = (unsigned short*)U;
    float* sq = (float*)U;
    float* sk = (float*)(U + 6144);
    float* sv = (float*)(U + 12288);
    float* sp = (float*)(U + 18432);
    unsigned short* W1t = (unsigned short*)U;
    unsigned short* W2t = (unsigned short*)U;
    unsigned short* hBs = (unsigned short*)(U + 18432);

    if (t < 64) {
        vpg1b[t] = pg1b[t]; vpg2b[t] = pg2b[t]; vplg[t] = plng[t]; vplb[t] = plnb[t];
        vob[t] = bout[t]; vag1b[t] = ag1b[t]; vag2b[t] = ag2b[t];
        valg[t] = alng[t]; valb[t] = alnb[t];
        vf2b[t] = fb2[t]; vfg1b[t] = fg1b[t]; vfg2b[t] = fg2b[t];
        vflg[t] = flng[t]; vflb[t] = flnb[t];
    }
    if (t < 128) vf1b[t] = fb1[t];
    for (int e = t; e < 8 * 72; e += 256) hA[24*72 + e] = 0;

    // ---- LSTM recurrence ----
    float wreg[64];
    #pragma unroll
    for (int i = 0; i < 64; ++i) wreg[i] = whh[t*64 + i];
    if (t < 64) sh[t] = 0.f;
    float c_reg = 0.f;
    float xnext = xW[(size_t)m0 * 256 + t];
    __syncthreads();

    for (int tt = 0; tt < TSEQ; ++tt) {
        float acc = xnext;
        if (tt + 1 < TSEQ)
            xnext = xW[(size_t)(m0 + tt + 1) * 256 + t];
        #pragma unroll
        for (int i = 0; i < 64; ++i) acc += sh[i] * wreg[i];
        sg[t] = acc;
        __syncthreads();
        if (t < 64) {
            float gi = sg[t], gf = sg[64 + t], gg = sg[128 + t], go = sg[192 + t];
            c_reg = sigmoidf_(gf) * c_reg + sigmoidf_(gi) * ftanh_(gg);
            float hn = sigmoidf_(go) * ftanh_(c_reg);
            sh[t] = hn;
            hA[tt*72 + t] = f2bf(hn);
        }
        __syncthreads();
    }

    // ---- pl GLU: stage g1/g2 from arena ----
    {
        const int c = t >> 2, k0 = (t & 3) * 16;
        *(short8v*)&Wt0[c*72+k0]   = *(const short8v*)&A[APL1 + c*64 + k0];
        *(short8v*)&Wt0[c*72+k0+8] = *(const short8v*)&A[APL1 + c*64 + k0 + 8];
        *(short8v*)&Wt1[c*72+k0]   = *(const short8v*)&A[APL2 + c*64 + k0];
        *(short8v*)&Wt1[c*72+k0+8] = *(const short8v*)&A[APL2 + c*64 + k0 + 8];
    }
    __syncthreads();

    f32x4 aA[2], aB[2];
    #pragma unroll
    for (int rg = 0; rg < 2; ++rg) { aA[rg] = (f32x4){0.f,0.f,0.f,0.f}; aB[rg] = (f32x4){0.f,0.f,0.f,0.f}; }
    #pragma unroll
    for (int ks = 0; ks < 2; ++ks) {
        short8v b0f = *(const short8v*)&Wt0[(w*16 + lr)*72 + ks*32 + lg*8];
        short8v b1f = *(const short8v*)&Wt1[(w*16 + lr)*72 + ks*32 + lg*8];
        #pragma unroll
        for (int rg = 0; rg < 2; ++rg) {
            short8v af = *(const short8v*)&hA[(rg*16 + lr)*72 + ks*32 + lg*8];
            aA[rg] = __builtin_amdgcn_mfma_f32_16x16x32_bf16(af, b0f, aA[rg], 0, 0, 0);
            aB[rg] = __builtin_amdgcn_mfma_f32_16x16x32_bf16(af, b1f, aB[rg], 0, 0, 0);
        }
    }
    float yv[2][4];
    #pragma unroll
    for (int rg = 0; rg < 2; ++rg)
        #pragma unroll
        for (int j = 0; j < 4; ++j) {
            int r = rg*16 + lg*4 + j, c = w*16 + lr;
            size_t rrow = (size_t)(m0 + (r < TSEQ ? r : TSEQ - 1));
            float sgv = sigmoidf_(aA[rg][j] + vpg1b[c]);
            yv[rg][j] = sgv * (aB[rg][j] + vpg2b[c]) + sel[rrow * 64 + c];
        }
    __syncthreads();

    #pragma unroll
    for (int rg = 0; rg < 2; ++rg)
        #pragma unroll
        for (int j = 0; j < 4; ++j) {
            int r = rg*16 + lg*4 + j, c = w*16 + lr;
            yA[r*68 + c] = yv[rg][j];
        }
    __syncthreads();

    // pl-LN -> temporal
    #pragma unroll
    for (int a = 0; a < 2; ++a) {
        const int r = tr + 16*a;
        float4 v4 = *(const float4*)&yA[r*68 + tc*4];
        float part = v4.x + v4.y + v4.z + v4.w;
        #pragma unroll
        for (int off = 1; off < 16; off <<= 1) part += __shfl_xor(part, off);
        const float mean = part * (1.f / 64.f);
        float d0 = v4.x - mean, d1 = v4.y - mean, d2 = v4.z - mean, d3 = v4.w - mean;
        float vp = d0*d0 + d1*d1 + d2*d2 + d3*d3;
        #pragma unroll
        for (int off = 1; off < 16; off <<= 1) vp += __shfl_xor(vp, off);
        const float inv = rsqrtf(vp * (1.f / 64.f) + LN_EPS);
        const int c0 = tc * 4;
        float4 ov;
        ov.x = d0 * inv * vplg[c0+0] + vplb[c0+0];
        ov.y = d1 * inv * vplg[c0+1] + vplb[c0+1];
        ov.z = d2 * inv * vplg[c0+2] + vplb[c0+2];
        ov.w = d3 * inv * vplg[c0+3] + vplb[c0+3];
        if (r < TSEQ) *(float4*)&tmpS[r*68 + c0] = ov;
        ushort4 ob;
        ob.x = f2bf(ov.x); ob.y = f2bf(ov.y); ob.z = f2bf(ov.z); ob.w = f2bf(ov.w);
        *(ushort4*)&hA[r*72 + c0] = ob;
    }
    __syncthreads();

    // ---- QKV projection ----
    if (t < 192) {
        #pragma unroll
        for (int j = 0; j < 8; ++j)
            *(short8v*)&Wq[t*72 + j*8] = *(const short8v*)&A[AWQ + (size_t)t*64 + j*8];
    }
    __syncthreads();

    f32x4 accq[2][3];
    #pragma unroll
    for (int rg = 0; rg < 2; ++rg)
        #pragma unroll
        for (int cf = 0; cf < 3; ++cf) accq[rg][cf] = (f32x4){0.f,0.f,0.f,0.f};
    #pragma unroll
    for (int ks = 0; ks < 2; ++ks) {
        short8v af[2];
        #pragma unroll
        for (int rg = 0; rg < 2; ++rg)
            af[rg] = *(const short8v*)&hA[(rg*16 + lr)*72 + ks*32 + lg*8];
        #pragma unroll
        for (int cf = 0; cf < 3; ++cf) {
            short8v bf = *(const short8v*)&Wq[(w*48 + cf*16 + lr)*72 + ks*32 + lg*8];
            #pragma unroll
            for (int rg = 0; rg < 2; ++rg)
                accq[rg][cf] = __builtin_amdgcn_mfma_f32_16x16x32_bf16(af[rg], bf, accq[rg][cf], 0, 0, 0);
        }
    }
    __syncthreads();

    #pragma unroll
    for (int rg = 0; rg < 2; ++rg)
        #pragma unroll
        for (int cf = 0; cf < 3; ++cf)
            #pragma unroll
            for (int j = 0; j < 4; ++j) {
                int r = rg*16 + lg*4 + j, c = w*48 + cf*16 + lr;
                if (r < TSEQ) {
                    float val = accq[rg][cf][j] + bqkv[c];
                    int seg = c >> 6, hh = (c & 63) >> 4, dd = c & 15;
                    float* dst = (seg == 0) ? sq : (seg == 1 ? sk : sv);
                    dst[(hh*24 + r)*16 + dd] = val;
                }
            }
    __syncthreads();

    // ---- attention (wave w = head) ----
    #pragma unroll
    for (int p = 0; p < 9; ++p) {
        int e = l + 64 * p; int i = e / 24, j2 = e - i * 24;
        float s = 0.f;
        #pragma unroll
        for (int d = 0; d < 16; ++d) s += sq[(w*24 + i)*16 + d] * sk[(w*24 + j2)*16 + d];
        sp[(w*24 + i)*24 + j2] = s * 0.25f;
    }
    __syncthreads();
    if (l < 24) {
        float mx = -1e30f;
        for (int j = 0; j < 24; ++j) mx = fmaxf(mx, sp[(w*24 + l)*24 + j]);
        float s = 0.f;
        for (int j = 0; j < 24; ++j) { float e = __expf(sp[(w*24 + l)*24 + j] - mx); sp[(w*24 + l)*24 + j] = e; s += e; }
        float inv = __builtin_amdgcn_rcpf(s);
        for (int j = 0; j < 24; ++j) sp[(w*24 + l)*24 + j] *= inv;
    }
    __syncthreads();
    #pragma unroll
    for (int p = 0; p < 6; ++p) {
        int e = l + 64 * p; int ti = e >> 4, d = e & 15;
        float s = 0.f;
        #pragma unroll
        for (int j = 0; j < 24; ++j) s += sp[(w*24 + ti)*24 + j] * sv[(w*24 + j)*16 + d];
        hA[ti*72 + w*16 + d] = f2bf(s);
    }
    __syncthreads();

    // ---- pa mm1 ----
    {
        const int c = t >> 2, k0 = (t & 3) * 16;
        *(short8v*)&Wt0[c*72+k0]   = *(const short8v*)&A[AWOUT + c*64 + k0];
        *(short8v*)&Wt0[c*72+k0+8] = *(const short8v*)&A[AWOUT + c*64 + k0 + 8];
    }
    __syncthreads();

    f32x4 acc1[2];
    #pragma unroll
    for (int rg = 0; rg < 2; ++rg) acc1[rg] = (f32x4){0.f,0.f,0.f,0.f};
    #pragma unroll
    for (int ks = 0; ks < 2; ++ks) {
        short8v bf = *(const short8v*)&Wt0[(w*16 + lr)*72 + ks*32 + lg*8];
        #pragma unroll
        for (int rg = 0; rg < 2; ++rg) {
            short8v af = *(const short8v*)&hA[(rg*16 + lr)*72 + ks*32 + lg*8];
            acc1[rg] = __builtin_amdgcn_mfma_f32_16x16x32_bf16(af, bf, acc1[rg], 0, 0, 0);
        }
    }
    {
        const int c = t >> 2, k0 = (t & 3) * 16;
        *(short8v*)&Wt1[c*72+k0]   = *(const short8v*)&A[AAG1 + c*64 + k0];
        *(short8v*)&Wt1[c*72+k0+8] = *(const short8v*)&A[AAG1 + c*64 + k0 + 8];
    }
    __syncthreads();

    #pragma unroll
    for (int rg = 0; rg < 2; ++rg)
        #pragma unroll
        for (int j = 0; j < 4; ++j) {
            int r = rg*16 + lg*4 + j, c = w*16 + lr;
            hA[r*72 + c] = f2bf(acc1[rg][j] + vob[c]);
        }
    {
        const int c = t >> 2, k0 = (t & 3) * 16;
        *(short8v*)&Wt0[c*72+k0]   = *(const short8v*)&A[AAG2 + c*64 + k0];
        *(short8v*)&Wt0[c*72+k0+8] = *(const short8v*)&A[AAG2 + c*64 + k0 + 8];
    }
    __syncthreads();

    // ---- pa GLU + residual(temporal) ----
    #pragma unroll
    for (int rg = 0; rg < 2; ++rg) { aA[rg] = (f32x4){0.f,0.f,0.f,0.f}; aB[rg] = (f32x4){0.f,0.f,0.f,0.f}; }
    #pragma unroll
    for (int ks = 0; ks < 2; ++ks) {
        short8v b1f = *(const short8v*)&Wt1[(w*16 + lr)*72 + ks*32 + lg*8];
        short8v b2f = *(const short8v*)&Wt0[(w*16 + lr)*72 + ks*32 + lg*8];
        #pragma unroll
        for (int rg = 0; rg < 2; ++rg) {
            short8v af = *(const short8v*)&hA[(rg*16 + lr)*72 + ks*32 + lg*8];
            aA[rg] = __builtin_amdgcn_mfma_f32_16x16x32_bf16(af, b1f, aA[rg], 0, 0, 0);
            aB[rg] = __builtin_amdgcn_mfma_f32_16x16x32_bf16(af, b2f, aB[rg], 0, 0, 0);
        }
    }
    #pragma unroll
    for (int rg = 0; rg < 2; ++rg)
        #pragma unroll
        for (int j = 0; j < 4; ++j) {
            int r = rg*16 + lg*4 + j, c = w*16 + lr;
            int rc = r < TSEQ ? r : TSEQ - 1;
            float sgv = sigmoidf_(aA[rg][j] + vag1b[c]);
            yv[rg][j] = sgv * (aB[rg][j] + vag2b[c]) + tmpS[rc*68 + c];
        }
    __syncthreads();

    #pragma unroll
    for (int rg = 0; rg < 2; ++rg)
        #pragma unroll
        for (int j = 0; j < 4; ++j) {
            int r = rg*16 + lg*4 + j, c = w*16 + lr;
            yA[r*68 + c] = yv[rg][j];
        }
    __syncthreads();

    // pa-LN -> enriched
    #pragma unroll
    for (int a = 0; a < 2; ++a) {
        const int r = tr + 16*a;
        float4 v4 = *(const float4*)&yA[r*68 + tc*4];
        float part = v4.x + v4.y + v4.z + v4.w;
        #pragma unroll
        for (int off = 1; off < 16; off <<= 1) part += __shfl_xor(part, off);
        const float mean = part * (1.f / 64.f);
        float d0 = v4.x - mean, d1 = v4.y - mean, d2 = v4.z - mean, d3 = v4.w - mean;
        float vp = d0*d0 + d1*d1 + d2*d2 + d3*d3;
        #pragma unroll
        for (int off = 1; off < 16; off <<= 1) vp += __shfl_xor(vp, off);
        const float inv = rsqrtf(vp * (1.f / 64.f) + LN_EPS);
        const int c0 = tc * 4;
        float4 ov;
        ov.x = d0 * inv * valg[c0+0] + valb[c0+0];
        ov.y = d1 * inv * valg[c0+1] + valb[c0+1];
        ov.z = d2 * inv * valg[c0+2] + valb[c0+2];
        ov.w = d3 * inv * valg[c0+3] + valb[c0+3];
        if (r < TSEQ) *(float4*)&enrS[r*68 + c0] = ov;
        ushort4 ob;
        ob.x = f2bf(ov.x); ob.y = f2bf(ov.y); ob.z = f2bf(ov.z); ob.w = f2bf(ov.w);
        *(ushort4*)&hA[r*72 + c0] = ob;
    }
    __syncthreads();

    // ---- ff mm1 ----
    {
        const int c = t >> 1, k0 = (t & 1) * 32;
        #pragma unroll
        for (int j = 0; j < 4; ++j)
            *(short8v*)&W1t[c*72 + k0 + j*8] = *(const short8v*)&A[AFW1 + (size_t)c*64 + k0 + j*8];
    }
    __syncthreads();

    f32x4 accf[2][2];
    #pragma unroll
    for (int rg = 0; rg < 2; ++rg)
        #pragma unroll
        for (int cf = 0; cf < 2; ++cf) accf[rg][cf] = (f32x4){0.f,0.f,0.f,0.f};
    #pragma unroll
    for (int ks = 0; ks < 2; ++ks) {
        short8v af[2];
        #pragma unroll
        for (int rg = 0; rg < 2; ++rg)
            af[rg] = *(const short8v*)&hA[(rg*16 + lr)*72 + ks*32 + lg*8];
        #pragma unroll
        for (int cf = 0; cf < 2; ++cf) {
            short8v bf = *(const short8v*)&W1t[(w*32 + cf*16 + lr)*72 + ks*32 + lg*8];
            #pragma unroll
            for (int rg = 0; rg < 2; ++rg)
                accf[rg][cf] = __builtin_amdgcn_mfma_f32_16x16x32_bf16(af[rg], bf, accf[rg][cf], 0, 0, 0);
        }
    }
    __syncthreads();   // W1t reads done; hBs region disjoint

    #pragma unroll
    for (int rg = 0; rg < 2; ++rg)
        #pragma unroll
        for (int cf = 0; cf < 2; ++cf)
            #pragma unroll
            for (int j = 0; j < 4; ++j) {
                int r = rg*16 + lg*4 + j, c = w*32 + cf*16 + lr;
                hBs[r*136 + c] = f2bf(eluf_(accf[rg][cf][j] + vf1b[c]));
            }
    // stage W2t over dead W1t front
    {
        const int c = t >> 2, k0 = (t & 3) * 32;
        #pragma unroll
        for (int j = 0; j < 4; ++j)
            *(short8v*)&W2t[c*136 + k0 + j*8] = *(const short8v*)&A[AFW2 + (size_t)c*128 + k0 + j*8];
    }
    __syncthreads();

    // ff mm2
    f32x4 acc2[2];
    #pragma unroll
    for (int rg = 0; rg < 2; ++rg) acc2[rg] = (f32x4){0.f,0.f,0.f,0.f};
    #pragma unroll
    for (int ks = 0; ks < 4; ++ks) {
        short8v bf = *(const short8v*)&W2t[(w*16 + lr)*136 + ks*32 + lg*8];
        #pragma unroll
        for (int rg = 0; rg < 2; ++rg) {
            short8v af = *(const short8v*)&hBs[(rg*16 + lr)*136 + ks*32 + lg*8];
            acc2[rg] = __builtin_amdgcn_mfma_f32_16x16x32_bf16(af, bf, acc2[rg], 0, 0, 0);
        }
    }
    #pragma unroll
    for (int rg = 0; rg < 2; ++rg)
        #pragma unroll
        for (int j = 0; j < 4; ++j) {
            int r = rg*16 + lg*4 + j, c = w*16 + lr;
            hA[r*72 + c] = f2bf(acc2[rg][j] + vf2b[c]);
        }
    __syncthreads();

    // stage ff GLU weights
    {
        const int c = t >> 2, k0 = (t & 3) * 16;
        *(short8v*)&Wt0[c*72+k0]   = *(const short8v*)&A[AFG1 + c*64 + k0];
        *(short8v*)&Wt0[c*72+k0+8] = *(const short8v*)&A[AFG1 + c*64 + k0 + 8];
        *(short8v*)&Wt1[c*72+k0]   = *(const short8v*)&A[AFG2 + c*64 + k0];
        *(short8v*)&Wt1[c*72+k0+8] = *(const short8v*)&A[AFG2 + c*64 + k0 + 8];
    }
    __syncthreads();

    // ---- ff GLU + residual(enriched) ----
    #pragma unroll
    for (int rg = 0; rg < 2; ++rg) { aA[rg] = (f32x4){0.f,0.f,0.f,0.f}; aB[rg] = (f32x4){0.f,0.f,0.f,0.f}; }
    #pragma unroll
    for (int ks = 0; ks < 2; ++ks) {
        short8v b1f = *(const short8v*)&Wt0[(w*16 + lr)*72 + ks*32 + lg*8];
        short8v b2f = *(const short8v*)&Wt1[(w*16 + lr)*72 + ks*32 + lg*8];
        #pragma unroll
        for (int rg = 0; rg < 2; ++rg) {
            short8v af = *(const short8v*)&hA[(rg*16 + lr)*72 + ks*32 + lg*8];
            aA[rg] = __builtin_amdgcn_mfma_f32_16x16x32_bf16(af, b1f, aA[rg], 0, 0, 0);
            aB[rg] = __builtin_amdgcn_mfma_f32_16x16x32_bf16(af, b2f, aB[rg], 0, 0, 0);
        }
    }
    #pragma unroll
    for (int rg = 0; rg < 2; ++rg)
        #pragma unroll
        for (int j = 0; j < 4; ++j) {
            int r = rg*16 + lg*4 + j, c = w*16 + lr;
            int rc = r < TSEQ ? r : TSEQ - 1;
            float sgv = sigmoidf_(aA[rg][j] + vfg1b[c]);
            yv[rg][j] = sgv * (aB[rg][j] + vfg2b[c]) + enrS[rc*68 + c];
        }
    __syncthreads();

    #pragma unroll
    for (int rg = 0; rg < 2; ++rg)
        #pragma unroll
        for (int j = 0; j < 4; ++j) {
            int r = rg*16 + lg*4 + j, c = w*16 + lr;
            yA[r*68 + c] = yv[rg][j];
        }
    __syncthreads();

    // ff-LN -> outln (tmpS reused)
    #pragma unroll
    for (int a = 0; a < 2; ++a) {
        const int r = tr + 16*a;
        float4 v4 = *(const float4*)&yA[r*68 + tc*4];
        float part = v4.x + v4.y + v4.z + v4.w;
        #pragma unroll
        for (int off = 1; off < 16; off <<= 1) part += __shfl_xor(part, off);
        const float mean = part * (1.f / 64.f);
        float d0 = v4.x - mean, d1 = v4.y - mean, d2 = v4.z - mean, d3 = v4.w - mean;
        float vp = d0*d0 + d1*d1 + d2*d2 + d3*d3;
        #pragma unroll
        for (int off = 1; off < 16; off <<= 1) vp += __shfl_xor(vp, off);
        const float inv = rsqrtf(vp * (1.f / 64.f) + LN_EPS);
        const int c0 = tc * 4;
        if (r < TSEQ) {
            float4 ov;
            ov.x = d0 * inv * vflg[c0+0] + vflb[c0+0];
            ov.y = d1 * inv * vflg[c0+1] + vflb[c0+1];
            ov.z = d2 * inv * vflg[c0+2] + vflb[c0+2];
            ov.w = d3 * inv * vflg[c0+3] + vflb[c0+3];
            *(float4*)&tmpS[r*68 + c0] = ov;
        }
    }
    __syncthreads();

    // ---- head: pool -> fc1+relu -> fc2 ----
    if (t < 64) {
        float s = 0.f;
        #pragma unroll
        for (int tt = 0; tt < TSEQ; ++tt) s += tmpS[tt*68 + t];
        sh[t] = s * (1.f / 24.f);
    }
    __syncthreads();
    if (t < 64) {
        float a = fc1_b[t];
        for (int k = 0; k < 64; ++k) a += sh[k] * fc1_w[k*64 + t];
        float f1 = fmaxf(a, 0.f);
        #pragma unroll
        for (int j = 0; j < 6; ++j) {
            float p = f1 * fc2_w[t*6 + j];
            #pragma unroll
            for (int off = 32; off; off >>= 1) p += __shfl_xor(p, off);
            if (t == 0) out[b*6 + j] = p + fc2_b[j];
        }
    }
}

// =====================================================================
extern "C" void kernel_launch(void* const* d_in, const int* in_sizes, int n_in,
                              void* d_out, int out_size, void* d_ws, size_t ws_size,
                              hipStream_t stream)
{
    const float* x        = (const float*)d_in[0];
    const float* f_w1     = (const float*)d_in[1];
    const float* f_b1     = (const float*)d_in[2];
    const float* f_w2     = (const float*)d_in[3];
    const float* f_b2     = (const float*)d_in[4];
    const float* f_g1w    = (const float*)d_in[5];
    const float* f_g1b    = (const float*)d_in[6];
    const float* f_g2w    = (const float*)d_in[7];
    const float* f_g2b    = (const float*)d_in[8];
    const float* f_skw    = (const float*)d_in[9];
    const float* f_skb    = (const float*)d_in[10];
    const float* f_lng    = (const float*)d_in[11];
    const float* f_lnb    = (const float*)d_in[12];
    const float* w_w1     = (const float*)d_in[13];
    const float* w_b1     = (const float*)d_in[14];
    const float* w_w2     = (const float*)d_in[15];
    const float* w_b2     = (const float*)d_in[16];
    const float* w_g1w    = (const float*)d_in[17];
    const float* w_g1b    = (const float*)d_in[18];
    const float* w_g2w    = (const float*)d_in[19];
    const float* w_g2b    = (const float*)d_in[20];
    const float* w_skw    = (const float*)d_in[21];
    const float* w_skb    = (const float*)d_in[22];
    const float* w_lng    = (const float*)d_in[23];
    const float* w_lnb    = (const float*)d_in[24];
    const float* lstm_wih = (const float*)d_in[25];
    const float* lstm_whh = (const float*)d_in[26];
    const float* lstm_bih = (const float*)d_in[27];
    const float* lstm_bhh = (const float*)d_in[28];
    const float* pl_g1w   = (const float*)d_in[29];
    const float* pl_g1b   = (const float*)d_in[30];
    const float* pl_g2w   = (const float*)d_in[31];
    const float* pl_g2b   = (const float*)d_in[32];
    const float* pl_lng   = (const float*)d_in[33];
    const float* pl_lnb   = (const float*)d_in[34];
    const float* attn_in_w  = (const float*)d_in[35];
    const float* attn_in_b  = (const float*)d_in[36];
    const float* attn_out_w = (const float*)d_in[37];
    const float* attn_out_b = (const float*)d_in[38];
    const float* pa_g1w   = (const float*)d_in[39];
    const float* pa_g1b   = (const float*)d_in[40];
    const float* pa_g2w   = (const float*)d_in[41];
    const float* pa_g2b   = (const float*)d_in[42];
    const float* pa_lng   = (const float*)d_in[43];
    const float* pa_lnb   = (const float*)d_in[44];
    const float* ff_w1    = (const float*)d_in[45];
    const float* ff_b1    = (const float*)d_in[46];
    const float* ff_w2    = (const float*)d_in[47];
    const float* ff_b2    = (const float*)d_in[48];
    const float* ff_g1w   = (const float*)d_in[49];
    const float* ff_g1b   = (const float*)d_in[50];
    const float* ff_g2w   = (const float*)d_in[51];
    const float* ff_g2b   = (const float*)d_in[52];
    const float* ff_lng   = (const float*)d_in[53];
    const float* ff_lnb   = (const float*)d_in[54];
    const float* fc1_w    = (const float*)d_in[55];
    const float* fc1_b    = (const float*)d_in[56];
    const float* fc2_w    = (const float*)d_in[57];
    const float* fc2_b    = (const float*)d_in[58];

    float* ws = (float*)d_ws;

    // ---------------- layout ----------------------------------------------
    size_t o = 0;
    const size_t o_S0   = o; o += (size_t)MTOT * 256;   // xW
    o += (size_t)MTOT * 64;
    o += (size_t)MTOT * 64;
    o += (size_t)MTOT * 64;
    o += (size_t)MTOT * 64;
    o += (size_t)MTOT * 128;
    o += 16384;
    const size_t unionP2 = o;                            // 7,880,704 floats

    // persist: sel + selb + xT + arena
    const size_t arenaF = (ATOT + 2) / 2 + 64;           // arena in float units (+pad)
    const size_t persist = (size_t)MTOT * 177 + arenaF;
    int mc = 0;
    {
        const int cands[4] = {12288, 6144, 3072, 1536};
        for (int ci = 0; ci < 4; ++ci) {
            const size_t c = (size_t)cands[ci];
            size_t overlay = c * FDIM / 2 + (size_t)KS * c * NW + c * 81
                           + (size_t)NW * FDIM / 2;
            size_t A0 = overlay > unionP2 ? overlay : unionP2;
            if ((A0 + persist) * sizeof(float) <= ws_size) { mc = cands[ci]; break; }
        }
        if (mc == 0) return;
    }
    const size_t ovl_partial = (size_t)mc * FDIM / 2;
    const size_t ovl_w81     = ovl_partial + (size_t)KS * mc * NW;
    const size_t ovl_wcat    = ovl_w81 + (size_t)mc * 81;
    const size_t ovl_end     = ovl_wcat + (size_t)NW * FDIM / 2;
    const size_t regA        = ovl_end > unionP2 ? ovl_end : unionP2;
    const size_t o_sel   = regA;
    const size_t o_selb  = o_sel + (size_t)MTOT * 64;
    const size_t o_xt    = o_selb + (size_t)MTOT * 32;
    const size_t o_arena = o_xt + (size_t)NF * MTOT;     // 16B-aligned (all multiples)
    unsigned short* Ar = (unsigned short*)(ws + o_arena);

    const dim3 blk(256);

    // 0) transpose x ; pack weight-head matrices ; pack bf16 weight arena
    xt_kernel<<<dim3(MTOT / 128), blk, 0, stream>>>(x, ws + o_xt);
    wprep_kernel<<<dim3((FDIM + 255) / 256, NW), blk, 0, stream>>>(
        w_w1, w_skw, (unsigned short*)(ws + ovl_wcat));
    wprep2_kernel<<<dim3((int)((ATOT + 255) / 256)), blk, 0, stream>>>(
        f_w2, f_g1w, f_g2w, lstm_wih, pl_g1w, pl_g2w, attn_in_w, attn_out_w,
        pa_g1w, pa_g2w, ff_w1, ff_w2, ff_g1w, ff_g2w, w_w2, w_g1w, w_g2w, Ar);

    // ---------------- phase 1: VSN + weight-GRN ----------
    for (int mb = 0; mb < MTOT; mb += mc) {
        __hip_bfloat16* chunk = (__hip_bfloat16*)ws;
        vsn_kernel<<<dim3((mc / 64) / NT, NF), blk, 0, stream>>>(
            ws + o_xt + mb, Ar, f_w1, f_b1, f_b2, f_g1b, f_g2b,
            f_skw, f_skb, f_lng, f_lnb, chunk);
        wgemm_kernel<<<dim3(mc / 32, KS), dim3(64), 0, stream>>>(
            chunk, (const unsigned short*)(ws + ovl_wcat), ws + ovl_partial, mc);
        wtail_kernel<<<dim3(mc / 16), blk, 0, stream>>>(
            ws + ovl_partial, chunk, Ar, w_b1, w_skb, w_b2, w_g1b, w_g2b,
            w_lng, w_lnb,
            ws + o_sel + (size_t)mb * 64,
            (__hip_bfloat16*)(ws + o_selb) + (size_t)mb * 64, mc);
    }

    // ---------------- phase 2: xW then per-batch mega kernel -------------
    xw_kernel<<<dim3(MTOT / 64), blk, 0, stream>>>(
        (const __hip_bfloat16*)(ws + o_selb), Ar, lstm_bih, lstm_bhh, ws + o_S0);
    batch_kernel<<<dim3(BB), blk, 0, stream>>>(
        ws + o_S0, lstm_whh, ws + o_sel, Ar,
        pl_g1b, pl_g2b, pl_lng, pl_lnb,
        attn_in_b, attn_out_b, pa_g1b, pa_g2b, pa_lng, pa_lnb,
        ff_b1, ff_b2, ff_g1b, ff_g2b, ff_lng, ff_lnb,
        fc1_w, fc1_b, fc2_w, fc2_b, (float*)d_out);
}

// Round 16
// 293.316 us; speedup vs baseline: 1.2503x; 1.0021x over previous
//
#include <hip/hip_runtime.h>
#include <hip/hip_bf16.h>
#include <math.h>

// ---------------- problem constants ----------------
constexpr int BB   = 512;
constexpr int TSEQ = 24;
constexpr int NF   = 81;
constexpr int DD   = 64;
constexpr int MTOT = BB * TSEQ;      // 12288
constexpr int FDIM = NF * DD;        // 5184
constexpr int KS   = 6;              // split-K groups (5184/6 = 864)
constexpr int KSL  = 864;
constexpr int NW   = 160;
constexpr int NT   = 6;
constexpr float LN_EPS = 1e-5f;

// ---- bf16 weight arena offsets (ushort units) ----
constexpr size_t AV    = 0;          // vsn: [81][3][64][64] (c-major)
constexpr size_t AWIH  = 995328;     // lstm wih [256][64] (already [c][k])
constexpr size_t APL1  = 1011712;    // pl_g1w  [64][64] (c-major)
constexpr size_t APL2  = 1015808;    // pl_g2w
constexpr size_t AWQ   = 1019904;    // attn_in_w [192][64] (c-major)
constexpr size_t AWOUT = 1032192;    // attn_out_w [64][64]
constexpr size_t AAG1  = 1036288;    // pa_g1w
constexpr size_t AAG2  = 1040384;    // pa_g2w
constexpr size_t AFW1  = 1044480;    // ff_w1 [128][64] (c-major)
constexpr size_t AFW2  = 1052672;    // ff_w2 [64][128] (c-major)
constexpr size_t AFG1  = 1060864;    // ff_g1w
constexpr size_t AFG2  = 1064960;    // ff_g2w
constexpr size_t AW2S  = 1069056;    // w_w2 [64][81] natural
constexpr size_t AG1S  = 1074240;    // w_g1w [81][81] natural
constexpr size_t AG2S  = 1080801;    // w_g2w [81][81] natural
constexpr size_t ATOT  = 1087362;

typedef __attribute__((ext_vector_type(8))) short short8v;
typedef __attribute__((ext_vector_type(4))) float f32x4;

static __device__ __forceinline__ float sigmoidf_(float x) {
    return __builtin_amdgcn_rcpf(1.f + __expf(-x));
}
static __device__ __forceinline__ float eluf_(float x) {
    return x > 0.f ? x : (__expf(x) - 1.f);
}
static __device__ __forceinline__ float ftanh_(float x) {
    float e = __expf(2.f * x);
    return 1.f - 2.f * __builtin_amdgcn_rcpf(e + 1.f);
}
static __device__ __forceinline__ unsigned short f2bf(float x) {
    __hip_bfloat16 h = __float2bfloat16(x);
    return *reinterpret_cast<unsigned short*>(&h);
}
static __device__ __forceinline__ float b2f(unsigned short u) {
    __hip_bfloat16 h = *reinterpret_cast<__hip_bfloat16*>(&u);
    return __bfloat162float(h);
}

// =====================================================================
// x transpose: LDS-tiled. grid MTOT/128.
// =====================================================================
__global__ __launch_bounds__(256) void xt_kernel(
    const float* __restrict__ x, float* __restrict__ xT)
{
    __shared__ float tile[128 * 81];
    const int m0 = blockIdx.x * 128;
    const int t  = threadIdx.x;
    for (int e = t; e < 128 * 81; e += 256)
        tile[e] = x[(size_t)m0 * NF + e];
    __syncthreads();
    for (int e = t; e < 128 * 81; e += 256) {
        int f = e >> 7, r = e & 127;
        xT[(size_t)f * MTOT + m0 + r] = tile[r * 81 + f];
    }
}

// =====================================================================
// wprep2: pack ALL reused weights into the bf16 arena (pre-transposed).
// =====================================================================
__global__ void wprep2_kernel(
    const float* __restrict__ f_w2, const float* __restrict__ f_g1w,
    const float* __restrict__ f_g2w, const float* __restrict__ wih,
    const float* __restrict__ pg1w, const float* __restrict__ pg2w,
    const float* __restrict__ wqkv, const float* __restrict__ wout,
    const float* __restrict__ ag1w, const float* __restrict__ ag2w,
    const float* __restrict__ fw1, const float* __restrict__ fw2,
    const float* __restrict__ fg1w, const float* __restrict__ fg2w,
    const float* __restrict__ w_w2, const float* __restrict__ w_g1w,
    const float* __restrict__ w_g2w,
    unsigned short* __restrict__ A)
{
    size_t i = (size_t)blockIdx.x * 256 + threadIdx.x;
    if (i >= ATOT) return;
    float v;
    if (i < AWIH) {
        size_t f = i / 12288; int r = (int)(i % 12288); int mat = r >> 12; int e = r & 4095;
        int c = e >> 6, k = e & 63;
        const float* src = mat == 0 ? f_w2 : (mat == 1 ? f_g1w : f_g2w);
        v = src[f * 4096 + k * 64 + c];
    }
    else if (i < APL1) { v = wih[i - AWIH]; }
    else if (i < APL2) { int e = (int)(i - APL1); int c = e >> 6, k = e & 63; v = pg1w[k*64 + c]; }
    else if (i < AWQ)  { int e = (int)(i - APL2); int c = e >> 6, k = e & 63; v = pg2w[k*64 + c]; }
    else if (i < AWOUT){ int e = (int)(i - AWQ);  int c = e >> 6, k = e & 63; v = wqkv[k*192 + c]; }
    else if (i < AAG1) { int e = (int)(i - AWOUT);int c = e >> 6, k = e & 63; v = wout[k*64 + c]; }
    else if (i < AAG2) { int e = (int)(i - AAG1); int c = e >> 6, k = e & 63; v = ag1w[k*64 + c]; }
    else if (i < AFW1) { int e = (int)(i - AAG2); int c = e >> 6, k = e & 63; v = ag2w[k*64 + c]; }
    else if (i < AFW2) { int e = (int)(i - AFW1); int c = e >> 6, k = e & 63; v = fw1[k*128 + c]; }
    else if (i < AFG1) { int e = (int)(i - AFW2); int c = e >> 7, k = e & 127; v = fw2[k*64 + c]; }
    else if (i < AFG2) { int e = (int)(i - AFG1); int c = e >> 6, k = e & 63; v = fg1w[k*64 + c]; }
    else if (i < AW2S) { int e = (int)(i - AFG2); int c = e >> 6, k = e & 63; v = fg2w[k*64 + c]; }
    else if (i < AG1S) { v = w_w2[i - AW2S]; }
    else if (i < AG2S) { v = w_g1w[i - AG1S]; }
    else               { v = w_g2w[i - AG2S]; }
    A[i] = f2bf(v);
}

// =====================================================================
// Kernel 1: VSN v7 — arena-fed staging + xval software pipeline
// =====================================================================
__global__ __launch_bounds__(256) void vsn_kernel(
    const float* __restrict__ xT,
    const unsigned short* __restrict__ A,
    const float* __restrict__ f_w1,  const float* __restrict__ f_b1,
    const float* __restrict__ f_b2,
    const float* __restrict__ f_g1b, const float* __restrict__ f_g2b,
    const float* __restrict__ f_skw, const float* __restrict__ f_skb,
    const float* __restrict__ f_lng, const float* __restrict__ f_lnb,
    __hip_bfloat16* __restrict__ stacked)
{
    const int f  = blockIdx.y;
    const int t  = threadIdx.x;
    const int w  = t >> 6;
    const int l  = t & 63;
    const int lr = l & 15;
    const int lg = l >> 4;

    __shared__ __align__(16) unsigned short W2t[64 * 72];
    __shared__ __align__(16) unsigned short G1t[64 * 72];
    __shared__ __align__(16) unsigned short G2t[64 * 72];
    __shared__ __align__(16) unsigned short hS[4][16 * 72];
    __shared__ float vw1[64], vb1[64], vb2[64], vg1b[64], vg2b[64];
    __shared__ float vskw[64], vskb[64], vlng[64], vlnb[64];

    if (t < 64) {
        vw1[t]  = f_w1 [f*64 + t];  vb1[t]  = f_b1 [f*64 + t];
        vb2[t]  = f_b2 [f*64 + t];
        vg1b[t] = f_g1b[f*64 + t];  vg2b[t] = f_g2b[f*64 + t];
        vskw[t] = f_skw[f*64 + t];  vskb[t] = f_skb[f*64 + t];
        vlng[t] = f_lng[f*64 + t];  vlnb[t] = f_lnb[f*64 + t];
    }
    {
        const unsigned short* av = A + (size_t)f * 12288;
        const int c = t >> 2, k0 = (t & 3) * 16;
        *(short8v*)&W2t[c*72 + k0]     = *(const short8v*)&av[c*64 + k0];
        *(short8v*)&W2t[c*72 + k0 + 8] = *(const short8v*)&av[c*64 + k0 + 8];
        *(short8v*)&G1t[c*72 + k0]     = *(const short8v*)&av[4096 + c*64 + k0];
        *(short8v*)&G1t[c*72 + k0 + 8] = *(const short8v*)&av[4096 + c*64 + k0 + 8];
        *(short8v*)&G2t[c*72 + k0]     = *(const short8v*)&av[8192 + c*64 + k0];
        *(short8v*)&G2t[c*72 + k0 + 8] = *(const short8v*)&av[8192 + c*64 + k0 + 8];
    }
    __syncthreads();

    unsigned short* slab = hS[w];
    float xval = xT[(size_t)f * MTOT + blockIdx.x * (NT * 64) + w*16 + lr];

    for (int it = 0; it < NT; ++it) {
        const int m0 = (blockIdx.x * NT + it) * 64;
        const float xcur = xval;
        if (it + 1 < NT)   // prefetch next tile's x (hidden under compute)
            xval = xT[(size_t)f * MTOT + m0 + 64 + w*16 + lr];

        short8v a0f, a1f;
        #pragma unroll
        for (int j = 0; j < 8; ++j) {
            const int d0 = lg*8 + j, d1 = 32 + lg*8 + j;
            a0f[j] = (short)f2bf(eluf_(xcur * vw1[d0] + vb1[d0]));
            a1f[j] = (short)f2bf(eluf_(xcur * vw1[d1] + vb1[d1]));
        }

        f32x4 acc1[4];
        #pragma unroll
        for (int cf = 0; cf < 4; ++cf) acc1[cf] = (f32x4){0.f,0.f,0.f,0.f};
        #pragma unroll
        for (int cf = 0; cf < 4; ++cf) {
            short8v b0 = *(const short8v*)&W2t[(cf*16 + lr)*72 + lg*8];
            short8v b1 = *(const short8v*)&W2t[(cf*16 + lr)*72 + 32 + lg*8];
            acc1[cf] = __builtin_amdgcn_mfma_f32_16x16x32_bf16(a0f, b0, acc1[cf], 0, 0, 0);
            acc1[cf] = __builtin_amdgcn_mfma_f32_16x16x32_bf16(a1f, b1, acc1[cf], 0, 0, 0);
        }

        #pragma unroll
        for (int cf = 0; cf < 4; ++cf)
            #pragma unroll
            for (int j = 0; j < 4; ++j) {
                const int c = cf*16 + lr;
                slab[(4*lg + j)*72 + c] = f2bf(acc1[cf][j] + vb2[c]);
            }
        __builtin_amdgcn_sched_barrier(0);

        short8v h0f = *(const short8v*)&slab[lr*72 + lg*8];
        short8v h1f = *(const short8v*)&slab[lr*72 + 32 + lg*8];

        f32x4 aA[4], aB[4];
        #pragma unroll
        for (int cf = 0; cf < 4; ++cf) { aA[cf] = (f32x4){0.f,0.f,0.f,0.f}; aB[cf] = (f32x4){0.f,0.f,0.f,0.f}; }
        #pragma unroll
        for (int cf = 0; cf < 4; ++cf) {
            short8v b10 = *(const short8v*)&G1t[(cf*16 + lr)*72 + lg*8];
            short8v b11 = *(const short8v*)&G1t[(cf*16 + lr)*72 + 32 + lg*8];
            short8v b20 = *(const short8v*)&G2t[(cf*16 + lr)*72 + lg*8];
            short8v b21 = *(const short8v*)&G2t[(cf*16 + lr)*72 + 32 + lg*8];
            aA[cf] = __builtin_amdgcn_mfma_f32_16x16x32_bf16(h0f, b10, aA[cf], 0, 0, 0);
            aA[cf] = __builtin_amdgcn_mfma_f32_16x16x32_bf16(h1f, b11, aA[cf], 0, 0, 0);
            aB[cf] = __builtin_amdgcn_mfma_f32_16x16x32_bf16(h0f, b20, aB[cf], 0, 0, 0);
            aB[cf] = __builtin_amdgcn_mfma_f32_16x16x32_bf16(h1f, b21, aB[cf], 0, 0, 0);
        }

        float xs[4];
        #pragma unroll
        for (int j = 0; j < 4; ++j) xs[j] = __shfl(xcur, 4*lg + j, 64);
        float yv[4][4];
        #pragma unroll
        for (int cf = 0; cf < 4; ++cf)
            #pragma unroll
            for (int j = 0; j < 4; ++j) {
                const int c = cf*16 + lr;
                float sg = sigmoidf_(aA[cf][j] + vg1b[c]);
                yv[cf][j] = sg * (aB[cf][j] + vg2b[c]) + xs[j] * vskw[c] + vskb[c];
            }

        #pragma unroll
        for (int j = 0; j < 4; ++j) {
            float part = yv[0][j] + yv[1][j] + yv[2][j] + yv[3][j];
            #pragma unroll
            for (int off = 1; off < 16; off <<= 1) part += __shfl_xor(part, off);
            const float mean = part * (1.f / 64.f);
            float vp = 0.f;
            #pragma unroll
            for (int cf = 0; cf < 4; ++cf) { float d = yv[cf][j] - mean; vp += d * d; }
            #pragma unroll
            for (int off = 1; off < 16; off <<= 1) vp += __shfl_xor(vp, off);
            const float inv = rsqrtf(vp * (1.f / 64.f) + LN_EPS);
            #pragma unroll
            for (int cf = 0; cf < 4; ++cf) {
                const int c = cf*16 + lr;
                slab[(4*lg + j)*72 + c] = f2bf((yv[cf][j] - mean) * inv * vlng[c] + vlnb[c]);
            }
        }
        __builtin_amdgcn_sched_barrier(0);

        {
            const size_t base = (size_t)(m0 + w*16 + lr) * FDIM + (size_t)f * 64 + lg*16;
            short8v s0 = *(const short8v*)&slab[lr*72 + lg*16];
            short8v s1 = *(const short8v*)&slab[lr*72 + lg*16 + 8];
            *(short8v*)&stacked[base]     = s0;
            *(short8v*)&stacked[base + 8] = s1;
        }
    }
}

// =====================================================================
// Pack w_w1 / w_skw into bf16 WcatT[160][FDIM]
// =====================================================================
__global__ void wprep_kernel(
    const float* __restrict__ w_w1, const float* __restrict__ w_skw,
    unsigned short* __restrict__ WcatT)
{
    const int c = blockIdx.y;
    const int k = blockIdx.x * 256 + threadIdx.x;
    if (k >= FDIM) return;
    float v = 0.f;
    if (c < 64)       v = w_w1[(size_t)k * 64 + c];
    else if (c < 145) v = w_skw[(size_t)k * 81 + (c - 64)];
    WcatT[(size_t)c * FDIM + k] = f2bf(v);
}

// =====================================================================
// Split-K fused weight-head GEMM (MFMA, LDS-free), MR=2, KS=6
// =====================================================================
__global__ __launch_bounds__(64) void wgemm_kernel(
    const __hip_bfloat16* __restrict__ stacked,
    const unsigned short* __restrict__ WcatT,
    float* __restrict__ partial, int mc)
{
    const int m0 = blockIdx.x * 32;
    const int ks = blockIdx.y;
    const int l  = threadIdx.x;
    const int lr = l & 15, lg = l >> 4;

    f32x4 acc[2][10];
    #pragma unroll
    for (int h = 0; h < 2; ++h)
        #pragma unroll
        for (int n = 0; n < 10; ++n) acc[h][n] = (f32x4){0.f, 0.f, 0.f, 0.f};

    const size_t a0r = (size_t)(m0 + lr) * FDIM;
    const size_t a1r = (size_t)(m0 + 16 + lr) * FDIM;
    const int k0base = ks * KSL;
    for (int kk = 0; kk < KSL; kk += 32) {
        const int k = k0base + kk + lg * 8;
        short8v a0 = *(const short8v*)(stacked + a0r + k);
        short8v a1 = *(const short8v*)(stacked + a1r + k);
        #pragma unroll
        for (int n = 0; n < 10; ++n) {
            short8v bf = *(const short8v*)(WcatT + (size_t)(n*16 + lr) * FDIM + k);
            acc[0][n] = __builtin_amdgcn_mfma_f32_16x16x32_bf16(a0, bf, acc[0][n], 0, 0, 0);
            acc[1][n] = __builtin_amdgcn_mfma_f32_16x16x32_bf16(a1, bf, acc[1][n], 0, 0, 0);
        }
    }
    #pragma unroll
    for (int h = 0; h < 2; ++h)
        #pragma unroll
        for (int n = 0; n < 10; ++n)
            #pragma unroll
            for (int j = 0; j < 4; ++j) {
                const int m = m0 + h*16 + lg*4 + j;
                partial[((size_t)ks * mc + m) * NW + n*16 + lr] = acc[h][n][j];
            }
}

// =====================================================================
// Weight-GRN tail v4: bf16 weight LDS (52 KB -> 3 blocks/CU)
// =====================================================================
__global__ __launch_bounds__(256) void wtail_kernel(
    const float* __restrict__ partial,
    const __hip_bfloat16* __restrict__ stacked,
    const unsigned short* __restrict__ A,
    const float* __restrict__ w_b1,  const float* __restrict__ w_skb,
    const float* __restrict__ w_b2,
    const float* __restrict__ w_g1b, const float* __restrict__ w_g2b,
    const float* __restrict__ w_lng, const float* __restrict__ w_lnb,
    float* __restrict__ sel, __hip_bfloat16* __restrict__ selb, int mc)
{
    __shared__ unsigned short w2h[5184];
    __shared__ unsigned short g1h[6561];
    __shared__ unsigned short g2h[6561];
    __shared__ float sWh[16][64];
    __shared__ float sW2[16][96];
    __shared__ float wsh[16][81];

    const int t  = threadIdx.x;
    const int wv = t >> 6, l = t & 63;
    const int m0 = blockIdx.x * 16;
    const bool v1 = (l < 17);

    for (int e = t; e < 5184; e += 256) w2h[e] = A[AW2S + e];
    for (int e = t; e < 6561; e += 256) { g1h[e] = A[AG1S + e]; g2h[e] = A[AG2S + e]; }

    float s0[4], sk0[4], sk1[4];
    {
        const float b1v = w_b1[l], skb0 = w_skb[l], skb1 = v1 ? w_skb[64 + l] : 0.f;
        #pragma unroll
        for (int rr = 0; rr < 4; ++rr) { s0[rr] = b1v; sk0[rr] = skb0; sk1[rr] = skb1; }
    }
    #pragma unroll
    for (int ks = 0; ks < KS; ++ks) {
        #pragma unroll
        for (int rr = 0; rr < 4; ++rr) {
            const float* pr = partial + ((size_t)ks * mc + (m0 + wv*4 + rr)) * NW;
            s0[rr]  += pr[l];
            sk0[rr] += pr[64 + l];
            if (v1) sk1[rr] += pr[128 + l];
        }
    }
    #pragma unroll
    for (int rr = 0; rr < 4; ++rr) sWh[wv*4 + rr][l] = eluf_(s0[rr]);
    __syncthreads();

    float a0[4], a1[4];
    {
        const float b0 = w_b2[l], b1v = v1 ? w_b2[64 + l] : 0.f;
        #pragma unroll
        for (int rr = 0; rr < 4; ++rr) { a0[rr] = b0; a1[rr] = b1v; }
    }
    #pragma unroll 4
    for (int i = 0; i < 64; ++i) {
        const float wl = b2f(w2h[i*81 + l]);
        const float wh = v1 ? b2f(w2h[i*81 + 64 + l]) : 0.f;
        #pragma unroll
        for (int rr = 0; rr < 4; ++rr) {
            const float h = sWh[wv*4 + rr][i];
            a0[rr] += h * wl;
            a1[rr] += h * wh;
        }
    }
    #pragma unroll
    for (int rr = 0; rr < 4; ++rr) {
        sW2[wv*4 + rr][l] = a0[rr];
        if (v1) sW2[wv*4 + rr][64 + l] = a1[rr];
    }
    __syncthreads();

    float g10[4], g20[4], g11[4], g21[4];
    {
        const float c10 = w_g1b[l], c20 = w_g2b[l];
        const float c11 = v1 ? w_g1b[64 + l] : 0.f, c21 = v1 ? w_g2b[64 + l] : 0.f;
        #pragma unroll
        for (int rr = 0; rr < 4; ++rr) { g10[rr] = c10; g20[rr] = c20; g11[rr] = c11; g21[rr] = c21; }
    }
    #pragma unroll 3
    for (int i = 0; i < 81; ++i) {
        const float w1l = b2f(g1h[i*81 + l]),        w2l = b2f(g2h[i*81 + l]);
        const float w1h = v1 ? b2f(g1h[i*81 + 64 + l]) : 0.f;
        const float w2h2 = v1 ? b2f(g2h[i*81 + 64 + l]) : 0.f;
        #pragma unroll
        for (int rr = 0; rr < 4; ++rr) {
            const float h = sW2[wv*4 + rr][i];
            g10[rr] += h * w1l; g20[rr] += h * w2l;
            g11[rr] += h * w1h; g21[rr] += h * w2h2;
        }
    }

    #pragma unroll
    for (int rr = 0; rr < 4; ++rr) {
        float y0 = sigmoidf_(g10[rr]) * g20[rr] + sk0[rr];
        float y1 = v1 ? (sigmoidf_(g11[rr]) * g21[rr] + sk1[rr]) : 0.f;

        float s = y0 + (v1 ? y1 : 0.f);
        #pragma unroll
        for (int off = 32; off; off >>= 1) s += __shfl_xor(s, off);
        const float mean = s / 81.f;
        float d0 = y0 - mean, d1 = v1 ? (y1 - mean) : 0.f;
        float vs = d0*d0 + (v1 ? d1*d1 : 0.f);
        #pragma unroll
        for (int off = 32; off; off >>= 1) vs += __shfl_xor(vs, off);
        const float inv = rsqrtf(vs / 81.f + LN_EPS);
        float wn0 = d0 * inv * w_lng[l] + w_lnb[l];
        float wn1 = v1 ? (d1 * inv * w_lng[64 + l] + w_lnb[64 + l]) : -1e30f;

        float mx = fmaxf(wn0, wn1);
        #pragma unroll
        for (int off = 32; off; off >>= 1) mx = fmaxf(mx, __shfl_xor(mx, off));
        float e0 = __expf(wn0 - mx), e1 = v1 ? __expf(wn1 - mx) : 0.f;
        float es = e0 + e1;
        #pragma unroll
        for (int off = 32; off; off >>= 1) es += __shfl_xor(es, off);
        const float r = __builtin_amdgcn_rcpf(es);
        wsh[wv*4 + rr][l] = e0 * r;
        if (v1) wsh[wv*4 + rr][64 + l] = e1 * r;
    }
    __syncthreads();

    {
        const int rr2 = t >> 4;
        const int d0 = (t & 15) * 4;
        const size_t mrow = (size_t)(m0 + rr2);
        float acc0 = 0.f, acc1f = 0.f, acc2 = 0.f, acc3 = 0.f;
        for (int f = 0; f < 81; ++f) {
            const float wv81 = wsh[rr2][f];
            ushort4 u = *(const ushort4*)&stacked[mrow * FDIM + f*64 + d0];
            acc0 += b2f(u.x) * wv81;
            acc1f += b2f(u.y) * wv81;
            acc2 += b2f(u.z) * wv81;
            acc3 += b2f(u.w) * wv81;
        }
        float4 ov = {acc0, acc1f, acc2, acc3};
        *(float4*)&sel[mrow * 64 + d0] = ov;
        ushort4 ub;
        ub.x = f2bf(acc0); ub.y = f2bf(acc1f); ub.z = f2bf(acc2); ub.w = f2bf(acc3);
        *(ushort4*)&((unsigned short*)selb)[mrow * 64 + d0] = ub;
    }
}

// =====================================================================
// xW = selb @ wih^T + (bih+bhh)   — arena-fed staging
// =====================================================================
__global__ __launch_bounds__(256) void xw_kernel(
    const __hip_bfloat16* __restrict__ selb,
    const unsigned short* __restrict__ A,
    const float* __restrict__ bih, const float* __restrict__ bhh,
    float* __restrict__ xW)
{
    const int m0 = blockIdx.x * 64;
    const int t = threadIdx.x;
    const int w = t >> 6, l = t & 63, lr = l & 15, lg = l >> 4;
    __shared__ __align__(16) unsigned short hA[64 * 72];
    __shared__ __align__(16) unsigned short Wt[256 * 72];
    __shared__ float vbs[256];

    vbs[t] = bih[t] + bhh[t];
    #pragma unroll
    for (int p = 0; p < 16; ++p) {
        int e = t + 256 * p; int r = e >> 6, d = e & 63;
        hA[r*72 + d] = *(const unsigned short*)&selb[(size_t)(m0 + r) * 64 + d];
    }
    {
        const int c = t;
        #pragma unroll
        for (int j = 0; j < 8; ++j)
            *(short8v*)&Wt[c*72 + j*8] = *(const short8v*)&A[AWIH + (size_t)c*64 + j*8];
    }
    __syncthreads();

    f32x4 acc[4][4];
    #pragma unroll
    for (int rg = 0; rg < 4; ++rg)
        #pragma unroll
        for (int cf = 0; cf < 4; ++cf) acc[rg][cf] = (f32x4){0.f,0.f,0.f,0.f};
    #pragma unroll
    for (int ks = 0; ks < 2; ++ks) {
        short8v af[4];
        #pragma unroll
        for (int rg = 0; rg < 4; ++rg)
            af[rg] = *(const short8v*)&hA[(rg*16 + lr)*72 + ks*32 + lg*8];
        #pragma unroll
        for (int cf = 0; cf < 4; ++cf) {
            short8v bf = *(const short8v*)&Wt[(w*64 + cf*16 + lr)*72 + ks*32 + lg*8];
            #pragma unroll
            for (int rg = 0; rg < 4; ++rg)
                acc[rg][cf] = __builtin_amdgcn_mfma_f32_16x16x32_bf16(af[rg], bf, acc[rg][cf], 0, 0, 0);
        }
    }
    #pragma unroll
    for (int rg = 0; rg < 4; ++rg)
        #pragma unroll
        for (int cf = 0; cf < 4; ++cf)
            #pragma unroll
            for (int j = 0; j < 4; ++j) {
                int r = rg*16 + lg*4 + j, c = w*64 + cf*16 + lr;
                xW[(size_t)(m0 + r) * 256 + c] = acc[rg][cf][j] + vbs[c];
            }
}

// =====================================================================
// batch_kernel v4: per-batch mega fusion; xW/sel/bqkv preloaded to
// registers so the LSTM loop is vmem-free (no per-barrier vmcnt drain).
// =====================================================================
__global__ __launch_bounds__(256) void batch_kernel(
    const float* __restrict__ xW, const float* __restrict__ whh,
    const float* __restrict__ sel,
    const unsigned short* __restrict__ A,
    const float* __restrict__ pg1b, const float* __restrict__ pg2b,
    const float* __restrict__ plng, const float* __restrict__ plnb,
    const float* __restrict__ bqkv, const float* __restrict__ bout,
    const float* __restrict__ ag1b, const float* __restrict__ ag2b,
    const float* __restrict__ alng, const float* __restrict__ alnb,
    const float* __restrict__ fb1, const float* __restrict__ fb2,
    const float* __restrict__ fg1b, const float* __restrict__ fg2b,
    const float* __restrict__ flng, const float* __restrict__ flnb,
    const float* __restrict__ fc1_w, const float* __restrict__ fc1_b,
    const float* __restrict__ fc2_w, const float* __restrict__ fc2_b,
    float* __restrict__ out)
{
    const int b  = blockIdx.x;
    const int m0 = b * TSEQ;            // 24 rows
    const int t  = threadIdx.x;
    const int w  = t >> 6, l = t & 63, lr = l & 15, lg = l >> 4;
    const int tr = t >> 4, tc = t & 15;

    __shared__ float tmpS[24 * 68];
    __shared__ float enrS[24 * 68];
    __shared__ __align__(16) unsigned short hA[32 * 72];
    __shared__ __align__(16) unsigned char U[27648];
    __shared__ float sh[64], sg[256];
    __shared__ float vpg1b[64], vpg2b[64], vplg[64], vplb[64];
    __shared__ float vob[64], vag1b[64], vag2b[64], valg[64], valb[64];
    __shared__ float vf1b[128], vf2b[64], vfg1b[64], vfg2b[64], vflg[64], vflb[64];

    unsigned short* Wt0 = (unsigned short*)U;
    unsigned short* Wt1 = (unsigned short*)(U + 9216);
    float*          yA  = (float*)(U + 18432);
    unsigned short* Wq  = (unsigned short*)U;
    float* sq = (float*)U;
    float* sk = (float*)(U + 6144);
    float* sv = (float*)(U + 12288);
    float* sp = (float*)(U + 18432);
    unsigned short* W1t = (unsigned short*)U;
    unsigned short* W2t = (unsigned short*)U;
    unsigned short* hBs = (unsigned short*)(U + 18432);

    // ---- prefetch ALL per-thread global inputs up front (issue early) ----
    float xreg[TSEQ];
    #pragma unroll
    for (int tt = 0; tt < TSEQ; ++tt)
        xreg[tt] = xW[(size_t)(m0 + tt) * 256 + t];
    float selr[2][4];
    #pragma unroll
    for (int rg = 0; rg < 2; ++rg)
        #pragma unroll
        for (int j = 0; j < 4; ++j) {
            int r = rg*16 + lg*4 + j;
            size_t rrow = (size_t)(m0 + (r < TSEQ ? r : TSEQ - 1));
            selr[rg][j] = sel[rrow * 64 + (w*16 + lr)];
        }
    float bqr[3];
    #pragma unroll
    for (int cf = 0; cf < 3; ++cf) bqr[cf] = bqkv[w*48 + cf*16 + lr];
    float wreg[64];
    #pragma unroll
    for (int i = 0; i < 64; ++i) wreg[i] = whh[t*64 + i];

    if (t < 64) {
        vpg1b[t] = pg1b[t]; vpg2b[t] = pg2b[t]; vplg[t] = plng[t]; vplb[t] = plnb[t];
        vob[t] = bout[t]; vag1b[t] = ag1b[t]; vag2b[t] = ag2b[t];
        valg[t] = alng[t]; valb[t] = alnb[t];
        vf2b[t] = fb2[t]; vfg1b[t] = fg1b[t]; vfg2b[t] = fg2b[t];
        vflg[t] = flng[t]; vflb[t] = flnb[t];
    }
    if (t < 128) vf1b[t] = fb1[t];
    for (int e = t; e < 8 * 72; e += 256) hA[24*72 + e] = 0;

    // ---- LSTM recurrence (vmem-free loop) ----
    if (t < 64) sh[t] = 0.f;
    float c_reg = 0.f;
    __syncthreads();

    #pragma unroll 1
    for (int tt = 0; tt < TSEQ; ++tt) {
        float acc = xreg[tt];
        #pragma unroll
        for (int i = 0; i < 64; ++i) acc += sh[i] * wreg[i];
        sg[t] = acc;
        __syncthreads();
        if (t < 64) {
            float gi = sg[t], gf = sg[64 + t], gg = sg[128 + t], go = sg[192 + t];
            c_reg = sigmoidf_(gf) * c_reg + sigmoidf_(gi) * ftanh_(gg);
            float hn = sigmoidf_(go) * ftanh_(c_reg);
            sh[t] = hn;
            hA[tt*72 + t] = f2bf(hn);
        }
        __syncthreads();
    }

    // ---- pl GLU: stage g1/g2 from arena ----
    {
        const int c = t >> 2, k0 = (t & 3) * 16;
        *(short8v*)&Wt0[c*72+k0]   = *(const short8v*)&A[APL1 + c*64 + k0];
        *(short8v*)&Wt0[c*72+k0+8] = *(const short8v*)&A[APL1 + c*64 + k0 + 8];
        *(short8v*)&Wt1[c*72+k0]   = *(const short8v*)&A[APL2 + c*64 + k0];
        *(short8v*)&Wt1[c*72+k0+8] = *(const short8v*)&A[APL2 + c*64 + k0 + 8];
    }
    __syncthreads();

    f32x4 aA[2], aB[2];
    #pragma unroll
    for (int rg = 0; rg < 2; ++rg) { aA[rg] = (f32x4){0.f,0.f,0.f,0.f}; aB[rg] = (f32x4){0.f,0.f,0.f,0.f}; }
    #pragma unroll
    for (int ks = 0; ks < 2; ++ks) {
        short8v b0f = *(const short8v*)&Wt0[(w*16 + lr)*72 + ks*32 + lg*8];
        short8v b1f = *(const short8v*)&Wt1[(w*16 + lr)*72 + ks*32 + lg*8];
        #pragma unroll
        for (int rg = 0; rg < 2; ++rg) {
            short8v af = *(const short8v*)&hA[(rg*16 + lr)*72 + ks*32 + lg*8];
            aA[rg] = __builtin_amdgcn_mfma_f32_16x16x32_bf16(af, b0f, aA[rg], 0, 0, 0);
            aB[rg] = __builtin_amdgcn_mfma_f32_16x16x32_bf16(af, b1f, aB[rg], 0, 0, 0);
        }
    }
    float yv[2][4];
    #pragma unroll
    for (int rg = 0; rg < 2; ++rg)
        #pragma unroll
        for (int j = 0; j < 4; ++j) {
            int c = w*16 + lr;
            float sgv = sigmoidf_(aA[rg][j] + vpg1b[c]);
            yv[rg][j] = sgv * (aB[rg][j] + vpg2b[c]) + selr[rg][j];
        }
    __syncthreads();

    #pragma unroll
    for (int rg = 0; rg < 2; ++rg)
        #pragma unroll
        for (int j = 0; j < 4; ++j) {
            int r = rg*16 + lg*4 + j, c = w*16 + lr;
            yA[r*68 + c] = yv[rg][j];
        }
    __syncthreads();

    // pl-LN -> temporal
    #pragma unroll
    for (int a = 0; a < 2; ++a) {
        const int r = tr + 16*a;
        float4 v4 = *(const float4*)&yA[r*68 + tc*4];
        float part = v4.x + v4.y + v4.z + v4.w;
        #pragma unroll
        for (int off = 1; off < 16; off <<= 1) part += __shfl_xor(part, off);
        const float mean = part * (1.f / 64.f);
        float d0 = v4.x - mean, d1 = v4.y - mean, d2 = v4.z - mean, d3 = v4.w - mean;
        float vp = d0*d0 + d1*d1 + d2*d2 + d3*d3;
        #pragma unroll
        for (int off = 1; off < 16; off <<= 1) vp += __shfl_xor(vp, off);
        const float inv = rsqrtf(vp * (1.f / 64.f) + LN_EPS);
        const int c0 = tc * 4;
        float4 ov;
        ov.x = d0 * inv * vplg[c0+0] + vplb[c0+0];
        ov.y = d1 * inv * vplg[c0+1] + vplb[c0+1];
        ov.z = d2 * inv * vplg[c0+2] + vplb[c0+2];
        ov.w = d3 * inv * vplg[c0+3] + vplb[c0+3];
        if (r < TSEQ) *(float4*)&tmpS[r*68 + c0] = ov;
        ushort4 ob;
        ob.x = f2bf(ov.x); ob.y = f2bf(ov.y); ob.z = f2bf(ov.z); ob.w = f2bf(ov.w);
        *(ushort4*)&hA[r*72 + c0] = ob;
    }
    __syncthreads();

    // ---- QKV projection ----
    if (t < 192) {
        #pragma unroll
        for (int j = 0; j < 8; ++j)
            *(short8v*)&Wq[t*72 + j*8] = *(const short8v*)&A[AWQ + (size_t)t*64 + j*8];
    }
    __syncthreads();

    f32x4 accq[2][3];
    #pragma unroll
    for (int rg = 0; rg < 2; ++rg)
        #pragma unroll
        for (int cf = 0; cf < 3; ++cf) accq[rg][cf] = (f32x4){0.f,0.f,0.f,0.f};
    #pragma unroll
    for (int ks = 0; ks < 2; ++ks) {
        short8v af[2];
        #pragma unroll
        for (int rg = 0; rg < 2; ++rg)
            af[rg] = *(const short8v*)&hA[(rg*16 + lr)*72 + ks*32 + lg*8];
        #pragma unroll
        for (int cf = 0; cf < 3; ++cf) {
            short8v bf = *(const short8v*)&Wq[(w*48 + cf*16 + lr)*72 + ks*32 + lg*8];
            #pragma unroll
            for (int rg = 0; rg < 2; ++rg)
                accq[rg][cf] = __builtin_amdgcn_mfma_f32_16x16x32_bf16(af[rg], bf, accq[rg][cf], 0, 0, 0);
        }
    }
    __syncthreads();

    #pragma unroll
    for (int rg = 0; rg < 2; ++rg)
        #pragma unroll
        for (int cf = 0; cf < 3; ++cf)
            #pragma unroll
            for (int j = 0; j < 4; ++j) {
                int r = rg*16 + lg*4 + j, c = w*48 + cf*16 + lr;
                if (r < TSEQ) {
                    float val = accq[rg][cf][j] + bqr[cf];
                    int seg = c >> 6, hh = (c & 63) >> 4, dd = c & 15;
                    float* dst = (seg == 0) ? sq : (seg == 1 ? sk : sv);
                    dst[(hh*24 + r)*16 + dd] = val;
                }
            }
    __syncthreads();

    // ---- attention (wave w = head) ----
    #pragma unroll
    for (int p = 0; p < 9; ++p) {
        int e = l + 64 * p; int i = e / 24, j2 = e - i * 24;
        float s = 0.f;
        #pragma unroll
        for (int d = 0; d < 16; ++d) s += sq[(w*24 + i)*16 + d] * sk[(w*24 + j2)*16 + d];
        sp[(w*24 + i)*24 + j2] = s * 0.25f;
    }
    __syncthreads();
    if (l < 24) {
        float mx = -1e30f;
        for (int j = 0; j < 24; ++j) mx = fmaxf(mx, sp[(w*24 + l)*24 + j]);
        float s = 0.f;
        for (int j = 0; j < 24; ++j) { float e = __expf(sp[(w*24 + l)*24 + j] - mx); sp[(w*24 + l)*24 + j] = e; s += e; }
        float inv = __builtin_amdgcn_rcpf(s);
        for (int j = 0; j < 24; ++j) sp[(w*24 + l)*24 + j] *= inv;
    }
    __syncthreads();
    #pragma unroll
    for (int p = 0; p < 6; ++p) {
        int e = l + 64 * p; int ti = e >> 4, d = e & 15;
        float s = 0.f;
        #pragma unroll
        for (int j = 0; j < 24; ++j) s += sp[(w*24 + ti)*24 + j] * sv[(w*24 + j)*16 + d];
        hA[ti*72 + w*16 + d] = f2bf(s);
    }
    __syncthreads();

    // ---- pa mm1 ----
    {
        const int c = t >> 2, k0 = (t & 3) * 16;
        *(short8v*)&Wt0[c*72+k0]   = *(const short8v*)&A[AWOUT + c*64 + k0];
        *(short8v*)&Wt0[c*72+k0+8] = *(const short8v*)&A[AWOUT + c*64 + k0 + 8];
    }
    __syncthreads();

    f32x4 acc1[2];
    #pragma unroll
    for (int rg = 0; rg < 2; ++rg) acc1[rg] = (f32x4){0.f,0.f,0.f,0.f};
    #pragma unroll
    for (int ks = 0; ks < 2; ++ks) {
        short8v bf = *(const short8v*)&Wt0[(w*16 + lr)*72 + ks*32 + lg*8];
        #pragma unroll
        for (int rg = 0; rg < 2; ++rg) {
            short8v af = *(const short8v*)&hA[(rg*16 + lr)*72 + ks*32 + lg*8];
            acc1[rg] = __builtin_amdgcn_mfma_f32_16x16x32_bf16(af, bf, acc1[rg], 0, 0, 0);
        }
    }
    {
        const int c = t >> 2, k0 = (t & 3) * 16;
        *(short8v*)&Wt1[c*72+k0]   = *(const short8v*)&A[AAG1 + c*64 + k0];
        *(short8v*)&Wt1[c*72+k0+8] = *(const short8v*)&A[AAG1 + c*64 + k0 + 8];
    }
    __syncthreads();

    #pragma unroll
    for (int rg = 0; rg < 2; ++rg)
        #pragma unroll
        for (int j = 0; j < 4; ++j) {
            int r = rg*16 + lg*4 + j, c = w*16 + lr;
            hA[r*72 + c] = f2bf(acc1[rg][j] + vob[c]);
        }
    {
        const int c = t >> 2, k0 = (t & 3) * 16;
        *(short8v*)&Wt0[c*72+k0]   = *(const short8v*)&A[AAG2 + c*64 + k0];
        *(short8v*)&Wt0[c*72+k0+8] = *(const short8v*)&A[AAG2 + c*64 + k0 + 8];
    }
    __syncthreads();

    // ---- pa GLU + residual(temporal) ----
    #pragma unroll
    for (int rg = 0; rg < 2; ++rg) { aA[rg] = (f32x4){0.f,0.f,0.f,0.f}; aB[rg] = (f32x4){0.f,0.f,0.f,0.f}; }
    #pragma unroll
    for (int ks = 0; ks < 2; ++ks) {
        short8v b1f = *(const short8v*)&Wt1[(w*16 + lr)*72 + ks*32 + lg*8];
        short8v b2f = *(const short8v*)&Wt0[(w*16 + lr)*72 + ks*32 + lg*8];
        #pragma unroll
        for (int rg = 0; rg < 2; ++rg) {
            short8v af = *(const short8v*)&hA[(rg*16 + lr)*72 + ks*32 + lg*8];
            aA[rg] = __builtin_amdgcn_mfma_f32_16x16x32_bf16(af, b1f, aA[rg], 0, 0, 0);
            aB[rg] = __builtin_amdgcn_mfma_f32_16x16x32_bf16(af, b2f, aB[rg], 0, 0, 0);
        }
    }
    #pragma unroll
    for (int rg = 0; rg < 2; ++rg)
        #pragma unroll
        for (int j = 0; j < 4; ++j) {
            int r = rg*16 + lg*4 + j, c = w*16 + lr;
            int rc = r < TSEQ ? r : TSEQ - 1;
            float sgv = sigmoidf_(aA[rg][j] + vag1b[c]);
            yv[rg][j] = sgv * (aB[rg][j] + vag2b[c]) + tmpS[rc*68 + c];
        }
    __syncthreads();

    #pragma unroll
    for (int rg = 0; rg < 2; ++rg)
        #pragma unroll
        for (int j = 0; j < 4; ++j) {
            int r = rg*16 + lg*4 + j, c = w*16 + lr;
            yA[r*68 + c] = yv[rg][j];
        }
    __syncthreads();

    // pa-LN -> enriched
    #pragma unroll
    for (int a = 0; a < 2; ++a) {
        const int r = tr + 16*a;
        float4 v4 = *(const float4*)&yA[r*68 + tc*4];
        float part = v4.x + v4.y + v4.z + v4.w;
        #pragma unroll
        for (int off = 1; off < 16; off <<= 1) part += __shfl_xor(part, off);
        const float mean = part * (1.f / 64.f);
        float d0 = v4.x - mean, d1 = v4.y - mean, d2 = v4.z - mean, d3 = v4.w - mean;
        float vp = d0*d0 + d1*d1 + d2*d2 + d3*d3;
        #pragma unroll
        for (int off = 1; off < 16; off <<= 1) vp += __shfl_xor(vp, off);
        const float inv = rsqrtf(vp * (1.f / 64.f) + LN_EPS);
        const int c0 = tc * 4;
        float4 ov;
        ov.x = d0 * inv * valg[c0+0] + valb[c0+0];
        ov.y = d1 * inv * valg[c0+1] + valb[c0+1];
        ov.z = d2 * inv * valg[c0+2] + valb[c0+2];
        ov.w = d3 * inv * valg[c0+3] + valb[c0+3];
        if (r < TSEQ) *(float4*)&enrS[r*68 + c0] = ov;
        ushort4 ob;
        ob.x = f2bf(ov.x); ob.y = f2bf(ov.y); ob.z = f2bf(ov.z); ob.w = f2bf(ov.w);
        *(ushort4*)&hA[r*72 + c0] = ob;
    }
    __syncthreads();

    // ---- ff mm1 ----
    {
        const int c = t >> 1, k0 = (t & 1) * 32;
        #pragma unroll
        for (int j = 0; j < 4; ++j)
            *(short8v*)&W1t[c*72 + k0 + j*8] = *(const short8v*)&A[AFW1 + (size_t)c*64 + k0 + j*8];
    }
    __syncthreads();

    f32x4 accf[2][2];
    #pragma unroll
    for (int rg = 0; rg < 2; ++rg)
        #pragma unroll
        for (int cf = 0; cf < 2; ++cf) accf[rg][cf] = (f32x4){0.f,0.f,0.f,0.f};
    #pragma unroll
    for (int ks = 0; ks < 2; ++ks) {
        short8v af[2];
        #pragma unroll
        for (int rg = 0; rg < 2; ++rg)
            af[rg] = *(const short8v*)&hA[(rg*16 + lr)*72 + ks*32 + lg*8];
        #pragma unroll
        for (int cf = 0; cf < 2; ++cf) {
            short8v bf = *(const short8v*)&W1t[(w*32 + cf*16 + lr)*72 + ks*32 + lg*8];
            #pragma unroll
            for (int rg = 0; rg < 2; ++rg)
                accf[rg][cf] = __builtin_amdgcn_mfma_f32_16x16x32_bf16(af[rg], bf, accf[rg][cf], 0, 0, 0);
        }
    }
    __syncthreads();   // W1t reads done; hBs region disjoint

    #pragma unroll
    for (int rg = 0; rg < 2; ++rg)
        #pragma unroll
        for (int cf = 0; cf < 2; ++cf)
            #pragma unroll
            for (int j = 0; j < 4; ++j) {
                int r = rg*16 + lg*4 + j, c = w*32 + cf*16 + lr;
                hBs[r*136 + c] = f2bf(eluf_(accf[rg][cf][j] + vf1b[c]));
            }
    // stage W2t over dead W1t front
    {
        const int c = t >> 2, k0 = (t & 3) * 32;
        #pragma unroll
        for (int j = 0; j < 4; ++j)
            *(short8v*)&W2t[c*136 + k0 + j*8] = *(const short8v*)&A[AFW2 + (size_t)c*128 + k0 + j*8];
    }
    __syncthreads();

    // ff mm2
    f32x4 acc2[2];
    #pragma unroll
    for (int rg = 0; rg < 2; ++rg) acc2[rg] = (f32x4){0.f,0.f,0.f,0.f};
    #pragma unroll
    for (int ks = 0; ks < 4; ++ks) {
        short8v bf = *(const short8v*)&W2t[(w*16 + lr)*136 + ks*32 + lg*8];
        #pragma unroll
        for (int rg = 0; rg < 2; ++rg) {
            short8v af = *(const short8v*)&hBs[(rg*16 + lr)*136 + ks*32 + lg*8];
            acc2[rg] = __builtin_amdgcn_mfma_f32_16x16x32_bf16(af, bf, acc2[rg], 0, 0, 0);
        }
    }
    #pragma unroll
    for (int rg = 0; rg < 2; ++rg)
        #pragma unroll
        for (int j = 0; j < 4; ++j) {
            int r = rg*16 + lg*4 + j, c = w*16 + lr;
            hA[r*72 + c] = f2bf(acc2[rg][j] + vf2b[c]);
        }
    __syncthreads();

    // stage ff GLU weights
    {
        const int c = t >> 2, k0 = (t & 3) * 16;
        *(short8v*)&Wt0[c*72+k0]   = *(const short8v*)&A[AFG1 + c*64 + k0];
        *(short8v*)&Wt0[c*72+k0+8] = *(const short8v*)&A[AFG1 + c*64 + k0 + 8];
        *(short8v*)&Wt1[c*72+k0]   = *(const short8v*)&A[AFG2 + c*64 + k0];
        *(short8v*)&Wt1[c*72+k0+8] = *(const short8v*)&A[AFG2 + c*64 + k0 + 8];
    }
    __syncthreads();

    // ---- ff GLU + residual(enriched) ----
    #pragma unroll
    for (int rg = 0; rg < 2; ++rg) { aA[rg] = (f32x4){0.f,0.f,0.f,0.f}; aB[rg] = (f32x4){0.f,0.f,0.f,0.f}; }
    #pragma unroll
    for (int ks = 0; ks < 2; ++ks) {
        short8v b1f = *(const short8v*)&Wt0[(w*16 + lr)*72 + ks*32 + lg*8];
        short8v b2f = *(const short8v*)&Wt1[(w*16 + lr)*72 + ks*32 + lg*8];
        #pragma unroll
        for (int rg = 0; rg < 2; ++rg) {
            short8v af = *(const short8v*)&hA[(rg*16 + lr)*72 + ks*32 + lg*8];
            aA[rg] = __builtin_amdgcn_mfma_f32_16x16x32_bf16(af, b1f, aA[rg], 0, 0, 0);
            aB[rg] = __builtin_amdgcn_mfma_f32_16x16x32_bf16(af, b2f, aB[rg], 0, 0, 0);
        }
    }
    #pragma unroll
    for (int rg = 0; rg < 2; ++rg)
        #pragma unroll
        for (int j = 0; j < 4; ++j) {
            int r = rg*16 + lg*4 + j, c = w*16 + lr;
            int rc = r < TSEQ ? r : TSEQ - 1;
            float sgv = sigmoidf_(aA[rg][j] + vfg1b[c]);
            yv[rg][j] = sgv * (aB[rg][j] + vfg2b[c]) + enrS[rc*68 + c];
        }
    __syncthreads();

    #pragma unroll
    for (int rg = 0; rg < 2; ++rg)
        #pragma unroll
        for (int j = 0; j < 4; ++j) {
            int r = rg*16 + lg*4 + j, c = w*16 + lr;
            yA[r*68 + c] = yv[rg][j];
        }
    __syncthreads();

    // ff-LN -> outln (tmpS reused)
    #pragma unroll
    for (int a = 0; a < 2; ++a) {
        const int r = tr + 16*a;
        float4 v4 = *(const float4*)&yA[r*68 + tc*4];
        float part = v4.x + v4.y + v4.z + v4.w;
        #pragma unroll
        for (int off = 1; off < 16; off <<= 1) part += __shfl_xor(part, off);
        const float mean = part * (1.f / 64.f);
        float d0 = v4.x - mean, d1 = v4.y - mean, d2 = v4.z - mean, d3 = v4.w - mean;
        float vp = d0*d0 + d1*d1 + d2*d2 + d3*d3;
        #pragma unroll
        for (int off = 1; off < 16; off <<= 1) vp += __shfl_xor(vp, off);
        const float inv = rsqrtf(vp * (1.f / 64.f) + LN_EPS);
        const int c0 = tc * 4;
        if (r < TSEQ) {
            float4 ov;
            ov.x = d0 * inv * vflg[c0+0] + vflb[c0+0];
            ov.y = d1 * inv * vflg[c0+1] + vflb[c0+1];
            ov.z = d2 * inv * vflg[c0+2] + vflb[c0+2];
            ov.w = d3 * inv * vflg[c0+3] + vflb[c0+3];
            *(float4*)&tmpS[r*68 + c0] = ov;
        }
    }
    __syncthreads();

    // ---- head: pool -> fc1+relu -> fc2 ----
    if (t < 64) {
        float s = 0.f;
        #pragma unroll
        for (int tt = 0; tt < TSEQ; ++tt) s += tmpS[tt*68 + t];
        sh[t] = s * (1.f / 24.f);
    }
    __syncthreads();
    if (t < 64) {
        float a = fc1_b[t];
        for (int k = 0; k < 64; ++k) a += sh[k] * fc1_w[k*64 + t];
        float f1 = fmaxf(a, 0.f);
        #pragma unroll
        for (int j = 0; j < 6; ++j) {
            float p = f1 * fc2_w[t*6 + j];
            #pragma unroll
            for (int off = 32; off; off >>= 1) p += __shfl_xor(p, off);
            if (t == 0) out[b*6 + j] = p + fc2_b[j];
        }
    }
}

// =====================================================================
extern "C" void kernel_launch(void* const* d_in, const int* in_sizes, int n_in,
                              void* d_out, int out_size, void* d_ws, size_t ws_size,
                              hipStream_t stream)
{
    const float* x        = (const float*)d_in[0];
    const float* f_w1     = (const float*)d_in[1];
    const float* f_b1     = (const float*)d_in[2];
    const float* f_w2     = (const float*)d_in[3];
    const float* f_b2     = (const float*)d_in[4];
    const float* f_g1w    = (const float*)d_in[5];
    const float* f_g1b    = (const float*)d_in[6];
    const float* f_g2w    = (const float*)d_in[7];
    const float* f_g2b    = (const float*)d_in[8];
    const float* f_skw    = (const float*)d_in[9];
    const float* f_skb    = (const float*)d_in[10];
    const float* f_lng    = (const float*)d_in[11];
    const float* f_lnb    = (const float*)d_in[12];
    const float* w_w1     = (const float*)d_in[13];
    const float* w_b1     = (const float*)d_in[14];
    const float* w_w2     = (const float*)d_in[15];
    const float* w_b2     = (const float*)d_in[16];
    const float* w_g1w    = (const float*)d_in[17];
    const float* w_g1b    = (const float*)d_in[18];
    const float* w_g2w    = (const float*)d_in[19];
    const float* w_g2b    = (const float*)d_in[20];
    const float* w_skw    = (const float*)d_in[21];
    const float* w_skb    = (const float*)d_in[22];
    const float* w_lng    = (const float*)d_in[23];
    const float* w_lnb    = (const float*)d_in[24];
    const float* lstm_wih = (const float*)d_in[25];
    const float* lstm_whh = (const float*)d_in[26];
    const float* lstm_bih = (const float*)d_in[27];
    const float* lstm_bhh = (const float*)d_in[28];
    const float* pl_g1w   = (const float*)d_in[29];
    const float* pl_g1b   = (const float*)d_in[30];
    const float* pl_g2w   = (const float*)d_in[31];
    const float* pl_g2b   = (const float*)d_in[32];
    const float* pl_lng   = (const float*)d_in[33];
    const float* pl_lnb   = (const float*)d_in[34];
    const float* attn_in_w  = (const float*)d_in[35];
    const float* attn_in_b  = (const float*)d_in[36];
    const float* attn_out_w = (const float*)d_in[37];
    const float* attn_out_b = (const float*)d_in[38];
    const float* pa_g1w   = (const float*)d_in[39];
    const float* pa_g1b   = (const float*)d_in[40];
    const float* pa_g2w   = (const float*)d_in[41];
    const float* pa_g2b   = (const float*)d_in[42];
    const float* pa_lng   = (const float*)d_in[43];
    const float* pa_lnb   = (const float*)d_in[44];
    const float* ff_w1    = (const float*)d_in[45];
    const float* ff_b1    = (const float*)d_in[46];
    const float* ff_w2    = (const float*)d_in[47];
    const float* ff_b2    = (const float*)d_in[48];
    const float* ff_g1w   = (const float*)d_in[49];
    const float* ff_g1b   = (const float*)d_in[50];
    const float* ff_g2w   = (const float*)d_in[51];
    const float* ff_g2b   = (const float*)d_in[52];
    const float* ff_lng   = (const float*)d_in[53];
    const float* ff_lnb   = (const float*)d_in[54];
    const float* fc1_w    = (const float*)d_in[55];
    const float* fc1_b    = (const float*)d_in[56];
    const float* fc2_w    = (const float*)d_in[57];
    const float* fc2_b    = (const float*)d_in[58];

    float* ws = (float*)d_ws;

    // ---------------- layout ----------------------------------------------
    size_t o = 0;
    const size_t o_S0   = o; o += (size_t)MTOT * 256;   // xW
    o += (size_t)MTOT * 64;
    o += (size_t)MTOT * 64;
    o += (size_t)MTOT * 64;
    o += (size_t)MTOT * 64;
    o += (size_t)MTOT * 128;
    o += 16384;
    const size_t unionP2 = o;                            // 7,880,704 floats

    // persist: sel + selb + xT + arena
    const size_t arenaF = (ATOT + 2) / 2 + 64;           // arena in float units (+pad)
    const size_t persist = (size_t)MTOT * 177 + arenaF;
    int mc = 0;
    {
        const int cands[4] = {12288, 6144, 3072, 1536};
        for (int ci = 0; ci < 4; ++ci) {
            const size_t c = (size_t)cands[ci];
            size_t overlay = c * FDIM / 2 + (size_t)KS * c * NW + c * 81
                           + (size_t)NW * FDIM / 2;
            size_t A0 = overlay > unionP2 ? overlay : unionP2;
            if ((A0 + persist) * sizeof(float) <= ws_size) { mc = cands[ci]; break; }
        }
        if (mc == 0) return;
    }
    const size_t ovl_partial = (size_t)mc * FDIM / 2;
    const size_t ovl_w81     = ovl_partial + (size_t)KS * mc * NW;
    const size_t ovl_wcat    = ovl_w81 + (size_t)mc * 81;
    const size_t ovl_end     = ovl_wcat + (size_t)NW * FDIM / 2;
    const size_t regA        = ovl_end > unionP2 ? ovl_end : unionP2;
    const size_t o_sel   = regA;
    const size_t o_selb  = o_sel + (size_t)MTOT * 64;
    const size_t o_xt    = o_selb + (size_t)MTOT * 32;
    const size_t o_arena = o_xt + (size_t)NF * MTOT;
    unsigned short* Ar = (unsigned short*)(ws + o_arena);

    const dim3 blk(256);

    // 0) transpose x ; pack weight-head matrices ; pack bf16 weight arena
    xt_kernel<<<dim3(MTOT / 128), blk, 0, stream>>>(x, ws + o_xt);
    wprep_kernel<<<dim3((FDIM + 255) / 256, NW), blk, 0, stream>>>(
        w_w1, w_skw, (unsigned short*)(ws + ovl_wcat));
    wprep2_kernel<<<dim3((int)((ATOT + 255) / 256)), blk, 0, stream>>>(
        f_w2, f_g1w, f_g2w, lstm_wih, pl_g1w, pl_g2w, attn_in_w, attn_out_w,
        pa_g1w, pa_g2w, ff_w1, ff_w2, ff_g1w, ff_g2w, w_w2, w_g1w, w_g2w, Ar);

    // ---------------- phase 1: VSN + weight-GRN ----------
    for (int mb = 0; mb < MTOT; mb += mc) {
        __hip_bfloat16* chunk = (__hip_bfloat16*)ws;
        vsn_kernel<<<dim3((mc / 64) / NT, NF), blk, 0, stream>>>(
            ws + o_xt + mb, Ar, f_w1, f_b1, f_b2, f_g1b, f_g2b,
            f_skw, f_skb, f_lng, f_lnb, chunk);
        wgemm_kernel<<<dim3(mc / 32, KS), dim3(64), 0, stream>>>(
            chunk, (const unsigned short*)(ws + ovl_wcat), ws + ovl_partial, mc);
        wtail_kernel<<<dim3(mc / 16), blk, 0, stream>>>(
            ws + ovl_partial, chunk, Ar, w_b1, w_skb, w_b2, w_g1b, w_g2b,
            w_lng, w_lnb,
            ws + o_sel + (size_t)mb * 64,
            (__hip_bfloat16*)(ws + o_selb) + (size_t)mb * 64, mc);
    }

    // ---------------- phase 2: xW then per-batch mega kernel -------------
    xw_kernel<<<dim3(MTOT / 64), blk, 0, stream>>>(
        (const __hip_bfloat16*)(ws + o_selb), Ar, lstm_bih, lstm_bhh, ws + o_S0);
    batch_kernel<<<dim3(BB), blk, 0, stream>>>(
        ws + o_S0, lstm_whh, ws + o_sel, Ar,
        pl_g1b, pl_g2b, pl_lng, pl_lnb,
        attn_in_b, attn_out_b, pa_g1b, pa_g2b, pa_lng, pa_lnb,
        ff_b1, ff_b2, ff_g1b, ff_g2b, ff_lng, ff_lnb,
        fc1_w, fc1_b, fc2_w, fc2_b, (float*)d_out);
}